// Round 1
// baseline (1182.929 us; speedup 1.0000x reference)
//
#include <hip/hip_runtime.h>
#include <math.h>

#define N_NODES 50000
#define N_EDGES 400000
#define NE_TOT  (N_NODES + N_EDGES)   // 450000 edges incl. self loops
#define HC0 128   // H*HID  (layer0 per-node feature width)
#define HC1 256   // H*OUT  (layer1 per-node feature width)

// ---------------------------------------------------------------------------
// self-loop weight = mean of incoming edge weights (PyG fill_value='mean')
// ---------------------------------------------------------------------------
__global__ void deg_kernel(const int* __restrict__ ei, const float* __restrict__ ew,
                           float* __restrict__ s, float* __restrict__ cnt) {
  int e = blockIdx.x * 256 + threadIdx.x;
  if (e < N_EDGES) {
    int dst = ei[N_EDGES + e];
    atomicAdd(&s[dst], ew[e]);
    atomicAdd(&cnt[dst], 1.0f);
  }
}

__global__ void loopw_kernel(float* __restrict__ s, const float* __restrict__ cnt) {
  int i = blockIdx.x * 256 + threadIdx.x;
  if (i < N_NODES) s[i] = s[i] / fmaxf(cnt[i], 1.0f);
}

// ---------------------------------------------------------------------------
// GEMM: out[n,k] = in[n,0:128] @ W[0:128,k] + bias[k].  M fixed = 128.
// block 256 threads; each thread: 2 rows x 4 cols. LDS-staged x tile.
// ---------------------------------------------------------------------------
template<int K>
__global__ __launch_bounds__(256) void gemm128(const float* __restrict__ in,
                                               const float* __restrict__ W,
                                               const float* __restrict__ bias,
                                               float* __restrict__ out, int nrows) {
  constexpr int ROWS  = 2048 / K;   // 32 / 16 / 8
  constexpr int KG    = K / 4;      // col groups
  constexpr int RSLOT = 256 / KG;   // = ROWS/2
  __shared__ float xs[ROWS * 132];  // pad 128->132 floats to break bank aliasing
  int tid  = threadIdx.x;
  int base = blockIdx.x * ROWS;
  for (int i = tid; i < ROWS * 32; i += 256) {
    int r = i >> 5, c4 = i & 31;
    int grow = base + r;
    float4 v = (grow < nrows) ? ((const float4*)in)[(size_t)grow * 32 + c4]
                              : float4{0.f, 0.f, 0.f, 0.f};
    *(float4*)&xs[r * 132 + c4 * 4] = v;
  }
  __syncthreads();
  int rslot = tid / KG;
  int k0    = (tid % KG) * 4;
  int lr0 = rslot, lr1 = rslot + RSLOT;
  float4 acc0{0.f,0.f,0.f,0.f}, acc1{0.f,0.f,0.f,0.f};
#pragma unroll 8
  for (int m = 0; m < 128; ++m) {
    float4 wv = *(const float4*)&W[m * K + k0];
    float x0 = xs[lr0 * 132 + m];
    float x1 = xs[lr1 * 132 + m];
    acc0.x += x0 * wv.x; acc0.y += x0 * wv.y; acc0.z += x0 * wv.z; acc0.w += x0 * wv.w;
    acc1.x += x1 * wv.x; acc1.y += x1 * wv.y; acc1.z += x1 * wv.z; acc1.w += x1 * wv.w;
  }
  float4 bv = *(const float4*)&bias[k0];
  acc0.x += bv.x; acc0.y += bv.y; acc0.z += bv.z; acc0.w += bv.w;
  acc1.x += bv.x; acc1.y += bv.y; acc1.z += bv.z; acc1.w += bv.w;
  int g0r = base + lr0, g1r = base + lr1;
  if (g0r < nrows) *(float4*)&out[(size_t)g0r * K + k0] = acc0;
  if (g1r < nrows) *(float4*)&out[(size_t)g1r * K + k0] = acc1;
}

// ---------------------------------------------------------------------------
// Layer-0 edge pass: 128 threads per edge (2 edges / 256-block).
// Unnormalized softmax (logits are O(1), exp-safe): p = exp(logit),
// scatter p into denom[dst,h] and p*xl[src,:] into out0[dst,:].
// ---------------------------------------------------------------------------
__global__ void edge_kernel0(const int* __restrict__ ei, const float* __restrict__ ew,
                             const float* __restrict__ loop_w,
                             const float* __restrict__ xl, const float* __restrict__ xr,
                             const float* __restrict__ We, const float* __restrict__ att,
                             float* __restrict__ denom, float* __restrict__ outacc) {
  int e = blockIdx.x * 2 + (threadIdx.x >> 7);
  int t = threadIdx.x & 127;
  if (e >= NE_TOT) return;
  int src, dst; float w;
  if (e < N_EDGES) { src = ei[e]; dst = ei[N_EDGES + e]; w = ew[e]; }
  else             { src = dst = e - N_EDGES; w = loop_w[e - N_EDGES]; }
  float a  = xl[(size_t)src * HC0 + t];
  float b  = xr[(size_t)dst * HC0 + t];
  float sv = a + b + w * We[t];
  float l  = sv > 0.f ? sv : 0.2f * sv;          // leaky_relu 0.2
  float contrib = l * att[t];                    // att flat [4*32]
#pragma unroll
  for (int off = 16; off > 0; off >>= 1) contrib += __shfl_xor(contrib, off, 64);
  float p = __expf(contrib);
  if ((t & 31) == 0) atomicAdd(&denom[dst * 4 + (t >> 5)], p);
  atomicAdd(&outacc[(size_t)dst * HC0 + t], p * a);
}

// ---------------------------------------------------------------------------
// Layer-1 edge pass: 256 threads per edge (1 edge / block). head = full wave.
// ---------------------------------------------------------------------------
__global__ void edge_kernel1(const int* __restrict__ ei, const float* __restrict__ ew,
                             const float* __restrict__ loop_w,
                             const float* __restrict__ xl, const float* __restrict__ xr,
                             const float* __restrict__ We, const float* __restrict__ att,
                             float* __restrict__ denom, float* __restrict__ outacc) {
  int e = blockIdx.x;
  int t = threadIdx.x;           // 0..255, head = t>>6
  if (e >= NE_TOT) return;
  int src, dst; float w;
  if (e < N_EDGES) { src = ei[e]; dst = ei[N_EDGES + e]; w = ew[e]; }
  else             { src = dst = e - N_EDGES; w = loop_w[e - N_EDGES]; }
  float a  = xl[(size_t)src * HC1 + t];
  float b  = xr[(size_t)dst * HC1 + t];
  float sv = a + b + w * We[t];
  float l  = sv > 0.f ? sv : 0.2f * sv;
  float contrib = l * att[t];                    // att flat [4*64]
#pragma unroll
  for (int off = 32; off > 0; off >>= 1) contrib += __shfl_xor(contrib, off, 64);
  float p = __expf(contrib);
  if ((t & 63) == 0) atomicAdd(&denom[dst * 4 + (t >> 6)], p);
  atomicAdd(&outacc[(size_t)dst * HC1 + t], p * a);
}

// ---------------------------------------------------------------------------
// Layer-0 epilogue: wave per node. v = out0/denom + b0 -> ELU -> LN -> *g+be
// -> h += result (h holds x@P0+pb0 residual).
// ---------------------------------------------------------------------------
__global__ void epilogue0(const float* __restrict__ outacc, const float* __restrict__ denom,
                          const float* __restrict__ b, const float* __restrict__ g,
                          const float* __restrict__ be, float* __restrict__ h) {
  int n = blockIdx.x * 4 + (threadIdx.x >> 6);
  int l = threadIdx.x & 63;
  if (n >= N_NODES) return;
  float d0 = denom[n * 4 + (l >> 5)];
  float d1 = denom[n * 4 + 2 + (l >> 5)];
  float v0 = outacc[(size_t)n * 128 + l]      / d0 + b[l];
  float v1 = outacc[(size_t)n * 128 + 64 + l] / d1 + b[64 + l];
  v0 = v0 > 0.f ? v0 : __expf(v0) - 1.f;       // ELU
  v1 = v1 > 0.f ? v1 : __expf(v1) - 1.f;
  float sum = v0 + v1, sq = v0 * v0 + v1 * v1;
#pragma unroll
  for (int off = 32; off > 0; off >>= 1) {
    sum += __shfl_xor(sum, off, 64);
    sq  += __shfl_xor(sq,  off, 64);
  }
  float mean = sum * (1.f / 128.f);
  float var  = sq * (1.f / 128.f) - mean * mean;
  float inv  = rsqrtf(var + 1e-5f);
  h[(size_t)n * 128 + l]      += (v0 - mean) * inv * g[l]      + be[l];
  h[(size_t)n * 128 + 64 + l] += (v1 - mean) * inv * g[64 + l] + be[64 + l];
}

// ---------------------------------------------------------------------------
// Layer-1 epilogue: wave per node; mean over 4 heads (each /denom), +b1,
// ELU, LN(64), *g+be, += residual already in d_out.
// ---------------------------------------------------------------------------
__global__ void epilogue1(const float* __restrict__ outacc, const float* __restrict__ denom,
                          const float* __restrict__ b, const float* __restrict__ g,
                          const float* __restrict__ be, float* __restrict__ out) {
  int n = blockIdx.x * 4 + (threadIdx.x >> 6);
  int c = threadIdx.x & 63;
  if (n >= N_NODES) return;
  float acc = 0.f;
#pragma unroll
  for (int hh = 0; hh < 4; ++hh)
    acc += outacc[(size_t)n * 256 + hh * 64 + c] / denom[n * 4 + hh];
  float v = acc * 0.25f + b[c];
  v = v > 0.f ? v : __expf(v) - 1.f;
  float sum = v, sq = v * v;
#pragma unroll
  for (int off = 32; off > 0; off >>= 1) {
    sum += __shfl_xor(sum, off, 64);
    sq  += __shfl_xor(sq,  off, 64);
  }
  float mean = sum * (1.f / 64.f);
  float var  = sq * (1.f / 64.f) - mean * mean;
  float inv  = rsqrtf(var + 1e-5f);
  out[(size_t)n * 64 + c] += (v - mean) * inv * g[c] + be[c];
}

// ---------------------------------------------------------------------------
extern "C" void kernel_launch(void* const* d_in, const int* in_sizes, int n_in,
                              void* d_out, int out_size, void* d_ws, size_t ws_size,
                              hipStream_t stream) {
  const float* x    = (const float*)d_in[0];
  const int*   ei   = (const int*)  d_in[1];
  const float* ew   = (const float*)d_in[2];
  const float* Wl0  = (const float*)d_in[3];
  const float* bl0  = (const float*)d_in[4];
  const float* Wr0  = (const float*)d_in[5];
  const float* br0  = (const float*)d_in[6];
  const float* We0  = (const float*)d_in[7];
  const float* att0 = (const float*)d_in[8];
  const float* b0   = (const float*)d_in[9];
  const float* g0   = (const float*)d_in[10];
  const float* be0  = (const float*)d_in[11];
  const float* Wl1  = (const float*)d_in[12];
  const float* bl1  = (const float*)d_in[13];
  const float* Wr1  = (const float*)d_in[14];
  const float* br1  = (const float*)d_in[15];
  const float* We1  = (const float*)d_in[16];
  const float* att1 = (const float*)d_in[17];
  const float* b1   = (const float*)d_in[18];
  const float* g1   = (const float*)d_in[19];
  const float* be1  = (const float*)d_in[20];
  const float* P0   = (const float*)d_in[21];
  const float* pb0  = (const float*)d_in[22];
  const float* P1   = (const float*)d_in[23];
  const float* pb1  = (const float*)d_in[24];
  float* out = (float*)d_out;

  // workspace layout (floats). Aliasing: R1 = {xl0,xr0} then xl1;
  // R2 = {out0} then xr1.
  float* f       = (float*)d_ws;
  float* s_loopw = f;                       //   50176
  float* cnt     = f + 50176;               //   50176
  float* denom   = f + 100352;              //  200704 (N*4)
  float* hbuf    = f + 301056;              // 6.40e6
  float* R1      = hbuf + 6400000;          // 12.8e6
  float* R2      = R1 + 12800000;           // 12.8e6
  float* out1    = R2 + 12800000;           // 12.8e6
  float* xl0 = R1;
  float* xr0 = R1 + 6400000;
  float* out0 = R2;
  float* xl1 = R1;
  float* xr1 = R2;

  // ---- self-loop weights -------------------------------------------------
  hipMemsetAsync(s_loopw, 0, (size_t)(50176 * 2 + 200704) * sizeof(float), stream);
  deg_kernel<<<(N_EDGES + 255) / 256, 256, 0, stream>>>(ei, ew, s_loopw, cnt);
  loopw_kernel<<<(N_NODES + 255) / 256, 256, 0, stream>>>(s_loopw, cnt);

  // ---- layer 0 -----------------------------------------------------------
  gemm128<128><<<(N_NODES + 15) / 16, 256, 0, stream>>>(x, Wl0, bl0, xl0, N_NODES);
  gemm128<128><<<(N_NODES + 15) / 16, 256, 0, stream>>>(x, Wr0, br0, xr0, N_NODES);
  gemm128<128><<<(N_NODES + 15) / 16, 256, 0, stream>>>(x, P0, pb0, hbuf, N_NODES);
  hipMemsetAsync(out0, 0, (size_t)6400000 * sizeof(float), stream);
  edge_kernel0<<<NE_TOT / 2, 256, 0, stream>>>(ei, ew, s_loopw, xl0, xr0, We0, att0,
                                               denom, out0);
  epilogue0<<<(N_NODES + 3) / 4, 256, 0, stream>>>(out0, denom, b0, g0, be0, hbuf);

  // ---- layer 1 -----------------------------------------------------------
  gemm128<256><<<(N_NODES + 7) / 8, 256, 0, stream>>>(hbuf, Wl1, bl1, xl1, N_NODES);
  gemm128<256><<<(N_NODES + 7) / 8, 256, 0, stream>>>(hbuf, Wr1, br1, xr1, N_NODES);
  gemm128<64><<<(N_NODES + 31) / 32, 256, 0, stream>>>(hbuf, P1, pb1, out, N_NODES);
  hipMemsetAsync(denom, 0, (size_t)200704 * sizeof(float), stream);
  hipMemsetAsync(out1, 0, (size_t)12800000 * sizeof(float), stream);
  edge_kernel1<<<NE_TOT, 256, 0, stream>>>(ei, ew, s_loopw, xl1, xr1, We1, att1,
                                           denom, out1);
  epilogue1<<<(N_NODES + 3) / 4, 256, 0, stream>>>(out1, denom, b1, g1, be1, out);
}

// Round 2
// 728.050 us; speedup vs baseline: 1.6248x; 1.6248x over previous
//
#include <hip/hip_runtime.h>
#include <math.h>

#define N_NODES 50000
#define N_EDGES 400000
#define NPAD    50176            // 196*256
#define HC0 128
#define HC1 256

// ---------------------------------------------------------------------------
// degree histogram + edge-weight sum (for PyG self-loop fill_value='mean')
// ---------------------------------------------------------------------------
__global__ void deg_kernel(const int* __restrict__ ei, const float* __restrict__ ew,
                           float* __restrict__ s, int* __restrict__ deg) {
  int e = blockIdx.x * 256 + threadIdx.x;
  if (e < N_EDGES) {
    int dst = ei[N_EDGES + e];
    atomicAdd(&s[dst], ew[e]);
    atomicAdd(&deg[dst], 1);
  }
}

__global__ void loopw_kernel(float* __restrict__ s, const int* __restrict__ deg) {
  int i = blockIdx.x * 256 + threadIdx.x;
  if (i < N_NODES) s[i] = s[i] / fmaxf((float)deg[i], 1.0f);
}

// ---------------------------------------------------------------------------
// two-level exclusive scan of deg[NPAD] -> part (within-block excl) + bsum
// ---------------------------------------------------------------------------
__global__ void scan1(const int* __restrict__ deg, int* __restrict__ part,
                      int* __restrict__ bsum) {
  int i = blockIdx.x * 256 + threadIdx.x;
  int lane = threadIdx.x & 63, wid = threadIdx.x >> 6;
  int v = deg[i];                       // deg[NPAD] zero-padded
  int inc = v;
#pragma unroll
  for (int d = 1; d < 64; d <<= 1) { int y = __shfl_up(inc, d, 64); if (lane >= d) inc += y; }
  __shared__ int wsum[4];
  if (lane == 63) wsum[wid] = inc;
  __syncthreads();
  int off = 0;
#pragma unroll
  for (int w = 0; w < 4; ++w) { int sv = wsum[w]; if (w < wid) off += sv; }
  part[i] = inc - v + off;
  if (threadIdx.x == 0) bsum[blockIdx.x] = wsum[0] + wsum[1] + wsum[2] + wsum[3];
}

__global__ void scan2(int* __restrict__ bsum) {
  int t = threadIdx.x;                  // 256 threads, 196 valid
  int lane = t & 63, wid = t >> 6;
  int v = (t < 196) ? bsum[t] : 0;
  int inc = v;
#pragma unroll
  for (int d = 1; d < 64; d <<= 1) { int y = __shfl_up(inc, d, 64); if (lane >= d) inc += y; }
  __shared__ int wsum[4];
  if (lane == 63) wsum[wid] = inc;
  __syncthreads();
  int off = 0;
#pragma unroll
  for (int w = 0; w < 4; ++w) { int sv = wsum[w]; if (w < wid) off += sv; }
  if (t < 196) bsum[t] = inc - v + off;
}

// ---------------------------------------------------------------------------
// scatter edges into CSR slots (order within a row is atomic-cursor order;
// fp sum order only -> far below threshold)
// ---------------------------------------------------------------------------
__global__ void scatter_kernel(const int* __restrict__ ei, const float* __restrict__ ew,
                               const int* __restrict__ part, const int* __restrict__ bsum,
                               int* __restrict__ cursor,
                               int* __restrict__ csrc, float* __restrict__ cw) {
  int e = blockIdx.x * 256 + threadIdx.x;
  if (e >= N_EDGES) return;
  int dst = ei[N_EDGES + e];
  int pos = atomicAdd(&cursor[dst], 1);
  int idx = part[dst] + bsum[dst >> 8] + pos;
  csrc[idx] = ei[e];
  cw[idx]  = ew[e];
}

// ---------------------------------------------------------------------------
// GEMM: out[n,k] = in[n,0:128] @ W[0:128,k] + bias[k]
// ---------------------------------------------------------------------------
template<int K>
__global__ __launch_bounds__(256) void gemm128(const float* __restrict__ in,
                                               const float* __restrict__ W,
                                               const float* __restrict__ bias,
                                               float* __restrict__ out, int nrows) {
  constexpr int ROWS  = 2048 / K;
  constexpr int KG    = K / 4;
  constexpr int RSLOT = 256 / KG;
  __shared__ float xs[ROWS * 132];
  int tid  = threadIdx.x;
  int base = blockIdx.x * ROWS;
  for (int i = tid; i < ROWS * 32; i += 256) {
    int r = i >> 5, c4 = i & 31;
    int grow = base + r;
    float4 v = (grow < nrows) ? ((const float4*)in)[(size_t)grow * 32 + c4]
                              : float4{0.f, 0.f, 0.f, 0.f};
    *(float4*)&xs[r * 132 + c4 * 4] = v;
  }
  __syncthreads();
  int rslot = tid / KG;
  int k0    = (tid % KG) * 4;
  int lr0 = rslot, lr1 = rslot + RSLOT;
  float4 acc0{0.f,0.f,0.f,0.f}, acc1{0.f,0.f,0.f,0.f};
#pragma unroll 8
  for (int m = 0; m < 128; ++m) {
    float4 wv = *(const float4*)&W[m * K + k0];
    float x0 = xs[lr0 * 132 + m];
    float x1 = xs[lr1 * 132 + m];
    acc0.x += x0 * wv.x; acc0.y += x0 * wv.y; acc0.z += x0 * wv.z; acc0.w += x0 * wv.w;
    acc1.x += x1 * wv.x; acc1.y += x1 * wv.y; acc1.z += x1 * wv.z; acc1.w += x1 * wv.w;
  }
  float4 bv = *(const float4*)&bias[k0];
  acc0.x += bv.x; acc0.y += bv.y; acc0.z += bv.z; acc0.w += bv.w;
  acc1.x += bv.x; acc1.y += bv.y; acc1.z += bv.z; acc1.w += bv.w;
  int g0r = base + lr0, g1r = base + lr1;
  if (g0r < nrows) *(float4*)&out[(size_t)g0r * K + k0] = acc0;
  if (g1r < nrows) *(float4*)&out[(size_t)g1r * K + k0] = acc1;
}

// ---------------------------------------------------------------------------
// Layer-0 gather aggregation + fused epilogue. 128 thr/block, 1 node/block.
// head = t>>5 (32-lane subgroup). acc/denom in registers. LN(128) via LDS.
// ---------------------------------------------------------------------------
__global__ __launch_bounds__(128) void agg0(
    const int* __restrict__ part, const int* __restrict__ bsum,
    const int* __restrict__ deg, const int* __restrict__ csrc,
    const float* __restrict__ cw, const float* __restrict__ loop_w,
    const float* __restrict__ xl, const float* __restrict__ xr,
    const float* __restrict__ We, const float* __restrict__ att,
    const float* __restrict__ b, const float* __restrict__ g,
    const float* __restrict__ be, float* __restrict__ h) {
  int n = blockIdx.x, t = threadIdx.x;
  float xrv  = xr[(size_t)n * HC0 + t];
  float wev  = We[t], attv = att[t];
  int start  = part[n] + bsum[n >> 8];
  int cnt    = deg[n];
  float acc = 0.f, den = 0.f;
  {   // self loop
    float a  = xl[(size_t)n * HC0 + t];
    float sv = a + xrv + loop_w[n] * wev;
    float l  = sv > 0.f ? sv : 0.2f * sv;
    float c  = l * attv;
#pragma unroll
    for (int o = 16; o > 0; o >>= 1) c += __shfl_xor(c, o, 64);
    float p = __expf(c);
    acc += p * a; den += p;
  }
  for (int k = 0; k < cnt; ++k) {
    int   src = csrc[start + k];
    float w   = cw[start + k];
    float a   = xl[(size_t)src * HC0 + t];
    float sv  = a + xrv + w * wev;
    float l   = sv > 0.f ? sv : 0.2f * sv;
    float c   = l * attv;
#pragma unroll
    for (int o = 16; o > 0; o >>= 1) c += __shfl_xor(c, o, 64);
    float p = __expf(c);
    acc += p * a; den += p;
  }
  float v = acc / den + b[t];
  v = v > 0.f ? v : __expf(v) - 1.f;            // ELU
  float s1 = v, s2 = v * v;
#pragma unroll
  for (int o = 32; o > 0; o >>= 1) { s1 += __shfl_xor(s1, o, 64); s2 += __shfl_xor(s2, o, 64); }
  __shared__ float red[4];
  int lane = t & 63, wid = t >> 6;
  if (lane == 0) { red[wid] = s1; red[wid + 2] = s2; }
  __syncthreads();
  float sum = red[0] + red[1], sq = red[2] + red[3];
  float mean = sum * (1.f / 128.f);
  float inv  = rsqrtf(sq * (1.f / 128.f) - mean * mean + 1e-5f);
  h[(size_t)n * HC0 + t] += (v - mean) * inv * g[t] + be[t];
}

// ---------------------------------------------------------------------------
// Layer-1 gather aggregation + fused epilogue. 256 thr/block, 1 node/block.
// head = wave (t>>6). mean-over-heads + LN(64) via LDS.
// ---------------------------------------------------------------------------
__global__ __launch_bounds__(256) void agg1(
    const int* __restrict__ part, const int* __restrict__ bsum,
    const int* __restrict__ deg, const int* __restrict__ csrc,
    const float* __restrict__ cw, const float* __restrict__ loop_w,
    const float* __restrict__ xl, const float* __restrict__ xr,
    const float* __restrict__ We, const float* __restrict__ att,
    const float* __restrict__ b, const float* __restrict__ g,
    const float* __restrict__ be, float* __restrict__ out) {
  int n = blockIdx.x, t = threadIdx.x;
  float xrv  = xr[(size_t)n * HC1 + t];
  float wev  = We[t], attv = att[t];
  int start  = part[n] + bsum[n >> 8];
  int cnt    = deg[n];
  float acc = 0.f, den = 0.f;
  {   // self loop
    float a  = xl[(size_t)n * HC1 + t];
    float sv = a + xrv + loop_w[n] * wev;
    float l  = sv > 0.f ? sv : 0.2f * sv;
    float c  = l * attv;
#pragma unroll
    for (int o = 32; o > 0; o >>= 1) c += __shfl_xor(c, o, 64);
    float p = __expf(c);
    acc += p * a; den += p;
  }
  for (int k = 0; k < cnt; ++k) {
    int   src = csrc[start + k];
    float w   = cw[start + k];
    float a   = xl[(size_t)src * HC1 + t];
    float sv  = a + xrv + w * wev;
    float l   = sv > 0.f ? sv : 0.2f * sv;
    float c   = l * attv;
#pragma unroll
    for (int o = 32; o > 0; o >>= 1) c += __shfl_xor(c, o, 64);
    float p = __expf(c);
    acc += p * a; den += p;
  }
  __shared__ float lds[HC1];
  lds[t] = acc / den;
  __syncthreads();
  if (t < 64) {
    float v = (lds[t] + lds[t + 64] + lds[t + 128] + lds[t + 192]) * 0.25f + b[t];
    v = v > 0.f ? v : __expf(v) - 1.f;          // ELU
    float s1 = v, s2 = v * v;
#pragma unroll
    for (int o = 32; o > 0; o >>= 1) { s1 += __shfl_xor(s1, o, 64); s2 += __shfl_xor(s2, o, 64); }
    float mean = s1 * (1.f / 64.f);
    float inv  = rsqrtf(s2 * (1.f / 64.f) - mean * mean + 1e-5f);
    out[(size_t)n * 64 + t] += (v - mean) * inv * g[t] + be[t];
  }
}

// ---------------------------------------------------------------------------
extern "C" void kernel_launch(void* const* d_in, const int* in_sizes, int n_in,
                              void* d_out, int out_size, void* d_ws, size_t ws_size,
                              hipStream_t stream) {
  const float* x    = (const float*)d_in[0];
  const int*   ei   = (const int*)  d_in[1];
  const float* ew   = (const float*)d_in[2];
  const float* Wl0  = (const float*)d_in[3];
  const float* bl0  = (const float*)d_in[4];
  const float* Wr0  = (const float*)d_in[5];
  const float* br0  = (const float*)d_in[6];
  const float* We0  = (const float*)d_in[7];
  const float* att0 = (const float*)d_in[8];
  const float* b0   = (const float*)d_in[9];
  const float* g0   = (const float*)d_in[10];
  const float* be0  = (const float*)d_in[11];
  const float* Wl1  = (const float*)d_in[12];
  const float* bl1  = (const float*)d_in[13];
  const float* Wr1  = (const float*)d_in[14];
  const float* br1  = (const float*)d_in[15];
  const float* We1  = (const float*)d_in[16];
  const float* att1 = (const float*)d_in[17];
  const float* b1   = (const float*)d_in[18];
  const float* g1   = (const float*)d_in[19];
  const float* be1  = (const float*)d_in[20];
  const float* P0   = (const float*)d_in[21];
  const float* pb0  = (const float*)d_in[22];
  const float* P1   = (const float*)d_in[23];
  const float* pb1  = (const float*)d_in[24];
  float* out = (float*)d_out;

  // workspace layout (32-bit words)
  float* f       = (float*)d_ws;
  float* s_loopw = f;                          // 50176 f
  int*   deg     = (int*)(f + 50176);          // 50176 i
  int*   cursor  = (int*)(f + 100352);         // 50176 i
  int*   part    = (int*)(f + 150528);         // 50176 i
  int*   bsum    = (int*)(f + 200704);         // 256 i
  int*   csrc    = (int*)(f + 200960);         // 400384 i
  float* cw      = f + 601344;                 // 400384 f
  float* hbuf    = f + 1001728;                // 6.4M f
  float* A       = hbuf + 6400000;             // 12.8M f (xl0 then xl1)
  float* B       = A + 12800000;               // 12.8M f (xr0 then xr1)
  float* xl0 = A, *xr0 = B, *xl1 = A, *xr1 = B;

  // ---- CSR build (once, reused by both layers) ---------------------------
  hipMemsetAsync(s_loopw, 0, (size_t)(50176 * 3) * sizeof(float), stream); // s,deg,cursor
  deg_kernel<<<(N_EDGES + 255) / 256, 256, 0, stream>>>(ei, ew, s_loopw, deg);
  loopw_kernel<<<(N_NODES + 255) / 256, 256, 0, stream>>>(s_loopw, deg);
  scan1<<<NPAD / 256, 256, 0, stream>>>(deg, part, bsum);
  scan2<<<1, 256, 0, stream>>>(bsum);
  scatter_kernel<<<(N_EDGES + 255) / 256, 256, 0, stream>>>(ei, ew, part, bsum,
                                                            cursor, csrc, cw);

  // ---- layer 0 -----------------------------------------------------------
  gemm128<128><<<(N_NODES + 15) / 16, 256, 0, stream>>>(x, Wl0, bl0, xl0, N_NODES);
  gemm128<128><<<(N_NODES + 15) / 16, 256, 0, stream>>>(x, Wr0, br0, xr0, N_NODES);
  gemm128<128><<<(N_NODES + 15) / 16, 256, 0, stream>>>(x, P0, pb0, hbuf, N_NODES);
  agg0<<<N_NODES, 128, 0, stream>>>(part, bsum, deg, csrc, cw, s_loopw,
                                    xl0, xr0, We0, att0, b0, g0, be0, hbuf);

  // ---- layer 1 -----------------------------------------------------------
  gemm128<256><<<(N_NODES + 7) / 8, 256, 0, stream>>>(hbuf, Wl1, bl1, xl1, N_NODES);
  gemm128<256><<<(N_NODES + 7) / 8, 256, 0, stream>>>(hbuf, Wr1, br1, xr1, N_NODES);
  gemm128<64><<<(N_NODES + 31) / 32, 256, 0, stream>>>(hbuf, P1, pb1, out, N_NODES);
  agg1<<<N_NODES, 256, 0, stream>>>(part, bsum, deg, csrc, cw, s_loopw,
                                    xl1, xr1, We1, att1, b1, g1, be1, out);
}

// Round 3
// 496.279 us; speedup vs baseline: 2.3836x; 1.4670x over previous
//
#include <hip/hip_runtime.h>
#include <math.h>

#define N_NODES 50000
#define N_EDGES 400000
#define NPAD    50176            // 196*256
#define HC0 128
#define HC1 256

typedef short bf16x8 __attribute__((ext_vector_type(8)));
typedef float f32x4  __attribute__((ext_vector_type(4)));

__device__ inline unsigned short f2bf(float f) {
  union { float f; unsigned u; } v; v.f = f;
  unsigned r = v.u + 0x7FFFu + ((v.u >> 16) & 1u);   // RNE
  return (unsigned short)(r >> 16);
}
__device__ inline float bf2f(unsigned short h) {
  union { unsigned u; float f; } v; v.u = ((unsigned)h) << 16;
  return v.f;
}

// ---------------------------------------------------------------------------
// CSR build (unchanged from round 2)
// ---------------------------------------------------------------------------
__global__ void deg_kernel(const int* __restrict__ ei, const float* __restrict__ ew,
                           float* __restrict__ s, int* __restrict__ deg) {
  int e = blockIdx.x * 256 + threadIdx.x;
  if (e < N_EDGES) {
    int dst = ei[N_EDGES + e];
    atomicAdd(&s[dst], ew[e]);
    atomicAdd(&deg[dst], 1);
  }
}

__global__ void loopw_kernel(float* __restrict__ s, const int* __restrict__ deg) {
  int i = blockIdx.x * 256 + threadIdx.x;
  if (i < N_NODES) s[i] = s[i] / fmaxf((float)deg[i], 1.0f);
}

__global__ void scan1(const int* __restrict__ deg, int* __restrict__ part,
                      int* __restrict__ bsum) {
  int i = blockIdx.x * 256 + threadIdx.x;
  int lane = threadIdx.x & 63, wid = threadIdx.x >> 6;
  int v = deg[i];
  int inc = v;
#pragma unroll
  for (int d = 1; d < 64; d <<= 1) { int y = __shfl_up(inc, d, 64); if (lane >= d) inc += y; }
  __shared__ int wsum[4];
  if (lane == 63) wsum[wid] = inc;
  __syncthreads();
  int off = 0;
#pragma unroll
  for (int w = 0; w < 4; ++w) { int sv = wsum[w]; if (w < wid) off += sv; }
  part[i] = inc - v + off;
  if (threadIdx.x == 0) bsum[blockIdx.x] = wsum[0] + wsum[1] + wsum[2] + wsum[3];
}

__global__ void scan2(int* __restrict__ bsum) {
  int t = threadIdx.x;
  int lane = t & 63, wid = t >> 6;
  int v = (t < 196) ? bsum[t] : 0;
  int inc = v;
#pragma unroll
  for (int d = 1; d < 64; d <<= 1) { int y = __shfl_up(inc, d, 64); if (lane >= d) inc += y; }
  __shared__ int wsum[4];
  if (lane == 63) wsum[wid] = inc;
  __syncthreads();
  int off = 0;
#pragma unroll
  for (int w = 0; w < 4; ++w) { int sv = wsum[w]; if (w < wid) off += sv; }
  if (t < 196) bsum[t] = inc - v + off;
}

__global__ void scatter_kernel(const int* __restrict__ ei, const float* __restrict__ ew,
                               const int* __restrict__ part, const int* __restrict__ bsum,
                               int* __restrict__ cursor,
                               int* __restrict__ csrc, float* __restrict__ cw) {
  int e = blockIdx.x * 256 + threadIdx.x;
  if (e >= N_EDGES) return;
  int dst = ei[N_EDGES + e];
  int pos = atomicAdd(&cursor[dst], 1);
  int idx = part[dst] + bsum[dst >> 8] + pos;
  csrc[idx] = ei[e];
  cw[idx]  = ew[e];
}

// ---------------------------------------------------------------------------
// fp32 -> bf16 (vectorized)
// ---------------------------------------------------------------------------
__global__ void cvt_bf16(const float* __restrict__ in, unsigned short* __restrict__ out,
                         int n4) {
  int i = blockIdx.x * 256 + threadIdx.x;
  if (i >= n4) return;
  float4 v = ((const float4*)in)[i];
  ushort4 o; o.x = f2bf(v.x); o.y = f2bf(v.y); o.z = f2bf(v.z); o.w = f2bf(v.w);
  ((ushort4*)out)[i] = o;
}

// ---------------------------------------------------------------------------
// weight pack: W[128][N] fp32 -> BT[N][128] bf16 (all six in one launch)
// ---------------------------------------------------------------------------
__global__ void pack_w(const float* __restrict__ Wl0, const float* __restrict__ Wr0,
                       const float* __restrict__ P0,  const float* __restrict__ Wl1,
                       const float* __restrict__ Wr1, const float* __restrict__ P1,
                       unsigned short* __restrict__ o_wl0, unsigned short* __restrict__ o_wr0,
                       unsigned short* __restrict__ o_p0,  unsigned short* __restrict__ o_wl1,
                       unsigned short* __restrict__ o_wr1, unsigned short* __restrict__ o_p1) {
  int n = blockIdx.x, k = threadIdx.x;
  const float* W; unsigned short* O; int N, nl;
  if      (n < 128) { W = Wl0; O = o_wl0; N = 128; nl = n; }
  else if (n < 256) { W = Wr0; O = o_wr0; N = 128; nl = n - 128; }
  else if (n < 384) { W = P0;  O = o_p0;  N = 128; nl = n - 256; }
  else if (n < 640) { W = Wl1; O = o_wl1; N = 256; nl = n - 384; }
  else if (n < 896) { W = Wr1; O = o_wr1; N = 256; nl = n - 640; }
  else              { W = P1;  O = o_p1;  N = 64;  nl = n - 896; }
  O[nl * 128 + k] = f2bf(W[(size_t)k * N + nl]);
}

// ---------------------------------------------------------------------------
// MFMA GEMM: C[M][NCOLS] = A[M][128] @ BT^T + bias.  A,BT bf16; C fp32/bf16.
// Block = 4 waves x 16 rows = 64 rows; fragments loaded directly from global.
// A and B frags use the SAME per-lane k-pattern -> result invariant to the
// HW k-permutation; C/D layout col=lane&15,row=4*(lane>>4)+reg (m89-verified).
// ---------------------------------------------------------------------------
template<int NCOLS, bool OUT_BF16>
__global__ __launch_bounds__(256) void gemm_mfma(
    const unsigned short* __restrict__ A, const unsigned short* __restrict__ BT,
    const float* __restrict__ bias, void* __restrict__ Cv, int M) {
  constexpr int NT = NCOLS / 16;
  const int w  = threadIdx.x >> 6, l = threadIdx.x & 63;
  const int lr = l & 15, lg = l >> 4;
  const int r0 = blockIdx.x * 64 + w * 16;
  int ar = r0 + lr; if (ar > M - 1) ar = M - 1;   // clamped loads only corrupt unstored rows
  const bf16x8* ap = (const bf16x8*)(A + (size_t)ar * 128 + lg * 8);
  bf16x8 a0 = ap[0], a1 = ap[4], a2 = ap[8], a3 = ap[12];   // k = 0,32,64,96
#pragma unroll
  for (int ct = 0; ct < NT; ++ct) {
    const bf16x8* bp = (const bf16x8*)(BT + ((size_t)(ct * 16 + lr)) * 128 + lg * 8);
    bf16x8 b0 = bp[0], b1 = bp[4], b2 = bp[8], b3 = bp[12];
    f32x4 acc = {0.f, 0.f, 0.f, 0.f};
    acc = __builtin_amdgcn_mfma_f32_16x16x32_bf16(a0, b0, acc, 0, 0, 0);
    acc = __builtin_amdgcn_mfma_f32_16x16x32_bf16(a1, b1, acc, 0, 0, 0);
    acc = __builtin_amdgcn_mfma_f32_16x16x32_bf16(a2, b2, acc, 0, 0, 0);
    acc = __builtin_amdgcn_mfma_f32_16x16x32_bf16(a3, b3, acc, 0, 0, 0);
    const int col = ct * 16 + lr;
    const float bv = bias[col];
#pragma unroll
    for (int q = 0; q < 4; ++q) {
      int row = r0 + lg * 4 + q;
      if (row < M) {
        float o = acc[q] + bv;
        if (OUT_BF16)
          ((unsigned short*)Cv)[(size_t)row * NCOLS + col] = f2bf(o);
        else
          ((float*)Cv)[(size_t)row * NCOLS + col] = o;
      }
    }
  }
}

// ---------------------------------------------------------------------------
// Layer-0 gather aggregation + fused epilogue; bf16 gathers; writes h as bf16.
// ---------------------------------------------------------------------------
__global__ __launch_bounds__(128) void agg0(
    const int* __restrict__ part, const int* __restrict__ bsum,
    const int* __restrict__ deg, const int* __restrict__ csrc,
    const float* __restrict__ cw, const float* __restrict__ loop_w,
    const unsigned short* __restrict__ xl, const unsigned short* __restrict__ xr,
    const float* __restrict__ We, const float* __restrict__ att,
    const float* __restrict__ b, const float* __restrict__ g,
    const float* __restrict__ be, const float* __restrict__ hres,
    unsigned short* __restrict__ hout) {
  int n = blockIdx.x, t = threadIdx.x;
  float xrv  = bf2f(xr[(size_t)n * HC0 + t]);
  float wev  = We[t], attv = att[t];
  int start  = part[n] + bsum[n >> 8];
  int cnt    = deg[n];
  float acc = 0.f, den = 0.f;
  {   // self loop
    float a  = bf2f(xl[(size_t)n * HC0 + t]);
    float sv = a + xrv + loop_w[n] * wev;
    float lk = sv > 0.f ? sv : 0.2f * sv;
    float c  = lk * attv;
#pragma unroll
    for (int o = 16; o > 0; o >>= 1) c += __shfl_xor(c, o, 64);
    float p = __expf(c);
    acc += p * a; den += p;
  }
  for (int k = 0; k < cnt; ++k) {
    int   src = csrc[start + k];
    float wgt = cw[start + k];
    float a   = bf2f(xl[(size_t)src * HC0 + t]);
    float sv  = a + xrv + wgt * wev;
    float lk  = sv > 0.f ? sv : 0.2f * sv;
    float c   = lk * attv;
#pragma unroll
    for (int o = 16; o > 0; o >>= 1) c += __shfl_xor(c, o, 64);
    float p = __expf(c);
    acc += p * a; den += p;
  }
  float v = acc / den + b[t];
  v = v > 0.f ? v : __expf(v) - 1.f;            // ELU
  float s1 = v, s2 = v * v;
#pragma unroll
  for (int o = 32; o > 0; o >>= 1) { s1 += __shfl_xor(s1, o, 64); s2 += __shfl_xor(s2, o, 64); }
  __shared__ float red[4];
  int lane = t & 63, wid = t >> 6;
  if (lane == 0) { red[wid] = s1; red[wid + 2] = s2; }
  __syncthreads();
  float sum = red[0] + red[1], sq = red[2] + red[3];
  float mean = sum * (1.f / 128.f);
  float inv  = rsqrtf(sq * (1.f / 128.f) - mean * mean + 1e-5f);
  float hv = (v - mean) * inv * g[t] + be[t] + hres[(size_t)n * HC0 + t];
  hout[(size_t)n * HC0 + t] = f2bf(hv);
}

// ---------------------------------------------------------------------------
// Layer-1 gather aggregation + fused epilogue; bf16 gathers; out fp32 +=.
// ---------------------------------------------------------------------------
__global__ __launch_bounds__(256) void agg1(
    const int* __restrict__ part, const int* __restrict__ bsum,
    const int* __restrict__ deg, const int* __restrict__ csrc,
    const float* __restrict__ cw, const float* __restrict__ loop_w,
    const unsigned short* __restrict__ xl, const unsigned short* __restrict__ xr,
    const float* __restrict__ We, const float* __restrict__ att,
    const float* __restrict__ b, const float* __restrict__ g,
    const float* __restrict__ be, float* __restrict__ out) {
  int n = blockIdx.x, t = threadIdx.x;
  float xrv  = bf2f(xr[(size_t)n * HC1 + t]);
  float wev  = We[t], attv = att[t];
  int start  = part[n] + bsum[n >> 8];
  int cnt    = deg[n];
  float acc = 0.f, den = 0.f;
  {   // self loop
    float a  = bf2f(xl[(size_t)n * HC1 + t]);
    float sv = a + xrv + loop_w[n] * wev;
    float lk = sv > 0.f ? sv : 0.2f * sv;
    float c  = lk * attv;
#pragma unroll
    for (int o = 32; o > 0; o >>= 1) c += __shfl_xor(c, o, 64);
    float p = __expf(c);
    acc += p * a; den += p;
  }
  for (int k = 0; k < cnt; ++k) {
    int   src = csrc[start + k];
    float wgt = cw[start + k];
    float a   = bf2f(xl[(size_t)src * HC1 + t]);
    float sv  = a + xrv + wgt * wev;
    float lk  = sv > 0.f ? sv : 0.2f * sv;
    float c   = lk * attv;
#pragma unroll
    for (int o = 32; o > 0; o >>= 1) c += __shfl_xor(c, o, 64);
    float p = __expf(c);
    acc += p * a; den += p;
  }
  __shared__ float lds[HC1];
  lds[t] = acc / den;
  __syncthreads();
  if (t < 64) {
    float v = (lds[t] + lds[t + 64] + lds[t + 128] + lds[t + 192]) * 0.25f + b[t];
    v = v > 0.f ? v : __expf(v) - 1.f;          // ELU
    float s1 = v, s2 = v * v;
#pragma unroll
    for (int o = 32; o > 0; o >>= 1) { s1 += __shfl_xor(s1, o, 64); s2 += __shfl_xor(s2, o, 64); }
    float mean = s1 * (1.f / 64.f);
    float inv  = rsqrtf(s2 * (1.f / 64.f) - mean * mean + 1e-5f);
    out[(size_t)n * 64 + t] += (v - mean) * inv * g[t] + be[t];
  }
}

// ---------------------------------------------------------------------------
extern "C" void kernel_launch(void* const* d_in, const int* in_sizes, int n_in,
                              void* d_out, int out_size, void* d_ws, size_t ws_size,
                              hipStream_t stream) {
  const float* x    = (const float*)d_in[0];
  const int*   ei   = (const int*)  d_in[1];
  const float* ew   = (const float*)d_in[2];
  const float* Wl0  = (const float*)d_in[3];
  const float* bl0  = (const float*)d_in[4];
  const float* Wr0  = (const float*)d_in[5];
  const float* br0  = (const float*)d_in[6];
  const float* We0  = (const float*)d_in[7];
  const float* att0 = (const float*)d_in[8];
  const float* b0   = (const float*)d_in[9];
  const float* g0   = (const float*)d_in[10];
  const float* be0  = (const float*)d_in[11];
  const float* Wl1  = (const float*)d_in[12];
  const float* bl1  = (const float*)d_in[13];
  const float* Wr1  = (const float*)d_in[14];
  const float* br1  = (const float*)d_in[15];
  const float* We1  = (const float*)d_in[16];
  const float* att1 = (const float*)d_in[17];
  const float* b1   = (const float*)d_in[18];
  const float* g1   = (const float*)d_in[19];
  const float* be1  = (const float*)d_in[20];
  const float* P0   = (const float*)d_in[21];
  const float* pb0  = (const float*)d_in[22];
  const float* P1   = (const float*)d_in[23];
  const float* pb1  = (const float*)d_in[24];
  float* out = (float*)d_out;

  // workspace layout (32-bit words)
  float* f        = (float*)d_ws;
  float* s_loopw  = f;                               // 50176
  int*   deg      = (int*)(f + 50176);               // 50176
  int*   cursor   = (int*)(f + 100352);              // 50176
  int*   part     = (int*)(f + 150528);              // 50176
  int*   bsum     = (int*)(f + 200704);              // 256
  int*   csrc     = (int*)(f + 200960);              // 400384
  float* cw       = f + 601344;                      // 400384
  unsigned short* wl0T = (unsigned short*)(f + 1001728);  //  8192 w
  unsigned short* wr0T = (unsigned short*)(f + 1009920);  //  8192 w
  unsigned short* p0T  = (unsigned short*)(f + 1018112);  //  8192 w
  unsigned short* wl1T = (unsigned short*)(f + 1026304);  // 16384 w
  unsigned short* wr1T = (unsigned short*)(f + 1042688);  // 16384 w
  unsigned short* p1T  = (unsigned short*)(f + 1059072);  //  4096 w
  unsigned short* xb   = (unsigned short*)(f + 1063168);  // 3.2M w (x bf16)
  unsigned short* hb   = (unsigned short*)(f + 4263168);  // 3.2M w (h bf16)
  float*          hres = f + 7463168;                     // 6.4M w (x@P0+pb0)
  unsigned short* RA   = (unsigned short*)(f + 13863168); // 6.4M w
  unsigned short* RB   = (unsigned short*)(f + 20263168); // 6.4M w
  unsigned short* xl0b = RA, *xr0b = RB;   // 50000x128 bf16
  unsigned short* xl1b = RA, *xr1b = RB;   // 50000x256 bf16 (alias after agg0)

  // ---- CSR build ---------------------------------------------------------
  hipMemsetAsync(s_loopw, 0, (size_t)(50176 * 3) * sizeof(float), stream);
  deg_kernel<<<(N_EDGES + 255) / 256, 256, 0, stream>>>(ei, ew, s_loopw, deg);
  loopw_kernel<<<(N_NODES + 255) / 256, 256, 0, stream>>>(s_loopw, deg);
  scan1<<<NPAD / 256, 256, 0, stream>>>(deg, part, bsum);
  scan2<<<1, 256, 0, stream>>>(bsum);
  scatter_kernel<<<(N_EDGES + 255) / 256, 256, 0, stream>>>(ei, ew, part, bsum,
                                                            cursor, csrc, cw);

  // ---- precision prep ----------------------------------------------------
  cvt_bf16<<<(N_NODES * 128 / 4 + 255) / 256, 256, 0, stream>>>(x, xb, N_NODES * 128 / 4);
  pack_w<<<960, 128, 0, stream>>>(Wl0, Wr0, P0, Wl1, Wr1, P1,
                                  wl0T, wr0T, p0T, wl1T, wr1T, p1T);

  // ---- layer 0 -----------------------------------------------------------
  const int GB = (N_NODES + 63) / 64;
  gemm_mfma<128, true ><<<GB, 256, 0, stream>>>(xb, wl0T, bl0, xl0b, N_NODES);
  gemm_mfma<128, true ><<<GB, 256, 0, stream>>>(xb, wr0T, br0, xr0b, N_NODES);
  gemm_mfma<128, false><<<GB, 256, 0, stream>>>(xb, p0T,  pb0, hres, N_NODES);
  agg0<<<N_NODES, 128, 0, stream>>>(part, bsum, deg, csrc, cw, s_loopw,
                                    xl0b, xr0b, We0, att0, b0, g0, be0, hres, hb);

  // ---- layer 1 -----------------------------------------------------------
  gemm_mfma<256, true ><<<GB, 256, 0, stream>>>(hb, wl1T, bl1, xl1b, N_NODES);
  gemm_mfma<256, true ><<<GB, 256, 0, stream>>>(hb, wr1T, br1, xr1b, N_NODES);
  gemm_mfma<64,  false><<<GB, 256, 0, stream>>>(hb, p1T,  pb1, out,  N_NODES);
  agg1<<<N_NODES, 256, 0, stream>>>(part, bsum, deg, csrc, cw, s_loopw,
                                    xl1b, xr1b, We1, att1, b1, g1, be1, out);
}

// Round 4
// 331.825 us; speedup vs baseline: 3.5649x; 1.4956x over previous
//
#include <hip/hip_runtime.h>
#include <math.h>

#define N_NODES 50000
#define N_EDGES 400000
#define NPAD    50176            // 196*256
#define HC0 128
#define HC1 256

typedef short bf16x8 __attribute__((ext_vector_type(8)));
typedef float f32x4  __attribute__((ext_vector_type(4)));

__device__ inline unsigned short f2bf(float f) {
  union { float f; unsigned u; } v; v.f = f;
  unsigned r = v.u + 0x7FFFu + ((v.u >> 16) & 1u);   // RNE
  return (unsigned short)(r >> 16);
}
__device__ inline float bf2f(unsigned short h) {
  union { unsigned u; float f; } v; v.u = ((unsigned)h) << 16;
  return v.f;
}

// ---------------------------------------------------------------------------
// CSR build
// ---------------------------------------------------------------------------
__global__ void deg_kernel(const int* __restrict__ ei, const float* __restrict__ ew,
                           float* __restrict__ s, int* __restrict__ deg) {
  int e = blockIdx.x * 256 + threadIdx.x;
  if (e < N_EDGES) {
    int dst = ei[N_EDGES + e];
    atomicAdd(&s[dst], ew[e]);
    atomicAdd(&deg[dst], 1);
  }
}

__global__ void loopw_kernel(float* __restrict__ s, const int* __restrict__ deg) {
  int i = blockIdx.x * 256 + threadIdx.x;
  if (i < N_NODES) s[i] = s[i] / fmaxf((float)deg[i], 1.0f);
}

__global__ void scan1(const int* __restrict__ deg, int* __restrict__ part,
                      int* __restrict__ bsum) {
  int i = blockIdx.x * 256 + threadIdx.x;
  int lane = threadIdx.x & 63, wid = threadIdx.x >> 6;
  int v = deg[i];
  int inc = v;
#pragma unroll
  for (int d = 1; d < 64; d <<= 1) { int y = __shfl_up(inc, d, 64); if (lane >= d) inc += y; }
  __shared__ int wsum[4];
  if (lane == 63) wsum[wid] = inc;
  __syncthreads();
  int off = 0;
#pragma unroll
  for (int w = 0; w < 4; ++w) { int sv = wsum[w]; if (w < wid) off += sv; }
  part[i] = inc - v + off;
  if (threadIdx.x == 0) bsum[blockIdx.x] = wsum[0] + wsum[1] + wsum[2] + wsum[3];
}

__global__ void scan2(int* __restrict__ bsum) {
  int t = threadIdx.x;
  int lane = t & 63, wid = t >> 6;
  int v = (t < 196) ? bsum[t] : 0;
  int inc = v;
#pragma unroll
  for (int d = 1; d < 64; d <<= 1) { int y = __shfl_up(inc, d, 64); if (lane >= d) inc += y; }
  __shared__ int wsum[4];
  if (lane == 63) wsum[wid] = inc;
  __syncthreads();
  int off = 0;
#pragma unroll
  for (int w = 0; w < 4; ++w) { int sv = wsum[w]; if (w < wid) off += sv; }
  if (t < 196) bsum[t] = inc - v + off;
}

__global__ void scatter_kernel(const int* __restrict__ ei, const float* __restrict__ ew,
                               const int* __restrict__ part, const int* __restrict__ bsum,
                               int* __restrict__ cursor,
                               int* __restrict__ csrc, float* __restrict__ cw) {
  int e = blockIdx.x * 256 + threadIdx.x;
  if (e >= N_EDGES) return;
  int dst = ei[N_EDGES + e];
  int pos = atomicAdd(&cursor[dst], 1);
  int idx = part[dst] + bsum[dst >> 8] + pos;
  csrc[idx] = ei[e];
  cw[idx]  = ew[e];
}

// ---------------------------------------------------------------------------
// fp32 -> bf16 (vectorized)
// ---------------------------------------------------------------------------
__global__ void cvt_bf16(const float* __restrict__ in, unsigned short* __restrict__ out,
                         int n4) {
  int i = blockIdx.x * 256 + threadIdx.x;
  if (i >= n4) return;
  float4 v = ((const float4*)in)[i];
  ushort4 o; o.x = f2bf(v.x); o.y = f2bf(v.y); o.z = f2bf(v.z); o.w = f2bf(v.w);
  ((ushort4*)out)[i] = o;
}

// ---------------------------------------------------------------------------
// weight pack: W[128][N] fp32 -> BT[N][128] bf16
// ---------------------------------------------------------------------------
__global__ void pack_w(const float* __restrict__ Wl0, const float* __restrict__ Wr0,
                       const float* __restrict__ P0,  const float* __restrict__ Wl1,
                       const float* __restrict__ Wr1, const float* __restrict__ P1,
                       unsigned short* __restrict__ o_wl0, unsigned short* __restrict__ o_wr0,
                       unsigned short* __restrict__ o_p0,  unsigned short* __restrict__ o_wl1,
                       unsigned short* __restrict__ o_wr1, unsigned short* __restrict__ o_p1) {
  int n = blockIdx.x, k = threadIdx.x;
  const float* W; unsigned short* O; int N, nl;
  if      (n < 128) { W = Wl0; O = o_wl0; N = 128; nl = n; }
  else if (n < 256) { W = Wr0; O = o_wr0; N = 128; nl = n - 128; }
  else if (n < 384) { W = P0;  O = o_p0;  N = 128; nl = n - 256; }
  else if (n < 640) { W = Wl1; O = o_wl1; N = 256; nl = n - 384; }
  else if (n < 896) { W = Wr1; O = o_wr1; N = 256; nl = n - 640; }
  else              { W = P1;  O = o_p1;  N = 64;  nl = n - 896; }
  O[nl * 128 + k] = f2bf(W[(size_t)k * N + nl]);
}

// ---------------------------------------------------------------------------
// Merged MFMA GEMM, layer 0: C[M][384] = A[M][128] @ BT^T, split stores:
// cols 0-127 -> xl bf16, 128-255 -> xr bf16, 256-383 -> hres fp32.
// ---------------------------------------------------------------------------
__global__ __launch_bounds__(256) void gemm_l0(
    const unsigned short* __restrict__ A, const unsigned short* __restrict__ BT,
    const float* __restrict__ bias0, const float* __restrict__ bias1,
    const float* __restrict__ bias2,
    unsigned short* __restrict__ o_xl, unsigned short* __restrict__ o_xr,
    float* __restrict__ o_h, int M) {
  const int w  = threadIdx.x >> 6, l = threadIdx.x & 63;
  const int lr = l & 15, lg = l >> 4;
  const int r0 = blockIdx.x * 64 + w * 16;
  int ar = r0 + lr; if (ar > M - 1) ar = M - 1;
  const bf16x8* ap = (const bf16x8*)(A + (size_t)ar * 128 + lg * 8);
  bf16x8 a0 = ap[0], a1 = ap[4], a2 = ap[8], a3 = ap[12];
#pragma unroll
  for (int ct = 0; ct < 24; ++ct) {
    const bf16x8* bp = (const bf16x8*)(BT + ((size_t)(ct * 16 + lr)) * 128 + lg * 8);
    bf16x8 b0 = bp[0], b1 = bp[4], b2 = bp[8], b3 = bp[12];
    f32x4 acc = {0.f, 0.f, 0.f, 0.f};
    acc = __builtin_amdgcn_mfma_f32_16x16x32_bf16(a0, b0, acc, 0, 0, 0);
    acc = __builtin_amdgcn_mfma_f32_16x16x32_bf16(a1, b1, acc, 0, 0, 0);
    acc = __builtin_amdgcn_mfma_f32_16x16x32_bf16(a2, b2, acc, 0, 0, 0);
    acc = __builtin_amdgcn_mfma_f32_16x16x32_bf16(a3, b3, acc, 0, 0, 0);
    const int col = ct * 16 + lr, cc = col & 127;
    const float bv = (ct < 8 ? bias0 : (ct < 16 ? bias1 : bias2))[cc];
#pragma unroll
    for (int q = 0; q < 4; ++q) {
      int row = r0 + lg * 4 + q;
      if (row < M) {
        float o = acc[q] + bv;
        if      (ct < 8)  o_xl[(size_t)row * 128 + cc] = f2bf(o);
        else if (ct < 16) o_xr[(size_t)row * 128 + cc] = f2bf(o);
        else              o_h [(size_t)row * 128 + cc] = o;
      }
    }
  }
}

// ---------------------------------------------------------------------------
// Merged MFMA GEMM, layer 1: C[M][576]: 0-255 -> xl bf16, 256-511 -> xr bf16,
// 512-575 -> out fp32 (residual h@P1+pb1).
// ---------------------------------------------------------------------------
__global__ __launch_bounds__(256) void gemm_l1(
    const unsigned short* __restrict__ A, const unsigned short* __restrict__ BT,
    const float* __restrict__ bias0, const float* __restrict__ bias1,
    const float* __restrict__ bias2,
    unsigned short* __restrict__ o_xl, unsigned short* __restrict__ o_xr,
    float* __restrict__ o_out, int M) {
  const int w  = threadIdx.x >> 6, l = threadIdx.x & 63;
  const int lr = l & 15, lg = l >> 4;
  const int r0 = blockIdx.x * 64 + w * 16;
  int ar = r0 + lr; if (ar > M - 1) ar = M - 1;
  const bf16x8* ap = (const bf16x8*)(A + (size_t)ar * 128 + lg * 8);
  bf16x8 a0 = ap[0], a1 = ap[4], a2 = ap[8], a3 = ap[12];
#pragma unroll
  for (int ct = 0; ct < 36; ++ct) {
    const bf16x8* bp = (const bf16x8*)(BT + ((size_t)(ct * 16 + lr)) * 128 + lg * 8);
    bf16x8 b0 = bp[0], b1 = bp[4], b2 = bp[8], b3 = bp[12];
    f32x4 acc = {0.f, 0.f, 0.f, 0.f};
    acc = __builtin_amdgcn_mfma_f32_16x16x32_bf16(a0, b0, acc, 0, 0, 0);
    acc = __builtin_amdgcn_mfma_f32_16x16x32_bf16(a1, b1, acc, 0, 0, 0);
    acc = __builtin_amdgcn_mfma_f32_16x16x32_bf16(a2, b2, acc, 0, 0, 0);
    acc = __builtin_amdgcn_mfma_f32_16x16x32_bf16(a3, b3, acc, 0, 0, 0);
    const int col = ct * 16 + lr;
    const int cc  = (ct < 32) ? (col & 255) : (col - 512);
    const float bv = (ct < 16 ? bias0 : (ct < 32 ? bias1 : bias2))[cc];
#pragma unroll
    for (int q = 0; q < 4; ++q) {
      int row = r0 + lg * 4 + q;
      if (row < M) {
        float o = acc[q] + bv;
        if      (ct < 16) o_xl [(size_t)row * 256 + cc] = f2bf(o);
        else if (ct < 32) o_xr [(size_t)row * 256 + cc] = f2bf(o);
        else              o_out[(size_t)row * 64  + cc] = o;
      }
    }
  }
}

// ---------------------------------------------------------------------------
// Layer-0 aggregation: 1 wave/node (4 nodes per 256-block).
// Lane l: edge-slot grp=l>>4 (4 edges in parallel), channels (l&15)*8..+7.
// Head = 32 ch = 4 lanes -> 2 shfl per 4 edges. bf16x8 gathers.
// ---------------------------------------------------------------------------
__global__ __launch_bounds__(256) void agg0(
    const int* __restrict__ part, const int* __restrict__ bsum,
    const int* __restrict__ deg, const int* __restrict__ csrc,
    const float* __restrict__ cw, const float* __restrict__ loop_w,
    const unsigned short* __restrict__ xl, const unsigned short* __restrict__ xr,
    const float* __restrict__ We, const float* __restrict__ att,
    const float* __restrict__ b, const float* __restrict__ g,
    const float* __restrict__ be, const float* __restrict__ hres,
    unsigned short* __restrict__ hout) {
  const int wid = threadIdx.x >> 6, l = threadIdx.x & 63;
  const int n = blockIdx.x * 4 + wid;          // 12500*4 = 50000 exact
  const int grp = l >> 4, cl = l & 15, c0 = cl * 8;
  float xrv[8], wef[8], attf[8];
  {
    bf16x8 x8 = *(const bf16x8*)(xr + (size_t)n * HC0 + c0);
    float4 w0 = *(const float4*)(We + c0),  w1 = *(const float4*)(We + c0 + 4);
    float4 t0 = *(const float4*)(att + c0), t1 = *(const float4*)(att + c0 + 4);
    wef[0]=w0.x; wef[1]=w0.y; wef[2]=w0.z; wef[3]=w0.w;
    wef[4]=w1.x; wef[5]=w1.y; wef[6]=w1.z; wef[7]=w1.w;
    attf[0]=t0.x; attf[1]=t0.y; attf[2]=t0.z; attf[3]=t0.w;
    attf[4]=t1.x; attf[5]=t1.y; attf[6]=t1.z; attf[7]=t1.w;
#pragma unroll
    for (int j = 0; j < 8; ++j) xrv[j] = bf2f((unsigned short)x8[j]);
  }
  const int start = part[n] + bsum[n >> 8];
  const int cnt   = deg[n] + 1;                // + self loop
  float acc[8] = {0,0,0,0,0,0,0,0}, den = 0.f;
  const int iters = (cnt + 3) >> 2;
  for (int kk = 0; kk < iters; ++kk) {
    int e = kk * 4 + grp;
    bool valid = e < cnt;
    int src; float w;
    if (e == 0)      { src = n; w = loop_w[n]; }
    else if (valid)  { src = csrc[start + e - 1]; w = cw[start + e - 1]; }
    else             { src = n; w = 0.f; }
    bf16x8 a8 = *(const bf16x8*)(xl + (size_t)src * HC0 + c0);
    float av[8], c = 0.f;
#pragma unroll
    for (int j = 0; j < 8; ++j) {
      av[j] = bf2f((unsigned short)a8[j]);
      float sv = av[j] + xrv[j] + w * wef[j];
      float lk = fmaxf(sv, 0.2f * sv);          // leaky_relu(0.2)
      c = fmaf(lk, attf[j], c);
    }
    c += __shfl_xor(c, 1, 64); c += __shfl_xor(c, 2, 64);
    float p = valid ? __expf(c) : 0.f;
    den += p;
#pragma unroll
    for (int j = 0; j < 8; ++j) acc[j] = fmaf(p, av[j], acc[j]);
  }
  den += __shfl_xor(den, 16, 64); den += __shfl_xor(den, 32, 64);
#pragma unroll
  for (int j = 0; j < 8; ++j) {
    acc[j] += __shfl_xor(acc[j], 16, 64);
    acc[j] += __shfl_xor(acc[j], 32, 64);
  }
  // epilogue: all lanes hold combined sums; LN over 128 ch (16 lanes x 8)
  float v[8], s1 = 0.f, s2 = 0.f;
  float dinv = 1.f / den;
  {
    float4 b0v = *(const float4*)(b + c0), b1v = *(const float4*)(b + c0 + 4);
    float bb[8] = {b0v.x,b0v.y,b0v.z,b0v.w,b1v.x,b1v.y,b1v.z,b1v.w};
#pragma unroll
    for (int j = 0; j < 8; ++j) {
      float t = acc[j] * dinv + bb[j];
      t = t > 0.f ? t : __expf(t) - 1.f;        // ELU
      v[j] = t; s1 += t; s2 += t * t;
    }
  }
  s1 += __shfl_xor(s1, 1, 64); s2 += __shfl_xor(s2, 1, 64);
  s1 += __shfl_xor(s1, 2, 64); s2 += __shfl_xor(s2, 2, 64);
  s1 += __shfl_xor(s1, 4, 64); s2 += __shfl_xor(s2, 4, 64);
  s1 += __shfl_xor(s1, 8, 64); s2 += __shfl_xor(s2, 8, 64);
  float mean = s1 * (1.f / 128.f);
  float inv  = rsqrtf(s2 * (1.f / 128.f) - mean * mean + 1e-5f);
  if (grp == 0) {
    float4 g0v = *(const float4*)(g + c0),  g1v = *(const float4*)(g + c0 + 4);
    float4 e0v = *(const float4*)(be + c0), e1v = *(const float4*)(be + c0 + 4);
    float4 h0v = *(const float4*)(hres + (size_t)n * HC0 + c0);
    float4 h1v = *(const float4*)(hres + (size_t)n * HC0 + c0 + 4);
    float gg[8] = {g0v.x,g0v.y,g0v.z,g0v.w,g1v.x,g1v.y,g1v.z,g1v.w};
    float ee[8] = {e0v.x,e0v.y,e0v.z,e0v.w,e1v.x,e1v.y,e1v.z,e1v.w};
    float hh[8] = {h0v.x,h0v.y,h0v.z,h0v.w,h1v.x,h1v.y,h1v.z,h1v.w};
    bf16x8 o;
#pragma unroll
    for (int j = 0; j < 8; ++j)
      o[j] = (short)f2bf((v[j] - mean) * inv * gg[j] + ee[j] + hh[j]);
    *(bf16x8*)(hout + (size_t)n * HC0 + c0) = o;
  }
}

// ---------------------------------------------------------------------------
// Layer-1 aggregation: 1 wave/node. Lane l: edge-slot grp=l>>5 (2 edges),
// channels (l&31)*8..+7. Head = 64 ch = 8 lanes -> 3 shfl per 2 edges.
// Epilogue: mean over heads via LDS, LN(64), += residual in out.
// ---------------------------------------------------------------------------
__global__ __launch_bounds__(256) void agg1(
    const int* __restrict__ part, const int* __restrict__ bsum,
    const int* __restrict__ deg, const int* __restrict__ csrc,
    const float* __restrict__ cw, const float* __restrict__ loop_w,
    const unsigned short* __restrict__ xl, const unsigned short* __restrict__ xr,
    const float* __restrict__ We, const float* __restrict__ att,
    const float* __restrict__ b, const float* __restrict__ g,
    const float* __restrict__ be, float* __restrict__ out) {
  const int wid = threadIdx.x >> 6, l = threadIdx.x & 63;
  const int n = blockIdx.x * 4 + wid;
  const int grp = l >> 5, cl = l & 31, c0 = cl * 8;
  float xrv[8], wef[8], attf[8];
  {
    bf16x8 x8 = *(const bf16x8*)(xr + (size_t)n * HC1 + c0);
    float4 w0 = *(const float4*)(We + c0),  w1 = *(const float4*)(We + c0 + 4);
    float4 t0 = *(const float4*)(att + c0), t1 = *(const float4*)(att + c0 + 4);
    wef[0]=w0.x; wef[1]=w0.y; wef[2]=w0.z; wef[3]=w0.w;
    wef[4]=w1.x; wef[5]=w1.y; wef[6]=w1.z; wef[7]=w1.w;
    attf[0]=t0.x; attf[1]=t0.y; attf[2]=t0.z; attf[3]=t0.w;
    attf[4]=t1.x; attf[5]=t1.y; attf[6]=t1.z; attf[7]=t1.w;
#pragma unroll
    for (int j = 0; j < 8; ++j) xrv[j] = bf2f((unsigned short)x8[j]);
  }
  const int start = part[n] + bsum[n >> 8];
  const int cnt   = deg[n] + 1;
  float acc[8] = {0,0,0,0,0,0,0,0}, den = 0.f;
  const int iters = (cnt + 1) >> 1;
  for (int kk = 0; kk < iters; ++kk) {
    int e = kk * 2 + grp;
    bool valid = e < cnt;
    int src; float w;
    if (e == 0)      { src = n; w = loop_w[n]; }
    else if (valid)  { src = csrc[start + e - 1]; w = cw[start + e - 1]; }
    else             { src = n; w = 0.f; }
    bf16x8 a8 = *(const bf16x8*)(xl + (size_t)src * HC1 + c0);
    float av[8], c = 0.f;
#pragma unroll
    for (int j = 0; j < 8; ++j) {
      av[j] = bf2f((unsigned short)a8[j]);
      float sv = av[j] + xrv[j] + w * wef[j];
      float lk = fmaxf(sv, 0.2f * sv);
      c = fmaf(lk, attf[j], c);
    }
    c += __shfl_xor(c, 1, 64); c += __shfl_xor(c, 2, 64); c += __shfl_xor(c, 4, 64);
    float p = valid ? __expf(c) : 0.f;
    den += p;
#pragma unroll
    for (int j = 0; j < 8; ++j) acc[j] = fmaf(p, av[j], acc[j]);
  }
  den += __shfl_xor(den, 32, 64);
#pragma unroll
  for (int j = 0; j < 8; ++j) acc[j] += __shfl_xor(acc[j], 32, 64);
  // stage per-channel alpha-weighted sums, mean over heads, LN(64)
  __shared__ float lds[4][HC1];
  if (grp == 0) {
    float dinv = 1.f / den;
#pragma unroll
    for (int j = 0; j < 8; ++j) lds[wid][c0 + j] = acc[j] * dinv;
  }
  __syncthreads();
  float v = 0.25f * (lds[wid][l] + lds[wid][64 + l] + lds[wid][128 + l] +
                     lds[wid][192 + l]) + b[l];
  v = v > 0.f ? v : __expf(v) - 1.f;            // ELU
  float s1 = v, s2 = v * v;
#pragma unroll
  for (int o = 32; o > 0; o >>= 1) { s1 += __shfl_xor(s1, o, 64); s2 += __shfl_xor(s2, o, 64); }
  float mean = s1 * (1.f / 64.f);
  float inv  = rsqrtf(s2 * (1.f / 64.f) - mean * mean + 1e-5f);
  out[(size_t)n * 64 + l] += (v - mean) * inv * g[l] + be[l];
}

// ---------------------------------------------------------------------------
extern "C" void kernel_launch(void* const* d_in, const int* in_sizes, int n_in,
                              void* d_out, int out_size, void* d_ws, size_t ws_size,
                              hipStream_t stream) {
  const float* x    = (const float*)d_in[0];
  const int*   ei   = (const int*)  d_in[1];
  const float* ew   = (const float*)d_in[2];
  const float* Wl0  = (const float*)d_in[3];
  const float* bl0  = (const float*)d_in[4];
  const float* Wr0  = (const float*)d_in[5];
  const float* br0  = (const float*)d_in[6];
  const float* We0  = (const float*)d_in[7];
  const float* att0 = (const float*)d_in[8];
  const float* b0   = (const float*)d_in[9];
  const float* g0   = (const float*)d_in[10];
  const float* be0  = (const float*)d_in[11];
  const float* Wl1  = (const float*)d_in[12];
  const float* bl1  = (const float*)d_in[13];
  const float* Wr1  = (const float*)d_in[14];
  const float* br1  = (const float*)d_in[15];
  const float* We1  = (const float*)d_in[16];
  const float* att1 = (const float*)d_in[17];
  const float* b1   = (const float*)d_in[18];
  const float* g1   = (const float*)d_in[19];
  const float* be1  = (const float*)d_in[20];
  const float* P0   = (const float*)d_in[21];
  const float* pb0  = (const float*)d_in[22];
  const float* P1   = (const float*)d_in[23];
  const float* pb1  = (const float*)d_in[24];
  float* out = (float*)d_out;

  // workspace layout (32-bit words)
  float* f        = (float*)d_ws;
  float* s_loopw  = f;                               // 50176
  int*   deg      = (int*)(f + 50176);               // 50176
  int*   cursor   = (int*)(f + 100352);              // 50176
  int*   part     = (int*)(f + 150528);              // 50176
  int*   bsum     = (int*)(f + 200704);              // 256
  int*   csrc     = (int*)(f + 200960);              // 400384
  float* cw       = f + 601344;                      // 400384
  unsigned short* wl0T = (unsigned short*)(f + 1001728);  // 384x128 combined l0
  unsigned short* wr0T = wl0T + 16384;
  unsigned short* p0T  = wl0T + 32768;
  unsigned short* wl1T = (unsigned short*)(f + 1026304);  // 576x128 combined l1
  unsigned short* wr1T = wl1T + 32768;
  unsigned short* p1T  = wl1T + 65536;
  unsigned short* xb   = (unsigned short*)(f + 1063168);  // 50000x128 bf16
  unsigned short* hb   = (unsigned short*)(f + 4263168);  // 50000x128 bf16
  float*          hres = f + 7463168;                     // 50000x128 fp32
  unsigned short* RA   = (unsigned short*)(f + 13863168);
  unsigned short* RB   = (unsigned short*)(f + 20263168);
  unsigned short* xl0b = RA, *xr0b = RB;   // 50000x128 bf16
  unsigned short* xl1b = RA, *xr1b = RB;   // 50000x256 bf16 (alias after agg0)

  // ---- CSR build ---------------------------------------------------------
  hipMemsetAsync(s_loopw, 0, (size_t)(50176 * 3) * sizeof(float), stream);
  deg_kernel<<<(N_EDGES + 255) / 256, 256, 0, stream>>>(ei, ew, s_loopw, deg);
  loopw_kernel<<<(N_NODES + 255) / 256, 256, 0, stream>>>(s_loopw, deg);
  scan1<<<NPAD / 256, 256, 0, stream>>>(deg, part, bsum);
  scan2<<<1, 256, 0, stream>>>(bsum);
  scatter_kernel<<<(N_EDGES + 255) / 256, 256, 0, stream>>>(ei, ew, part, bsum,
                                                            cursor, csrc, cw);

  // ---- precision prep ----------------------------------------------------
  cvt_bf16<<<(N_NODES * 128 / 4 + 255) / 256, 256, 0, stream>>>(x, xb, N_NODES * 128 / 4);
  pack_w<<<960, 128, 0, stream>>>(Wl0, Wr0, P0, Wl1, Wr1, P1,
                                  wl0T, wr0T, p0T, wl1T, wr1T, p1T);

  // ---- layer 0 -----------------------------------------------------------
  const int GB = (N_NODES + 63) / 64;
  gemm_l0<<<GB, 256, 0, stream>>>(xb, wl0T, bl0, br0, pb0, xl0b, xr0b, hres, N_NODES);
  agg0<<<N_NODES / 4, 256, 0, stream>>>(part, bsum, deg, csrc, cw, s_loopw,
                                        xl0b, xr0b, We0, att0, b0, g0, be0, hres, hb);

  // ---- layer 1 -----------------------------------------------------------
  gemm_l1<<<GB, 256, 0, stream>>>(hb, wl1T, bl1, br1, pb1, xl1b, xr1b, out, N_NODES);
  agg1<<<N_NODES / 4, 256, 0, stream>>>(part, bsum, deg, csrc, cw, s_loopw,
                                        xl1b, xr1b, We1, att1, b1, g1, be1, out);
}

// Round 5
// 330.283 us; speedup vs baseline: 3.5816x; 1.0047x over previous
//
#include <hip/hip_runtime.h>
#include <math.h>

#define N_NODES 50000
#define N_EDGES 400000
#define NPAD    50176            // 196*256
#define HC0 128
#define HC1 256

typedef short bf16x8 __attribute__((ext_vector_type(8)));
typedef float f32x4  __attribute__((ext_vector_type(4)));

__device__ inline unsigned short f2bf(float f) {
  union { float f; unsigned u; } v; v.f = f;
  unsigned r = v.u + 0x7FFFu + ((v.u >> 16) & 1u);   // RNE
  return (unsigned short)(r >> 16);
}
__device__ inline float bf2f(unsigned short h) {
  union { unsigned u; float f; } v; v.u = ((unsigned)h) << 16;
  return v.f;
}

// ---------------------------------------------------------------------------
// CSR build
// ---------------------------------------------------------------------------
__global__ void deg_kernel(const int* __restrict__ ei, const float* __restrict__ ew,
                           float* __restrict__ s, int* __restrict__ deg) {
  int e = blockIdx.x * 256 + threadIdx.x;
  if (e < N_EDGES) {
    int dst = ei[N_EDGES + e];
    atomicAdd(&s[dst], ew[e]);
    atomicAdd(&deg[dst], 1);
  }
}

__global__ void loopw_kernel(float* __restrict__ s, const int* __restrict__ deg) {
  int i = blockIdx.x * 256 + threadIdx.x;
  if (i < N_NODES) s[i] = s[i] / fmaxf((float)deg[i], 1.0f);
}

__global__ void scan1(const int* __restrict__ deg, int* __restrict__ part,
                      int* __restrict__ bsum) {
  int i = blockIdx.x * 256 + threadIdx.x;
  int lane = threadIdx.x & 63, wid = threadIdx.x >> 6;
  int v = deg[i];
  int inc = v;
#pragma unroll
  for (int d = 1; d < 64; d <<= 1) { int y = __shfl_up(inc, d, 64); if (lane >= d) inc += y; }
  __shared__ int wsum[4];
  if (lane == 63) wsum[wid] = inc;
  __syncthreads();
  int off = 0;
#pragma unroll
  for (int w = 0; w < 4; ++w) { int sv = wsum[w]; if (w < wid) off += sv; }
  part[i] = inc - v + off;
  if (threadIdx.x == 0) bsum[blockIdx.x] = wsum[0] + wsum[1] + wsum[2] + wsum[3];
}

__global__ void scan2(int* __restrict__ bsum) {
  int t = threadIdx.x;
  int lane = t & 63, wid = t >> 6;
  int v = (t < 196) ? bsum[t] : 0;
  int inc = v;
#pragma unroll
  for (int d = 1; d < 64; d <<= 1) { int y = __shfl_up(inc, d, 64); if (lane >= d) inc += y; }
  __shared__ int wsum[4];
  if (lane == 63) wsum[wid] = inc;
  __syncthreads();
  int off = 0;
#pragma unroll
  for (int w = 0; w < 4; ++w) { int sv = wsum[w]; if (w < wid) off += sv; }
  if (t < 196) bsum[t] = inc - v + off;
}

__global__ void scatter_kernel(const int* __restrict__ ei, const float* __restrict__ ew,
                               const int* __restrict__ part, const int* __restrict__ bsum,
                               int* __restrict__ cursor,
                               int* __restrict__ csrc, float* __restrict__ cw) {
  int e = blockIdx.x * 256 + threadIdx.x;
  if (e >= N_EDGES) return;
  int dst = ei[N_EDGES + e];
  int pos = atomicAdd(&cursor[dst], 1);
  int idx = part[dst] + bsum[dst >> 8] + pos;
  csrc[idx] = ei[e];
  cw[idx]  = ew[e];
}

// ---------------------------------------------------------------------------
// fp32 -> bf16 (vectorized)
// ---------------------------------------------------------------------------
__global__ void cvt_bf16(const float* __restrict__ in, unsigned short* __restrict__ out,
                         int n4) {
  int i = blockIdx.x * 256 + threadIdx.x;
  if (i >= n4) return;
  float4 v = ((const float4*)in)[i];
  ushort4 o; o.x = f2bf(v.x); o.y = f2bf(v.y); o.z = f2bf(v.z); o.w = f2bf(v.w);
  ((ushort4*)out)[i] = o;
}

// ---------------------------------------------------------------------------
// weight pack: W[128][N] fp32 -> BT[N][128] bf16
// ---------------------------------------------------------------------------
__global__ void pack_w(const float* __restrict__ Wl0, const float* __restrict__ Wr0,
                       const float* __restrict__ P0,  const float* __restrict__ Wl1,
                       const float* __restrict__ Wr1, const float* __restrict__ P1,
                       unsigned short* __restrict__ o_wl0, unsigned short* __restrict__ o_wr0,
                       unsigned short* __restrict__ o_p0,  unsigned short* __restrict__ o_wl1,
                       unsigned short* __restrict__ o_wr1, unsigned short* __restrict__ o_p1) {
  int n = blockIdx.x, k = threadIdx.x;
  const float* W; unsigned short* O; int N, nl;
  if      (n < 128) { W = Wl0; O = o_wl0; N = 128; nl = n; }
  else if (n < 256) { W = Wr0; O = o_wr0; N = 128; nl = n - 128; }
  else if (n < 384) { W = P0;  O = o_p0;  N = 128; nl = n - 256; }
  else if (n < 640) { W = Wl1; O = o_wl1; N = 256; nl = n - 384; }
  else if (n < 896) { W = Wr1; O = o_wr1; N = 256; nl = n - 640; }
  else              { W = P1;  O = o_p1;  N = 64;  nl = n - 896; }
  O[nl * 128 + k] = f2bf(W[(size_t)k * N + nl]);
}

// ---------------------------------------------------------------------------
// Merged MFMA GEMM, layer 0: C[M][384] = A[M][128] @ BT^T.
// Block = 64 rows; each wave holds ALL 4 row-tiles of A in regs and owns
// 6 of the 24 col-tiles -> per ct: 4 B-loads feed 16 MFMAs (4 indep chains).
// cols 0-127 -> xl bf16, 128-255 -> xr bf16, 256-383 -> hres fp32.
// ---------------------------------------------------------------------------
__global__ __launch_bounds__(256) void gemm_l0(
    const unsigned short* __restrict__ A, const unsigned short* __restrict__ BT,
    const float* __restrict__ bias0, const float* __restrict__ bias1,
    const float* __restrict__ bias2,
    unsigned short* __restrict__ o_xl, unsigned short* __restrict__ o_xr,
    float* __restrict__ o_h, int M) {
  const int w  = threadIdx.x >> 6, l = threadIdx.x & 63;
  const int lr = l & 15, lg = l >> 4;
  const int rbase = blockIdx.x * 64;
  bf16x8 a[4][4];
#pragma unroll
  for (int rt = 0; rt < 4; ++rt) {
    int ar = rbase + rt * 16 + lr; if (ar > M - 1) ar = M - 1;
    const bf16x8* ap = (const bf16x8*)(A + (size_t)ar * 128 + lg * 8);
#pragma unroll
    for (int k = 0; k < 4; ++k) a[rt][k] = ap[k * 4];
  }
#pragma unroll
  for (int i = 0; i < 6; ++i) {
    const int ct = w * 6 + i;
    const bf16x8* bp = (const bf16x8*)(BT + (size_t)(ct * 16 + lr) * 128 + lg * 8);
    bf16x8 b0 = bp[0], b1 = bp[4], b2 = bp[8], b3 = bp[12];
    f32x4 acc[4];
#pragma unroll
    for (int rt = 0; rt < 4; ++rt) acc[rt] = f32x4{0.f, 0.f, 0.f, 0.f};
#pragma unroll
    for (int rt = 0; rt < 4; ++rt)
      acc[rt] = __builtin_amdgcn_mfma_f32_16x16x32_bf16(a[rt][0], b0, acc[rt], 0, 0, 0);
#pragma unroll
    for (int rt = 0; rt < 4; ++rt)
      acc[rt] = __builtin_amdgcn_mfma_f32_16x16x32_bf16(a[rt][1], b1, acc[rt], 0, 0, 0);
#pragma unroll
    for (int rt = 0; rt < 4; ++rt)
      acc[rt] = __builtin_amdgcn_mfma_f32_16x16x32_bf16(a[rt][2], b2, acc[rt], 0, 0, 0);
#pragma unroll
    for (int rt = 0; rt < 4; ++rt)
      acc[rt] = __builtin_amdgcn_mfma_f32_16x16x32_bf16(a[rt][3], b3, acc[rt], 0, 0, 0);
    const int col = ct * 16 + lr, cc = col & 127;
    const float bv = (ct < 8 ? bias0 : (ct < 16 ? bias1 : bias2))[cc];
#pragma unroll
    for (int rt = 0; rt < 4; ++rt) {
#pragma unroll
      for (int q = 0; q < 4; ++q) {
        int row = rbase + rt * 16 + lg * 4 + q;
        if (row < M) {
          float o = acc[rt][q] + bv;
          if      (ct < 8)  o_xl[(size_t)row * 128 + cc] = f2bf(o);
          else if (ct < 16) o_xr[(size_t)row * 128 + cc] = f2bf(o);
          else              o_h [(size_t)row * 128 + cc] = o;
        }
      }
    }
  }
}

// ---------------------------------------------------------------------------
// Merged MFMA GEMM, layer 1: C[M][576]; same structure, 9 col-tiles/wave.
// cols 0-255 -> xl bf16, 256-511 -> xr bf16, 512-575 -> out fp32.
// ---------------------------------------------------------------------------
__global__ __launch_bounds__(256) void gemm_l1(
    const unsigned short* __restrict__ A, const unsigned short* __restrict__ BT,
    const float* __restrict__ bias0, const float* __restrict__ bias1,
    const float* __restrict__ bias2,
    unsigned short* __restrict__ o_xl, unsigned short* __restrict__ o_xr,
    float* __restrict__ o_out, int M) {
  const int w  = threadIdx.x >> 6, l = threadIdx.x & 63;
  const int lr = l & 15, lg = l >> 4;
  const int rbase = blockIdx.x * 64;
  bf16x8 a[4][4];
#pragma unroll
  for (int rt = 0; rt < 4; ++rt) {
    int ar = rbase + rt * 16 + lr; if (ar > M - 1) ar = M - 1;
    const bf16x8* ap = (const bf16x8*)(A + (size_t)ar * 128 + lg * 8);
#pragma unroll
    for (int k = 0; k < 4; ++k) a[rt][k] = ap[k * 4];
  }
#pragma unroll
  for (int i = 0; i < 9; ++i) {
    const int ct = w * 9 + i;
    const bf16x8* bp = (const bf16x8*)(BT + (size_t)(ct * 16 + lr) * 128 + lg * 8);
    bf16x8 b0 = bp[0], b1 = bp[4], b2 = bp[8], b3 = bp[12];
    f32x4 acc[4];
#pragma unroll
    for (int rt = 0; rt < 4; ++rt) acc[rt] = f32x4{0.f, 0.f, 0.f, 0.f};
#pragma unroll
    for (int rt = 0; rt < 4; ++rt)
      acc[rt] = __builtin_amdgcn_mfma_f32_16x16x32_bf16(a[rt][0], b0, acc[rt], 0, 0, 0);
#pragma unroll
    for (int rt = 0; rt < 4; ++rt)
      acc[rt] = __builtin_amdgcn_mfma_f32_16x16x32_bf16(a[rt][1], b1, acc[rt], 0, 0, 0);
#pragma unroll
    for (int rt = 0; rt < 4; ++rt)
      acc[rt] = __builtin_amdgcn_mfma_f32_16x16x32_bf16(a[rt][2], b2, acc[rt], 0, 0, 0);
#pragma unroll
    for (int rt = 0; rt < 4; ++rt)
      acc[rt] = __builtin_amdgcn_mfma_f32_16x16x32_bf16(a[rt][3], b3, acc[rt], 0, 0, 0);
    const int col = ct * 16 + lr;
    const int cc  = (ct < 32) ? (col & 255) : (col - 512);
    const float bv = (ct < 16 ? bias0 : (ct < 32 ? bias1 : bias2))[cc];
#pragma unroll
    for (int rt = 0; rt < 4; ++rt) {
#pragma unroll
      for (int q = 0; q < 4; ++q) {
        int row = rbase + rt * 16 + lg * 4 + q;
        if (row < M) {
          float o = acc[rt][q] + bv;
          if      (ct < 16) o_xl [(size_t)row * 256 + cc] = f2bf(o);
          else if (ct < 32) o_xr [(size_t)row * 256 + cc] = f2bf(o);
          else              o_out[(size_t)row * 64  + cc] = o;
        }
      }
    }
  }
}

// ---------------------------------------------------------------------------
// Layer-0 aggregation: 1 wave/node (4 nodes per 256-block).
// ---------------------------------------------------------------------------
__global__ __launch_bounds__(256) void agg0(
    const int* __restrict__ part, const int* __restrict__ bsum,
    const int* __restrict__ deg, const int* __restrict__ csrc,
    const float* __restrict__ cw, const float* __restrict__ loop_w,
    const unsigned short* __restrict__ xl, const unsigned short* __restrict__ xr,
    const float* __restrict__ We, const float* __restrict__ att,
    const float* __restrict__ b, const float* __restrict__ g,
    const float* __restrict__ be, const float* __restrict__ hres,
    unsigned short* __restrict__ hout) {
  const int wid = threadIdx.x >> 6, l = threadIdx.x & 63;
  const int n = blockIdx.x * 4 + wid;
  const int grp = l >> 4, cl = l & 15, c0 = cl * 8;
  float xrv[8], wef[8], attf[8];
  {
    bf16x8 x8 = *(const bf16x8*)(xr + (size_t)n * HC0 + c0);
    float4 w0 = *(const float4*)(We + c0),  w1 = *(const float4*)(We + c0 + 4);
    float4 t0 = *(const float4*)(att + c0), t1 = *(const float4*)(att + c0 + 4);
    wef[0]=w0.x; wef[1]=w0.y; wef[2]=w0.z; wef[3]=w0.w;
    wef[4]=w1.x; wef[5]=w1.y; wef[6]=w1.z; wef[7]=w1.w;
    attf[0]=t0.x; attf[1]=t0.y; attf[2]=t0.z; attf[3]=t0.w;
    attf[4]=t1.x; attf[5]=t1.y; attf[6]=t1.z; attf[7]=t1.w;
#pragma unroll
    for (int j = 0; j < 8; ++j) xrv[j] = bf2f((unsigned short)x8[j]);
  }
  const int start = part[n] + bsum[n >> 8];
  const int cnt   = deg[n] + 1;
  float acc[8] = {0,0,0,0,0,0,0,0}, den = 0.f;
  const int iters = (cnt + 3) >> 2;
  for (int kk = 0; kk < iters; ++kk) {
    int e = kk * 4 + grp;
    bool valid = e < cnt;
    int src; float w;
    if (e == 0)      { src = n; w = loop_w[n]; }
    else if (valid)  { src = csrc[start + e - 1]; w = cw[start + e - 1]; }
    else             { src = n; w = 0.f; }
    bf16x8 a8 = *(const bf16x8*)(xl + (size_t)src * HC0 + c0);
    float av[8], c = 0.f;
#pragma unroll
    for (int j = 0; j < 8; ++j) {
      av[j] = bf2f((unsigned short)a8[j]);
      float sv = av[j] + xrv[j] + w * wef[j];
      float lk = fmaxf(sv, 0.2f * sv);
      c = fmaf(lk, attf[j], c);
    }
    c += __shfl_xor(c, 1, 64); c += __shfl_xor(c, 2, 64);
    float p = valid ? __expf(c) : 0.f;
    den += p;
#pragma unroll
    for (int j = 0; j < 8; ++j) acc[j] = fmaf(p, av[j], acc[j]);
  }
  den += __shfl_xor(den, 16, 64); den += __shfl_xor(den, 32, 64);
#pragma unroll
  for (int j = 0; j < 8; ++j) {
    acc[j] += __shfl_xor(acc[j], 16, 64);
    acc[j] += __shfl_xor(acc[j], 32, 64);
  }
  float v[8], s1 = 0.f, s2 = 0.f;
  float dinv = 1.f / den;
  {
    float4 b0v = *(const float4*)(b + c0), b1v = *(const float4*)(b + c0 + 4);
    float bb[8] = {b0v.x,b0v.y,b0v.z,b0v.w,b1v.x,b1v.y,b1v.z,b1v.w};
#pragma unroll
    for (int j = 0; j < 8; ++j) {
      float t = acc[j] * dinv + bb[j];
      t = t > 0.f ? t : __expf(t) - 1.f;
      v[j] = t; s1 += t; s2 += t * t;
    }
  }
  s1 += __shfl_xor(s1, 1, 64); s2 += __shfl_xor(s2, 1, 64);
  s1 += __shfl_xor(s1, 2, 64); s2 += __shfl_xor(s2, 2, 64);
  s1 += __shfl_xor(s1, 4, 64); s2 += __shfl_xor(s2, 4, 64);
  s1 += __shfl_xor(s1, 8, 64); s2 += __shfl_xor(s2, 8, 64);
  float mean = s1 * (1.f / 128.f);
  float inv  = rsqrtf(s2 * (1.f / 128.f) - mean * mean + 1e-5f);
  if (grp == 0) {
    float4 g0v = *(const float4*)(g + c0),  g1v = *(const float4*)(g + c0 + 4);
    float4 e0v = *(const float4*)(be + c0), e1v = *(const float4*)(be + c0 + 4);
    float4 h0v = *(const float4*)(hres + (size_t)n * HC0 + c0);
    float4 h1v = *(const float4*)(hres + (size_t)n * HC0 + c0 + 4);
    float gg[8] = {g0v.x,g0v.y,g0v.z,g0v.w,g1v.x,g1v.y,g1v.z,g1v.w};
    float ee[8] = {e0v.x,e0v.y,e0v.z,e0v.w,e1v.x,e1v.y,e1v.z,e1v.w};
    float hh[8] = {h0v.x,h0v.y,h0v.z,h0v.w,h1v.x,h1v.y,h1v.z,h1v.w};
    bf16x8 o;
#pragma unroll
    for (int j = 0; j < 8; ++j)
      o[j] = (short)f2bf((v[j] - mean) * inv * gg[j] + ee[j] + hh[j]);
    *(bf16x8*)(hout + (size_t)n * HC0 + c0) = o;
  }
}

// ---------------------------------------------------------------------------
// Layer-1 aggregation: 1 wave/node; 2 edges in parallel.
// ---------------------------------------------------------------------------
__global__ __launch_bounds__(256) void agg1(
    const int* __restrict__ part, const int* __restrict__ bsum,
    const int* __restrict__ deg, const int* __restrict__ csrc,
    const float* __restrict__ cw, const float* __restrict__ loop_w,
    const unsigned short* __restrict__ xl, const unsigned short* __restrict__ xr,
    const float* __restrict__ We, const float* __restrict__ att,
    const float* __restrict__ b, const float* __restrict__ g,
    const float* __restrict__ be, float* __restrict__ out) {
  const int wid = threadIdx.x >> 6, l = threadIdx.x & 63;
  const int n = blockIdx.x * 4 + wid;
  const int grp = l >> 5, cl = l & 31, c0 = cl * 8;
  float xrv[8], wef[8], attf[8];
  {
    bf16x8 x8 = *(const bf16x8*)(xr + (size_t)n * HC1 + c0);
    float4 w0 = *(const float4*)(We + c0),  w1 = *(const float4*)(We + c0 + 4);
    float4 t0 = *(const float4*)(att + c0), t1 = *(const float4*)(att + c0 + 4);
    wef[0]=w0.x; wef[1]=w0.y; wef[2]=w0.z; wef[3]=w0.w;
    wef[4]=w1.x; wef[5]=w1.y; wef[6]=w1.z; wef[7]=w1.w;
    attf[0]=t0.x; attf[1]=t0.y; attf[2]=t0.z; attf[3]=t0.w;
    attf[4]=t1.x; attf[5]=t1.y; attf[6]=t1.z; attf[7]=t1.w;
#pragma unroll
    for (int j = 0; j < 8; ++j) xrv[j] = bf2f((unsigned short)x8[j]);
  }
  const int start = part[n] + bsum[n >> 8];
  const int cnt   = deg[n] + 1;
  float acc[8] = {0,0,0,0,0,0,0,0}, den = 0.f;
  const int iters = (cnt + 1) >> 1;
  for (int kk = 0; kk < iters; ++kk) {
    int e = kk * 2 + grp;
    bool valid = e < cnt;
    int src; float w;
    if (e == 0)      { src = n; w = loop_w[n]; }
    else if (valid)  { src = csrc[start + e - 1]; w = cw[start + e - 1]; }
    else             { src = n; w = 0.f; }
    bf16x8 a8 = *(const bf16x8*)(xl + (size_t)src * HC1 + c0);
    float av[8], c = 0.f;
#pragma unroll
    for (int j = 0; j < 8; ++j) {
      av[j] = bf2f((unsigned short)a8[j]);
      float sv = av[j] + xrv[j] + w * wef[j];
      float lk = fmaxf(sv, 0.2f * sv);
      c = fmaf(lk, attf[j], c);
    }
    c += __shfl_xor(c, 1, 64); c += __shfl_xor(c, 2, 64); c += __shfl_xor(c, 4, 64);
    float p = valid ? __expf(c) : 0.f;
    den += p;
#pragma unroll
    for (int j = 0; j < 8; ++j) acc[j] = fmaf(p, av[j], acc[j]);
  }
  den += __shfl_xor(den, 32, 64);
#pragma unroll
  for (int j = 0; j < 8; ++j) acc[j] += __shfl_xor(acc[j], 32, 64);
  __shared__ float lds[4][HC1];
  if (grp == 0) {
    float dinv = 1.f / den;
#pragma unroll
    for (int j = 0; j < 8; ++j) lds[wid][c0 + j] = acc[j] * dinv;
  }
  __syncthreads();
  float v = 0.25f * (lds[wid][l] + lds[wid][64 + l] + lds[wid][128 + l] +
                     lds[wid][192 + l]) + b[l];
  v = v > 0.f ? v : __expf(v) - 1.f;
  float s1 = v, s2 = v * v;
#pragma unroll
  for (int o = 32; o > 0; o >>= 1) { s1 += __shfl_xor(s1, o, 64); s2 += __shfl_xor(s2, o, 64); }
  float mean = s1 * (1.f / 64.f);
  float inv  = rsqrtf(s2 * (1.f / 64.f) - mean * mean + 1e-5f);
  out[(size_t)n * 64 + l] += (v - mean) * inv * g[l] + be[l];
}

// ---------------------------------------------------------------------------
extern "C" void kernel_launch(void* const* d_in, const int* in_sizes, int n_in,
                              void* d_out, int out_size, void* d_ws, size_t ws_size,
                              hipStream_t stream) {
  const float* x    = (const float*)d_in[0];
  const int*   ei   = (const int*)  d_in[1];
  const float* ew   = (const float*)d_in[2];
  const float* Wl0  = (const float*)d_in[3];
  const float* bl0  = (const float*)d_in[4];
  const float* Wr0  = (const float*)d_in[5];
  const float* br0  = (const float*)d_in[6];
  const float* We0  = (const float*)d_in[7];
  const float* att0 = (const float*)d_in[8];
  const float* b0   = (const float*)d_in[9];
  const float* g0   = (const float*)d_in[10];
  const float* be0  = (const float*)d_in[11];
  const float* Wl1  = (const float*)d_in[12];
  const float* bl1  = (const float*)d_in[13];
  const float* Wr1  = (const float*)d_in[14];
  const float* br1  = (const float*)d_in[15];
  const float* We1  = (const float*)d_in[16];
  const float* att1 = (const float*)d_in[17];
  const float* b1   = (const float*)d_in[18];
  const float* g1   = (const float*)d_in[19];
  const float* be1  = (const float*)d_in[20];
  const float* P0   = (const float*)d_in[21];
  const float* pb0  = (const float*)d_in[22];
  const float* P1   = (const float*)d_in[23];
  const float* pb1  = (const float*)d_in[24];
  float* out = (float*)d_out;

  // workspace layout (32-bit words)
  float* f        = (float*)d_ws;
  float* s_loopw  = f;                               // 50176
  int*   deg      = (int*)(f + 50176);               // 50176
  int*   cursor   = (int*)(f + 100352);              // 50176
  int*   part     = (int*)(f + 150528);               // 50176
  int*   bsum     = (int*)(f + 200704);              // 256
  int*   csrc     = (int*)(f + 200960);              // 400384
  float* cw       = f + 601344;                      // 400384
  unsigned short* wl0T = (unsigned short*)(f + 1001728);  // 384x128 combined l0
  unsigned short* wr0T = wl0T + 16384;
  unsigned short* p0T  = wl0T + 32768;
  unsigned short* wl1T = (unsigned short*)(f + 1026304);  // 576x128 combined l1
  unsigned short* wr1T = wl1T + 32768;
  unsigned short* p1T  = wl1T + 65536;
  unsigned short* xb   = (unsigned short*)(f + 1063168);  // 50000x128 bf16
  unsigned short* hb   = (unsigned short*)(f + 4263168);  // 50000x128 bf16
  float*          hres = f + 7463168;                     // 50000x128 fp32
  unsigned short* RA   = (unsigned short*)(f + 13863168);
  unsigned short* RB   = (unsigned short*)(f + 20263168);
  unsigned short* xl0b = RA, *xr0b = RB;   // 50000x128 bf16
  unsigned short* xl1b = RA, *xr1b = RB;   // 50000x256 bf16 (alias after agg0)

  // ---- CSR build ---------------------------------------------------------
  hipMemsetAsync(s_loopw, 0, (size_t)(50176 * 3) * sizeof(float), stream);
  deg_kernel<<<(N_EDGES + 255) / 256, 256, 0, stream>>>(ei, ew, s_loopw, deg);
  loopw_kernel<<<(N_NODES + 255) / 256, 256, 0, stream>>>(s_loopw, deg);
  scan1<<<NPAD / 256, 256, 0, stream>>>(deg, part, bsum);
  scan2<<<1, 256, 0, stream>>>(bsum);
  scatter_kernel<<<(N_EDGES + 255) / 256, 256, 0, stream>>>(ei, ew, part, bsum,
                                                            cursor, csrc, cw);

  // ---- precision prep ----------------------------------------------------
  cvt_bf16<<<(N_NODES * 128 / 4 + 255) / 256, 256, 0, stream>>>(x, xb, N_NODES * 128 / 4);
  pack_w<<<960, 128, 0, stream>>>(Wl0, Wr0, P0, Wl1, Wr1, P1,
                                  wl0T, wr0T, p0T, wl1T, wr1T, p1T);

  // ---- layer 0 -----------------------------------------------------------
  const int GB = (N_NODES + 63) / 64;
  gemm_l0<<<GB, 256, 0, stream>>>(xb, wl0T, bl0, br0, pb0, xl0b, xr0b, hres, N_NODES);
  agg0<<<N_NODES / 4, 256, 0, stream>>>(part, bsum, deg, csrc, cw, s_loopw,
                                        xl0b, xr0b, We0, att0, b0, g0, be0, hres, hb);

  // ---- layer 1 -----------------------------------------------------------
  gemm_l1<<<GB, 256, 0, stream>>>(hb, wl1T, bl1, br1, pb1, xl1b, xr1b, out, N_NODES);
  agg1<<<N_NODES / 4, 256, 0, stream>>>(part, bsum, deg, csrc, cw, s_loopw,
                                        xl1b, xr1b, We1, att1, b1, g1, be1, out);
}

// Round 6
// 262.417 us; speedup vs baseline: 4.5078x; 1.2586x over previous
//
#include <hip/hip_runtime.h>
#include <math.h>

#define N_NODES 50000
#define N_EDGES 400000
#define NPAD    50176            // 196*256
#define MROWS   50048            // 782*64, padded row count for gemm outputs
#define HC0 128
#define HC1 256

typedef short bf16x8 __attribute__((ext_vector_type(8)));
typedef float f32x4  __attribute__((ext_vector_type(4)));

__device__ inline unsigned short f2bf(float f) {
  union { float f; unsigned u; } v; v.f = f;
  unsigned r = v.u + 0x7FFFu + ((v.u >> 16) & 1u);   // RNE
  return (unsigned short)(r >> 16);
}
__device__ inline float bf2f(unsigned short h) {
  union { unsigned u; float f; } v; v.u = ((unsigned)h) << 16;
  return v.f;
}

// ---------------------------------------------------------------------------
// CSR build
// ---------------------------------------------------------------------------
__global__ void deg_kernel(const int* __restrict__ ei, const float* __restrict__ ew,
                           float* __restrict__ s, int* __restrict__ deg) {
  int e = blockIdx.x * 256 + threadIdx.x;
  if (e < N_EDGES) {
    int dst = ei[N_EDGES + e];
    atomicAdd(&s[dst], ew[e]);
    atomicAdd(&deg[dst], 1);
  }
}

__global__ void loopw_kernel(float* __restrict__ s, const int* __restrict__ deg) {
  int i = blockIdx.x * 256 + threadIdx.x;
  if (i < N_NODES) s[i] = s[i] / fmaxf((float)deg[i], 1.0f);
}

__global__ void scan1(const int* __restrict__ deg, int* __restrict__ part,
                      int* __restrict__ bsum) {
  int i = blockIdx.x * 256 + threadIdx.x;
  int lane = threadIdx.x & 63, wid = threadIdx.x >> 6;
  int v = deg[i];
  int inc = v;
#pragma unroll
  for (int d = 1; d < 64; d <<= 1) { int y = __shfl_up(inc, d, 64); if (lane >= d) inc += y; }
  __shared__ int wsum[4];
  if (lane == 63) wsum[wid] = inc;
  __syncthreads();
  int off = 0;
#pragma unroll
  for (int w = 0; w < 4; ++w) { int sv = wsum[w]; if (w < wid) off += sv; }
  part[i] = inc - v + off;
  if (threadIdx.x == 0) bsum[blockIdx.x] = wsum[0] + wsum[1] + wsum[2] + wsum[3];
}

__global__ void scan2(int* __restrict__ bsum) {
  int t = threadIdx.x;
  int lane = t & 63, wid = t >> 6;
  int v = (t < 196) ? bsum[t] : 0;
  int inc = v;
#pragma unroll
  for (int d = 1; d < 64; d <<= 1) { int y = __shfl_up(inc, d, 64); if (lane >= d) inc += y; }
  __shared__ int wsum[4];
  if (lane == 63) wsum[wid] = inc;
  __syncthreads();
  int off = 0;
#pragma unroll
  for (int w = 0; w < 4; ++w) { int sv = wsum[w]; if (w < wid) off += sv; }
  if (t < 196) bsum[t] = inc - v + off;
}

__global__ void scatter_kernel(const int* __restrict__ ei, const float* __restrict__ ew,
                               const int* __restrict__ part, const int* __restrict__ bsum,
                               int* __restrict__ cursor,
                               int* __restrict__ csrc, float* __restrict__ cw) {
  int e = blockIdx.x * 256 + threadIdx.x;
  if (e >= N_EDGES) return;
  int dst = ei[N_EDGES + e];
  int pos = atomicAdd(&cursor[dst], 1);
  int idx = part[dst] + bsum[dst >> 8] + pos;
  csrc[idx] = ei[e];
  cw[idx]  = ew[e];
}

// ---------------------------------------------------------------------------
// fp32 -> bf16 (vectorized)
// ---------------------------------------------------------------------------
__global__ void cvt_bf16(const float* __restrict__ in, unsigned short* __restrict__ out,
                         int n4) {
  int i = blockIdx.x * 256 + threadIdx.x;
  if (i >= n4) return;
  float4 v = ((const float4*)in)[i];
  ushort4 o; o.x = f2bf(v.x); o.y = f2bf(v.y); o.z = f2bf(v.z); o.w = f2bf(v.w);
  ((ushort4*)out)[i] = o;
}

// ---------------------------------------------------------------------------
// weight pack: W[128][N] fp32 -> BT[N][128] bf16
// ---------------------------------------------------------------------------
__global__ void pack_w(const float* __restrict__ Wl0, const float* __restrict__ Wr0,
                       const float* __restrict__ P0,  const float* __restrict__ Wl1,
                       const float* __restrict__ Wr1, const float* __restrict__ P1,
                       unsigned short* __restrict__ o_wl0, unsigned short* __restrict__ o_wr0,
                       unsigned short* __restrict__ o_p0,  unsigned short* __restrict__ o_wl1,
                       unsigned short* __restrict__ o_wr1, unsigned short* __restrict__ o_p1) {
  int n = blockIdx.x, k = threadIdx.x;
  const float* W; unsigned short* O; int N, nl;
  if      (n < 128) { W = Wl0; O = o_wl0; N = 128; nl = n; }
  else if (n < 256) { W = Wr0; O = o_wr0; N = 128; nl = n - 128; }
  else if (n < 384) { W = P0;  O = o_p0;  N = 128; nl = n - 256; }
  else if (n < 640) { W = Wl1; O = o_wl1; N = 256; nl = n - 384; }
  else if (n < 896) { W = Wr1; O = o_wr1; N = 256; nl = n - 640; }
  else              { W = P1;  O = o_p1;  N = 64;  nl = n - 896; }
  O[nl * 128 + k] = f2bf(W[(size_t)k * N + nl]);
}

// ---------------------------------------------------------------------------
// Merged GEMM layer 0: C[M][384] = A[M][128] @ BT^T.
// Block = 64 rows. A-tile staged in LDS (row pitch 272B: +16B pad -> ~2-way
// banks). Wave owns 6 col-tiles; per ct: 4 B-loads (L2-hot) feed 4 indep
// rt-chains of {4 ds_read_b128 + 4 MFMA}. MFMA operands SWAPPED ->
// lane holds row=..+lr, cols=ct*16+lg*4..+3 -> vectorized ushort4/float4 store.
// cols 0-127 -> xl bf16, 128-255 -> xr bf16, 256-383 -> hres fp32.
// ---------------------------------------------------------------------------
__global__ __launch_bounds__(256) void gemm_l0(
    const unsigned short* __restrict__ A, const unsigned short* __restrict__ BT,
    const float* __restrict__ bias0, const float* __restrict__ bias1,
    const float* __restrict__ bias2,
    unsigned short* __restrict__ o_xl, unsigned short* __restrict__ o_xr,
    float* __restrict__ o_h, int M) {
  __shared__ unsigned short As[64 * 136];   // 272B pitch
  const int tid = threadIdx.x;
  const int rbase = blockIdx.x * 64;
#pragma unroll
  for (int i = 0; i < 4; ++i) {
    int c = i * 256 + tid;                  // 1024 chunks of 16B
    int row = c >> 4, slot = c & 15;
    int ar = rbase + row; if (ar > M - 1) ar = M - 1;
    uint4 v = *(const uint4*)(A + (size_t)ar * 128 + slot * 8);
    *(uint4*)(As + row * 136 + slot * 8) = v;
  }
  __syncthreads();
  const int w = tid >> 6, l = tid & 63;
  const int lr = l & 15, lg = l >> 4;
#pragma unroll
  for (int i = 0; i < 6; ++i) {
    const int ct = w * 6 + i;
    const bf16x8* bp = (const bf16x8*)(BT + (size_t)(ct * 16 + lr) * 128 + lg * 8);
    bf16x8 b0 = bp[0], b1 = bp[4], b2 = bp[8], b3 = bp[12];
    const int colb = ct * 16 + lg * 4;
    const int cc = colb & 127;
    const float* bptr = (ct < 8 ? bias0 : (ct < 16 ? bias1 : bias2));
    float4 bv = *(const float4*)(bptr + cc);
#pragma unroll
    for (int rt = 0; rt < 4; ++rt) {
      const unsigned short* ap = As + (rt * 16 + lr) * 136 + lg * 8;
      bf16x8 a0 = *(const bf16x8*)(ap);
      bf16x8 a1 = *(const bf16x8*)(ap + 32);
      bf16x8 a2 = *(const bf16x8*)(ap + 64);
      bf16x8 a3 = *(const bf16x8*)(ap + 96);
      f32x4 acc = {0.f, 0.f, 0.f, 0.f};
      acc = __builtin_amdgcn_mfma_f32_16x16x32_bf16(b0, a0, acc, 0, 0, 0);
      acc = __builtin_amdgcn_mfma_f32_16x16x32_bf16(b1, a1, acc, 0, 0, 0);
      acc = __builtin_amdgcn_mfma_f32_16x16x32_bf16(b2, a2, acc, 0, 0, 0);
      acc = __builtin_amdgcn_mfma_f32_16x16x32_bf16(b3, a3, acc, 0, 0, 0);
      const int row = rbase + rt * 16 + lr;
      if (ct < 16) {
        ushort4 o;
        o.x = f2bf(acc[0] + bv.x); o.y = f2bf(acc[1] + bv.y);
        o.z = f2bf(acc[2] + bv.z); o.w = f2bf(acc[3] + bv.w);
        *(ushort4*)((ct < 8 ? o_xl : o_xr) + (size_t)row * 128 + cc) = o;
      } else {
        float4 o;
        o.x = acc[0] + bv.x; o.y = acc[1] + bv.y;
        o.z = acc[2] + bv.z; o.w = acc[3] + bv.w;
        *(float4*)(o_h + (size_t)row * 128 + cc) = o;
      }
    }
  }
}

// ---------------------------------------------------------------------------
// Merged GEMM layer 1: C[M][576]; 9 col-tiles/wave, same structure.
// cols 0-255 -> xl bf16, 256-511 -> xr bf16, 512-575 -> out fp32 (guarded).
// ---------------------------------------------------------------------------
__global__ __launch_bounds__(256) void gemm_l1(
    const unsigned short* __restrict__ A, const unsigned short* __restrict__ BT,
    const float* __restrict__ bias0, const float* __restrict__ bias1,
    const float* __restrict__ bias2,
    unsigned short* __restrict__ o_xl, unsigned short* __restrict__ o_xr,
    float* __restrict__ o_out, int M) {
  __shared__ unsigned short As[64 * 136];
  const int tid = threadIdx.x;
  const int rbase = blockIdx.x * 64;
#pragma unroll
  for (int i = 0; i < 4; ++i) {
    int c = i * 256 + tid;
    int row = c >> 4, slot = c & 15;
    int ar = rbase + row; if (ar > M - 1) ar = M - 1;
    uint4 v = *(const uint4*)(A + (size_t)ar * 128 + slot * 8);
    *(uint4*)(As + row * 136 + slot * 8) = v;
  }
  __syncthreads();
  const int w = tid >> 6, l = tid & 63;
  const int lr = l & 15, lg = l >> 4;
#pragma unroll
  for (int i = 0; i < 9; ++i) {
    const int ct = w * 9 + i;
    const bf16x8* bp = (const bf16x8*)(BT + (size_t)(ct * 16 + lr) * 128 + lg * 8);
    bf16x8 b0 = bp[0], b1 = bp[4], b2 = bp[8], b3 = bp[12];
    const int colb = ct * 16 + lg * 4;
    const int cc = (ct < 32) ? (colb & 255) : (colb - 512);
    const float* bptr = (ct < 16 ? bias0 : (ct < 32 ? bias1 : bias2));
    float4 bv = *(const float4*)(bptr + cc);
#pragma unroll
    for (int rt = 0; rt < 4; ++rt) {
      const unsigned short* ap = As + (rt * 16 + lr) * 136 + lg * 8;
      bf16x8 a0 = *(const bf16x8*)(ap);
      bf16x8 a1 = *(const bf16x8*)(ap + 32);
      bf16x8 a2 = *(const bf16x8*)(ap + 64);
      bf16x8 a3 = *(const bf16x8*)(ap + 96);
      f32x4 acc = {0.f, 0.f, 0.f, 0.f};
      acc = __builtin_amdgcn_mfma_f32_16x16x32_bf16(b0, a0, acc, 0, 0, 0);
      acc = __builtin_amdgcn_mfma_f32_16x16x32_bf16(b1, a1, acc, 0, 0, 0);
      acc = __builtin_amdgcn_mfma_f32_16x16x32_bf16(b2, a2, acc, 0, 0, 0);
      acc = __builtin_amdgcn_mfma_f32_16x16x32_bf16(b3, a3, acc, 0, 0, 0);
      const int row = rbase + rt * 16 + lr;
      if (ct < 32) {
        ushort4 o;
        o.x = f2bf(acc[0] + bv.x); o.y = f2bf(acc[1] + bv.y);
        o.z = f2bf(acc[2] + bv.z); o.w = f2bf(acc[3] + bv.w);
        *(ushort4*)((ct < 16 ? o_xl : o_xr) + (size_t)row * 256 + cc) = o;
      } else if (row < M) {
        float4 o;
        o.x = acc[0] + bv.x; o.y = acc[1] + bv.y;
        o.z = acc[2] + bv.z; o.w = acc[3] + bv.w;
        *(float4*)(o_out + (size_t)row * 64 + cc) = o;
      }
    }
  }
}

// ---------------------------------------------------------------------------
// Layer-0 aggregation: 1 wave/node (4 nodes per 256-block).
// ---------------------------------------------------------------------------
__global__ __launch_bounds__(256) void agg0(
    const int* __restrict__ part, const int* __restrict__ bsum,
    const int* __restrict__ deg, const int* __restrict__ csrc,
    const float* __restrict__ cw, const float* __restrict__ loop_w,
    const unsigned short* __restrict__ xl, const unsigned short* __restrict__ xr,
    const float* __restrict__ We, const float* __restrict__ att,
    const float* __restrict__ b, const float* __restrict__ g,
    const float* __restrict__ be, const float* __restrict__ hres,
    unsigned short* __restrict__ hout) {
  const int wid = threadIdx.x >> 6, l = threadIdx.x & 63;
  const int n = blockIdx.x * 4 + wid;
  const int grp = l >> 4, cl = l & 15, c0 = cl * 8;
  float xrv[8], wef[8], attf[8];
  {
    bf16x8 x8 = *(const bf16x8*)(xr + (size_t)n * HC0 + c0);
    float4 w0 = *(const float4*)(We + c0),  w1 = *(const float4*)(We + c0 + 4);
    float4 t0 = *(const float4*)(att + c0), t1 = *(const float4*)(att + c0 + 4);
    wef[0]=w0.x; wef[1]=w0.y; wef[2]=w0.z; wef[3]=w0.w;
    wef[4]=w1.x; wef[5]=w1.y; wef[6]=w1.z; wef[7]=w1.w;
    attf[0]=t0.x; attf[1]=t0.y; attf[2]=t0.z; attf[3]=t0.w;
    attf[4]=t1.x; attf[5]=t1.y; attf[6]=t1.z; attf[7]=t1.w;
#pragma unroll
    for (int j = 0; j < 8; ++j) xrv[j] = bf2f((unsigned short)x8[j]);
  }
  const int start = part[n] + bsum[n >> 8];
  const int cnt   = deg[n] + 1;
  float acc[8] = {0,0,0,0,0,0,0,0}, den = 0.f;
  const int iters = (cnt + 3) >> 2;
  for (int kk = 0; kk < iters; ++kk) {
    int e = kk * 4 + grp;
    bool valid = e < cnt;
    int src; float w;
    if (e == 0)      { src = n; w = loop_w[n]; }
    else if (valid)  { src = csrc[start + e - 1]; w = cw[start + e - 1]; }
    else             { src = n; w = 0.f; }
    bf16x8 a8 = *(const bf16x8*)(xl + (size_t)src * HC0 + c0);
    float av[8], c = 0.f;
#pragma unroll
    for (int j = 0; j < 8; ++j) {
      av[j] = bf2f((unsigned short)a8[j]);
      float sv = av[j] + xrv[j] + w * wef[j];
      float lk = fmaxf(sv, 0.2f * sv);
      c = fmaf(lk, attf[j], c);
    }
    c += __shfl_xor(c, 1, 64); c += __shfl_xor(c, 2, 64);
    float p = valid ? __expf(c) : 0.f;
    den += p;
#pragma unroll
    for (int j = 0; j < 8; ++j) acc[j] = fmaf(p, av[j], acc[j]);
  }
  den += __shfl_xor(den, 16, 64); den += __shfl_xor(den, 32, 64);
#pragma unroll
  for (int j = 0; j < 8; ++j) {
    acc[j] += __shfl_xor(acc[j], 16, 64);
    acc[j] += __shfl_xor(acc[j], 32, 64);
  }
  float v[8], s1 = 0.f, s2 = 0.f;
  float dinv = 1.f / den;
  {
    float4 b0v = *(const float4*)(b + c0), b1v = *(const float4*)(b + c0 + 4);
    float bb[8] = {b0v.x,b0v.y,b0v.z,b0v.w,b1v.x,b1v.y,b1v.z,b1v.w};
#pragma unroll
    for (int j = 0; j < 8; ++j) {
      float t = acc[j] * dinv + bb[j];
      t = t > 0.f ? t : __expf(t) - 1.f;
      v[j] = t; s1 += t; s2 += t * t;
    }
  }
  s1 += __shfl_xor(s1, 1, 64); s2 += __shfl_xor(s2, 1, 64);
  s1 += __shfl_xor(s1, 2, 64); s2 += __shfl_xor(s2, 2, 64);
  s1 += __shfl_xor(s1, 4, 64); s2 += __shfl_xor(s2, 4, 64);
  s1 += __shfl_xor(s1, 8, 64); s2 += __shfl_xor(s2, 8, 64);
  float mean = s1 * (1.f / 128.f);
  float inv  = rsqrtf(s2 * (1.f / 128.f) - mean * mean + 1e-5f);
  if (grp == 0) {
    float4 g0v = *(const float4*)(g + c0),  g1v = *(const float4*)(g + c0 + 4);
    float4 e0v = *(const float4*)(be + c0), e1v = *(const float4*)(be + c0 + 4);
    float4 h0v = *(const float4*)(hres + (size_t)n * HC0 + c0);
    float4 h1v = *(const float4*)(hres + (size_t)n * HC0 + c0 + 4);
    float gg[8] = {g0v.x,g0v.y,g0v.z,g0v.w,g1v.x,g1v.y,g1v.z,g1v.w};
    float ee[8] = {e0v.x,e0v.y,e0v.z,e0v.w,e1v.x,e1v.y,e1v.z,e1v.w};
    float hh[8] = {h0v.x,h0v.y,h0v.z,h0v.w,h1v.x,h1v.y,h1v.z,h1v.w};
    bf16x8 o;
#pragma unroll
    for (int j = 0; j < 8; ++j)
      o[j] = (short)f2bf((v[j] - mean) * inv * gg[j] + ee[j] + hh[j]);
    *(bf16x8*)(hout + (size_t)n * HC0 + c0) = o;
  }
}

// ---------------------------------------------------------------------------
// Layer-1 aggregation: 1 wave/node; 2 edges in parallel.
// ---------------------------------------------------------------------------
__global__ __launch_bounds__(256) void agg1(
    const int* __restrict__ part, const int* __restrict__ bsum,
    const int* __restrict__ deg, const int* __restrict__ csrc,
    const float* __restrict__ cw, const float* __restrict__ loop_w,
    const unsigned short* __restrict__ xl, const unsigned short* __restrict__ xr,
    const float* __restrict__ We, const float* __restrict__ att,
    const float* __restrict__ b, const float* __restrict__ g,
    const float* __restrict__ be, float* __restrict__ out) {
  const int wid = threadIdx.x >> 6, l = threadIdx.x & 63;
  const int n = blockIdx.x * 4 + wid;
  const int grp = l >> 5, cl = l & 31, c0 = cl * 8;
  float xrv[8], wef[8], attf[8];
  {
    bf16x8 x8 = *(const bf16x8*)(xr + (size_t)n * HC1 + c0);
    float4 w0 = *(const float4*)(We + c0),  w1 = *(const float4*)(We + c0 + 4);
    float4 t0 = *(const float4*)(att + c0), t1 = *(const float4*)(att + c0 + 4);
    wef[0]=w0.x; wef[1]=w0.y; wef[2]=w0.z; wef[3]=w0.w;
    wef[4]=w1.x; wef[5]=w1.y; wef[6]=w1.z; wef[7]=w1.w;
    attf[0]=t0.x; attf[1]=t0.y; attf[2]=t0.z; attf[3]=t0.w;
    attf[4]=t1.x; attf[5]=t1.y; attf[6]=t1.z; attf[7]=t1.w;
#pragma unroll
    for (int j = 0; j < 8; ++j) xrv[j] = bf2f((unsigned short)x8[j]);
  }
  const int start = part[n] + bsum[n >> 8];
  const int cnt   = deg[n] + 1;
  float acc[8] = {0,0,0,0,0,0,0,0}, den = 0.f;
  const int iters = (cnt + 1) >> 1;
  for (int kk = 0; kk < iters; ++kk) {
    int e = kk * 2 + grp;
    bool valid = e < cnt;
    int src; float w;
    if (e == 0)      { src = n; w = loop_w[n]; }
    else if (valid)  { src = csrc[start + e - 1]; w = cw[start + e - 1]; }
    else             { src = n; w = 0.f; }
    bf16x8 a8 = *(const bf16x8*)(xl + (size_t)src * HC1 + c0);
    float av[8], c = 0.f;
#pragma unroll
    for (int j = 0; j < 8; ++j) {
      av[j] = bf2f((unsigned short)a8[j]);
      float sv = av[j] + xrv[j] + w * wef[j];
      float lk = fmaxf(sv, 0.2f * sv);
      c = fmaf(lk, attf[j], c);
    }
    c += __shfl_xor(c, 1, 64); c += __shfl_xor(c, 2, 64); c += __shfl_xor(c, 4, 64);
    float p = valid ? __expf(c) : 0.f;
    den += p;
#pragma unroll
    for (int j = 0; j < 8; ++j) acc[j] = fmaf(p, av[j], acc[j]);
  }
  den += __shfl_xor(den, 32, 64);
#pragma unroll
  for (int j = 0; j < 8; ++j) acc[j] += __shfl_xor(acc[j], 32, 64);
  __shared__ float lds[4][HC1];
  if (grp == 0) {
    float dinv = 1.f / den;
#pragma unroll
    for (int j = 0; j < 8; ++j) lds[wid][c0 + j] = acc[j] * dinv;
  }
  __syncthreads();
  float v = 0.25f * (lds[wid][l] + lds[wid][64 + l] + lds[wid][128 + l] +
                     lds[wid][192 + l]) + b[l];
  v = v > 0.f ? v : __expf(v) - 1.f;
  float s1 = v, s2 = v * v;
#pragma unroll
  for (int o = 32; o > 0; o >>= 1) { s1 += __shfl_xor(s1, o, 64); s2 += __shfl_xor(s2, o, 64); }
  float mean = s1 * (1.f / 64.f);
  float inv  = rsqrtf(s2 * (1.f / 64.f) - mean * mean + 1e-5f);
  out[(size_t)n * 64 + l] += (v - mean) * inv * g[l] + be[l];
}

// ---------------------------------------------------------------------------
extern "C" void kernel_launch(void* const* d_in, const int* in_sizes, int n_in,
                              void* d_out, int out_size, void* d_ws, size_t ws_size,
                              hipStream_t stream) {
  const float* x    = (const float*)d_in[0];
  const int*   ei   = (const int*)  d_in[1];
  const float* ew   = (const float*)d_in[2];
  const float* Wl0  = (const float*)d_in[3];
  const float* bl0  = (const float*)d_in[4];
  const float* Wr0  = (const float*)d_in[5];
  const float* br0  = (const float*)d_in[6];
  const float* We0  = (const float*)d_in[7];
  const float* att0 = (const float*)d_in[8];
  const float* b0   = (const float*)d_in[9];
  const float* g0   = (const float*)d_in[10];
  const float* be0  = (const float*)d_in[11];
  const float* Wl1  = (const float*)d_in[12];
  const float* bl1  = (const float*)d_in[13];
  const float* Wr1  = (const float*)d_in[14];
  const float* br1  = (const float*)d_in[15];
  const float* We1  = (const float*)d_in[16];
  const float* att1 = (const float*)d_in[17];
  const float* b1   = (const float*)d_in[18];
  const float* g1   = (const float*)d_in[19];
  const float* be1  = (const float*)d_in[20];
  const float* P0   = (const float*)d_in[21];
  const float* pb0  = (const float*)d_in[22];
  const float* P1   = (const float*)d_in[23];
  const float* pb1  = (const float*)d_in[24];
  float* out = (float*)d_out;

  // workspace layout (32-bit words); gemm outputs padded to MROWS rows
  float* f        = (float*)d_ws;
  float* s_loopw  = f;                               // 50176
  int*   deg      = (int*)(f + 50176);               // 50176
  int*   cursor   = (int*)(f + 100352);              // 50176
  int*   part     = (int*)(f + 150528);              // 50176
  int*   bsum     = (int*)(f + 200704);              // 256
  int*   csrc     = (int*)(f + 200960);              // 400384
  float* cw       = f + 601344;                      // 400384
  unsigned short* wl0T = (unsigned short*)(f + 1001728);  // 384x128 combined l0
  unsigned short* wr0T = wl0T + 16384;
  unsigned short* p0T  = wl0T + 32768;
  unsigned short* wl1T = (unsigned short*)(f + 1026304);  // 576x128 combined l1
  unsigned short* wr1T = wl1T + 32768;
  unsigned short* p1T  = wl1T + 65536;
  unsigned short* xb   = (unsigned short*)(f + 1063168);  // MROWS x128 bf16
  unsigned short* hb   = (unsigned short*)(f + 4266240);  // MROWS x128 bf16
  float*          hres = f + 7469312;                     // MROWS x128 fp32
  unsigned short* RA   = (unsigned short*)(f + 13875456); // MROWS x256 bf16
  unsigned short* RB   = (unsigned short*)(f + 20281600); // MROWS x256 bf16
  unsigned short* xl0b = RA, *xr0b = RB;
  unsigned short* xl1b = RA, *xr1b = RB;

  // ---- CSR build ---------------------------------------------------------
  hipMemsetAsync(s_loopw, 0, (size_t)(50176 * 3) * sizeof(float), stream);
  deg_kernel<<<(N_EDGES + 255) / 256, 256, 0, stream>>>(ei, ew, s_loopw, deg);
  loopw_kernel<<<(N_NODES + 255) / 256, 256, 0, stream>>>(s_loopw, deg);
  scan1<<<NPAD / 256, 256, 0, stream>>>(deg, part, bsum);
  scan2<<<1, 256, 0, stream>>>(bsum);
  scatter_kernel<<<(N_EDGES + 255) / 256, 256, 0, stream>>>(ei, ew, part, bsum,
                                                            cursor, csrc, cw);

  // ---- precision prep ----------------------------------------------------
  cvt_bf16<<<(N_NODES * 128 / 4 + 255) / 256, 256, 0, stream>>>(x, xb, N_NODES * 128 / 4);
  pack_w<<<960, 128, 0, stream>>>(Wl0, Wr0, P0, Wl1, Wr1, P1,
                                  wl0T, wr0T, p0T, wl1T, wr1T, p1T);

  // ---- layer 0 -----------------------------------------------------------
  const int GB = MROWS / 64;   // 782
  gemm_l0<<<GB, 256, 0, stream>>>(xb, wl0T, bl0, br0, pb0, xl0b, xr0b, hres, N_NODES);
  agg0<<<N_NODES / 4, 256, 0, stream>>>(part, bsum, deg, csrc, cw, s_loopw,
                                        xl0b, xr0b, We0, att0, b0, g0, be0, hres, hb);

  // ---- layer 1 -----------------------------------------------------------
  gemm_l1<<<GB, 256, 0, stream>>>(hb, wl1T, bl1, br1, pb1, xl1b, xr1b, out, N_NODES);
  agg1<<<N_NODES / 4, 256, 0, stream>>>(part, bsum, deg, csrc, cw, s_loopw,
                                        xl1b, xr1b, We1, att1, b1, g1, be1, out);
}

// Round 7
// 247.337 us; speedup vs baseline: 4.7827x; 1.0610x over previous
//
#include <hip/hip_runtime.h>
#include <math.h>

#define N_NODES 50000
#define N_EDGES 400000
#define NPAD    50176            // 196*256
#define MROWS   50048            // 782*64, padded row count for gemm outputs
#define HC0 128
#define HC1 256

typedef short bf16x8 __attribute__((ext_vector_type(8)));
typedef float f32x4  __attribute__((ext_vector_type(4)));

__device__ inline unsigned short f2bf(float f) {
  union { float f; unsigned u; } v; v.f = f;
  unsigned r = v.u + 0x7FFFu + ((v.u >> 16) & 1u);   // RNE
  return (unsigned short)(r >> 16);
}
__device__ inline float bf2f(unsigned short h) {
  union { unsigned u; float f; } v; v.u = ((unsigned)h) << 16;
  return v.f;
}

// ---------------------------------------------------------------------------
// CSR build. Segment per node = 1 (self loop, slot 0) + deg entries of
// int2 {src, w_bits}. Scan is over deg+1.
// ---------------------------------------------------------------------------
__global__ void deg_kernel(const int* __restrict__ ei, const float* __restrict__ ew,
                           float* __restrict__ s, int* __restrict__ deg) {
  int e = blockIdx.x * 256 + threadIdx.x;
  if (e < N_EDGES) {
    int dst = ei[N_EDGES + e];
    atomicAdd(&s[dst], ew[e]);
    atomicAdd(&deg[dst], 1);
  }
}

__global__ void scan1(const int* __restrict__ deg, int* __restrict__ part,
                      int* __restrict__ bsum) {
  int i = blockIdx.x * 256 + threadIdx.x;
  int lane = threadIdx.x & 63, wid = threadIdx.x >> 6;
  int v = (i < N_NODES) ? deg[i] + 1 : 0;
  int inc = v;
#pragma unroll
  for (int d = 1; d < 64; d <<= 1) { int y = __shfl_up(inc, d, 64); if (lane >= d) inc += y; }
  __shared__ int wsum[4];
  if (lane == 63) wsum[wid] = inc;
  __syncthreads();
  int off = 0;
#pragma unroll
  for (int w = 0; w < 4; ++w) { int sv = wsum[w]; if (w < wid) off += sv; }
  part[i] = inc - v + off;
  if (threadIdx.x == 0) bsum[blockIdx.x] = wsum[0] + wsum[1] + wsum[2] + wsum[3];
}

__global__ void scan2(int* __restrict__ bsum) {
  int t = threadIdx.x;
  int lane = t & 63, wid = t >> 6;
  int v = (t < 196) ? bsum[t] : 0;
  int inc = v;
#pragma unroll
  for (int d = 1; d < 64; d <<= 1) { int y = __shfl_up(inc, d, 64); if (lane >= d) inc += y; }
  __shared__ int wsum[4];
  if (lane == 63) wsum[wid] = inc;
  __syncthreads();
  int off = 0;
#pragma unroll
  for (int w = 0; w < 4; ++w) { int sv = wsum[w]; if (w < wid) off += sv; }
  if (t < 196) bsum[t] = inc - v + off;
}

// self-loop weight (mean of incoming) -> csr2[start] record
__global__ void self_kernel(const float* __restrict__ s, const int* __restrict__ deg,
                            const int* __restrict__ part, const int* __restrict__ bsum,
                            int2* __restrict__ csr2) {
  int i = blockIdx.x * 256 + threadIdx.x;
  if (i >= N_NODES) return;
  float w = s[i] / fmaxf((float)deg[i], 1.0f);
  int start = part[i] + bsum[i >> 8];
  csr2[start] = make_int2(i, __float_as_int(w));
}

__global__ void scatter_kernel(const int* __restrict__ ei, const float* __restrict__ ew,
                               const int* __restrict__ part, const int* __restrict__ bsum,
                               int* __restrict__ cursor, int2* __restrict__ csr2) {
  int e = blockIdx.x * 256 + threadIdx.x;
  if (e >= N_EDGES) return;
  int dst = ei[N_EDGES + e];
  int pos = atomicAdd(&cursor[dst], 1);
  int idx = part[dst] + bsum[dst >> 8] + 1 + pos;
  csr2[idx] = make_int2(ei[e], __float_as_int(ew[e]));
}

// ---------------------------------------------------------------------------
// fp32 -> bf16 (vectorized)
// ---------------------------------------------------------------------------
__global__ void cvt_bf16(const float* __restrict__ in, unsigned short* __restrict__ out,
                         int n4) {
  int i = blockIdx.x * 256 + threadIdx.x;
  if (i >= n4) return;
  float4 v = ((const float4*)in)[i];
  ushort4 o; o.x = f2bf(v.x); o.y = f2bf(v.y); o.z = f2bf(v.z); o.w = f2bf(v.w);
  ((ushort4*)out)[i] = o;
}

// ---------------------------------------------------------------------------
// weight pack: W[128][N] fp32 -> BT[N][128] bf16
// ---------------------------------------------------------------------------
__global__ void pack_w(const float* __restrict__ Wl0, const float* __restrict__ Wr0,
                       const float* __restrict__ P0,  const float* __restrict__ Wl1,
                       const float* __restrict__ Wr1, const float* __restrict__ P1,
                       unsigned short* __restrict__ o_wl0, unsigned short* __restrict__ o_wr0,
                       unsigned short* __restrict__ o_p0,  unsigned short* __restrict__ o_wl1,
                       unsigned short* __restrict__ o_wr1, unsigned short* __restrict__ o_p1) {
  int n = blockIdx.x, k = threadIdx.x;
  const float* W; unsigned short* O; int N, nl;
  if      (n < 128) { W = Wl0; O = o_wl0; N = 128; nl = n; }
  else if (n < 256) { W = Wr0; O = o_wr0; N = 128; nl = n - 128; }
  else if (n < 384) { W = P0;  O = o_p0;  N = 128; nl = n - 256; }
  else if (n < 640) { W = Wl1; O = o_wl1; N = 256; nl = n - 384; }
  else if (n < 896) { W = Wr1; O = o_wr1; N = 256; nl = n - 640; }
  else              { W = P1;  O = o_p1;  N = 64;  nl = n - 896; }
  O[nl * 128 + k] = f2bf(W[(size_t)k * N + nl]);
}

// ---------------------------------------------------------------------------
// Merged GEMM layer 0 (unchanged from round 6).
// ---------------------------------------------------------------------------
__global__ __launch_bounds__(256) void gemm_l0(
    const unsigned short* __restrict__ A, const unsigned short* __restrict__ BT,
    const float* __restrict__ bias0, const float* __restrict__ bias1,
    const float* __restrict__ bias2,
    unsigned short* __restrict__ o_xl, unsigned short* __restrict__ o_xr,
    float* __restrict__ o_h, int M) {
  __shared__ unsigned short As[64 * 136];   // 272B pitch
  const int tid = threadIdx.x;
  const int rbase = blockIdx.x * 64;
#pragma unroll
  for (int i = 0; i < 4; ++i) {
    int c = i * 256 + tid;
    int row = c >> 4, slot = c & 15;
    int ar = rbase + row; if (ar > M - 1) ar = M - 1;
    uint4 v = *(const uint4*)(A + (size_t)ar * 128 + slot * 8);
    *(uint4*)(As + row * 136 + slot * 8) = v;
  }
  __syncthreads();
  const int w = tid >> 6, l = tid & 63;
  const int lr = l & 15, lg = l >> 4;
#pragma unroll
  for (int i = 0; i < 6; ++i) {
    const int ct = w * 6 + i;
    const bf16x8* bp = (const bf16x8*)(BT + (size_t)(ct * 16 + lr) * 128 + lg * 8);
    bf16x8 b0 = bp[0], b1 = bp[4], b2 = bp[8], b3 = bp[12];
    const int colb = ct * 16 + lg * 4;
    const int cc = colb & 127;
    const float* bptr = (ct < 8 ? bias0 : (ct < 16 ? bias1 : bias2));
    float4 bv = *(const float4*)(bptr + cc);
#pragma unroll
    for (int rt = 0; rt < 4; ++rt) {
      const unsigned short* ap = As + (rt * 16 + lr) * 136 + lg * 8;
      bf16x8 a0 = *(const bf16x8*)(ap);
      bf16x8 a1 = *(const bf16x8*)(ap + 32);
      bf16x8 a2 = *(const bf16x8*)(ap + 64);
      bf16x8 a3 = *(const bf16x8*)(ap + 96);
      f32x4 acc = {0.f, 0.f, 0.f, 0.f};
      acc = __builtin_amdgcn_mfma_f32_16x16x32_bf16(b0, a0, acc, 0, 0, 0);
      acc = __builtin_amdgcn_mfma_f32_16x16x32_bf16(b1, a1, acc, 0, 0, 0);
      acc = __builtin_amdgcn_mfma_f32_16x16x32_bf16(b2, a2, acc, 0, 0, 0);
      acc = __builtin_amdgcn_mfma_f32_16x16x32_bf16(b3, a3, acc, 0, 0, 0);
      const int row = rbase + rt * 16 + lr;
      if (ct < 16) {
        ushort4 o;
        o.x = f2bf(acc[0] + bv.x); o.y = f2bf(acc[1] + bv.y);
        o.z = f2bf(acc[2] + bv.z); o.w = f2bf(acc[3] + bv.w);
        *(ushort4*)((ct < 8 ? o_xl : o_xr) + (size_t)row * 128 + cc) = o;
      } else {
        float4 o;
        o.x = acc[0] + bv.x; o.y = acc[1] + bv.y;
        o.z = acc[2] + bv.z; o.w = acc[3] + bv.w;
        *(float4*)(o_h + (size_t)row * 128 + cc) = o;
      }
    }
  }
}

// ---------------------------------------------------------------------------
// Merged GEMM layer 1 (unchanged from round 6).
// ---------------------------------------------------------------------------
__global__ __launch_bounds__(256) void gemm_l1(
    const unsigned short* __restrict__ A, const unsigned short* __restrict__ BT,
    const float* __restrict__ bias0, const float* __restrict__ bias1,
    const float* __restrict__ bias2,
    unsigned short* __restrict__ o_xl, unsigned short* __restrict__ o_xr,
    float* __restrict__ o_out, int M) {
  __shared__ unsigned short As[64 * 136];
  const int tid = threadIdx.x;
  const int rbase = blockIdx.x * 64;
#pragma unroll
  for (int i = 0; i < 4; ++i) {
    int c = i * 256 + tid;
    int row = c >> 4, slot = c & 15;
    int ar = rbase + row; if (ar > M - 1) ar = M - 1;
    uint4 v = *(const uint4*)(A + (size_t)ar * 128 + slot * 8);
    *(uint4*)(As + row * 136 + slot * 8) = v;
  }
  __syncthreads();
  const int w = tid >> 6, l = tid & 63;
  const int lr = l & 15, lg = l >> 4;
#pragma unroll
  for (int i = 0; i < 9; ++i) {
    const int ct = w * 9 + i;
    const bf16x8* bp = (const bf16x8*)(BT + (size_t)(ct * 16 + lr) * 128 + lg * 8);
    bf16x8 b0 = bp[0], b1 = bp[4], b2 = bp[8], b3 = bp[12];
    const int colb = ct * 16 + lg * 4;
    const int cc = (ct < 32) ? (colb & 255) : (colb - 512);
    const float* bptr = (ct < 16 ? bias0 : (ct < 32 ? bias1 : bias2));
    float4 bv = *(const float4*)(bptr + cc);
#pragma unroll
    for (int rt = 0; rt < 4; ++rt) {
      const unsigned short* ap = As + (rt * 16 + lr) * 136 + lg * 8;
      bf16x8 a0 = *(const bf16x8*)(ap);
      bf16x8 a1 = *(const bf16x8*)(ap + 32);
      bf16x8 a2 = *(const bf16x8*)(ap + 64);
      bf16x8 a3 = *(const bf16x8*)(ap + 96);
      f32x4 acc = {0.f, 0.f, 0.f, 0.f};
      acc = __builtin_amdgcn_mfma_f32_16x16x32_bf16(b0, a0, acc, 0, 0, 0);
      acc = __builtin_amdgcn_mfma_f32_16x16x32_bf16(b1, a1, acc, 0, 0, 0);
      acc = __builtin_amdgcn_mfma_f32_16x16x32_bf16(b2, a2, acc, 0, 0, 0);
      acc = __builtin_amdgcn_mfma_f32_16x16x32_bf16(b3, a3, acc, 0, 0, 0);
      const int row = rbase + rt * 16 + lr;
      if (ct < 32) {
        ushort4 o;
        o.x = f2bf(acc[0] + bv.x); o.y = f2bf(acc[1] + bv.y);
        o.z = f2bf(acc[2] + bv.z); o.w = f2bf(acc[3] + bv.w);
        *(ushort4*)((ct < 16 ? o_xl : o_xr) + (size_t)row * 256 + cc) = o;
      } else if (row < M) {
        float4 o;
        o.x = acc[0] + bv.x; o.y = acc[1] + bv.y;
        o.z = acc[2] + bv.z; o.w = acc[3] + bv.w;
        *(float4*)(o_out + (size_t)row * 64 + cc) = o;
      }
    }
  }
}

// ---------------------------------------------------------------------------
// per-edge step helpers (acc/den in registers; fully unrolled)
// ---------------------------------------------------------------------------
__device__ inline void edge_step0(int2 rec, bf16x8 a8, bool valid,
                                  const float* xrv, const float* wef, const float* attf,
                                  float* acc, float& den) {
  float w = __int_as_float(rec.y);
  float av[8], c = 0.f;
#pragma unroll
  for (int j = 0; j < 8; ++j) {
    av[j] = bf2f((unsigned short)a8[j]);
    float t  = fmaf(w, wef[j], xrv[j]);
    float sv = av[j] + t;
    float lk = fmaxf(sv, 0.2f * sv);
    c = fmaf(lk, attf[j], c);
  }
  c += __shfl_xor(c, 1, 64); c += __shfl_xor(c, 2, 64);   // head = 4 lanes
  float p = valid ? __expf(c) : 0.f;
  den += p;
#pragma unroll
  for (int j = 0; j < 8; ++j) acc[j] = fmaf(p, av[j], acc[j]);
}

__device__ inline void edge_step1(int2 rec, bf16x8 a8, bool valid,
                                  const float* xrv, const float* wef, const float* attf,
                                  float* acc, float& den) {
  float w = __int_as_float(rec.y);
  float av[8], c = 0.f;
#pragma unroll
  for (int j = 0; j < 8; ++j) {
    av[j] = bf2f((unsigned short)a8[j]);
    float t  = fmaf(w, wef[j], xrv[j]);
    float sv = av[j] + t;
    float lk = fmaxf(sv, 0.2f * sv);
    c = fmaf(lk, attf[j], c);
  }
  c += __shfl_xor(c, 1, 64); c += __shfl_xor(c, 2, 64); c += __shfl_xor(c, 4, 64);
  float p = valid ? __expf(c) : 0.f;
  den += p;
#pragma unroll
  for (int j = 0; j < 8; ++j) acc[j] = fmaf(p, av[j], acc[j]);
}

// ---------------------------------------------------------------------------
// Layer-0 aggregation: 1 wave/node, 4 edge groups, unroll 2 + prefetch
// (8 gathers in flight per wave).
// ---------------------------------------------------------------------------
__global__ __launch_bounds__(256) void agg0(
    const int* __restrict__ part, const int* __restrict__ bsum,
    const int* __restrict__ deg, const int2* __restrict__ csr2,
    const unsigned short* __restrict__ xl, const unsigned short* __restrict__ xr,
    const float* __restrict__ We, const float* __restrict__ att,
    const float* __restrict__ b, const float* __restrict__ g,
    const float* __restrict__ be, const float* __restrict__ hres,
    unsigned short* __restrict__ hout) {
  const int wid = threadIdx.x >> 6, l = threadIdx.x & 63;
  const int n = blockIdx.x * 4 + wid;
  const int grp = l >> 4, cl = l & 15, c0 = cl * 8;
  float xrv[8], wef[8], attf[8];
  {
    bf16x8 x8 = *(const bf16x8*)(xr + (size_t)n * HC0 + c0);
    float4 w0 = *(const float4*)(We + c0),  w1 = *(const float4*)(We + c0 + 4);
    float4 t0 = *(const float4*)(att + c0), t1 = *(const float4*)(att + c0 + 4);
    wef[0]=w0.x; wef[1]=w0.y; wef[2]=w0.z; wef[3]=w0.w;
    wef[4]=w1.x; wef[5]=w1.y; wef[6]=w1.z; wef[7]=w1.w;
    attf[0]=t0.x; attf[1]=t0.y; attf[2]=t0.z; attf[3]=t0.w;
    attf[4]=t1.x; attf[5]=t1.y; attf[6]=t1.z; attf[7]=t1.w;
#pragma unroll
    for (int j = 0; j < 8; ++j) xrv[j] = bf2f((unsigned short)x8[j]);
  }
  const int start = part[n] + bsum[n >> 8];
  const int cnt   = deg[n] + 1;
  const int last  = start + cnt - 1;
  float acc[8] = {0,0,0,0,0,0,0,0}, den = 0.f;
  int e = grp;
  int i0 = start + e;     if (i0 > last) i0 = last;
  int i1 = start + e + 4; if (i1 > last) i1 = last;
  int2 r0 = csr2[i0], r1 = csr2[i1];
  bf16x8 a0 = *(const bf16x8*)(xl + (size_t)r0.x * HC0 + c0);
  bf16x8 a1 = *(const bf16x8*)(xl + (size_t)r1.x * HC0 + c0);
  const int trips = (cnt + 7) >> 3;
  for (int t = 0; t < trips; ++t) {
    int i2 = start + e + 8;  if (i2 > last) i2 = last;
    int i3 = start + e + 12; if (i3 > last) i3 = last;
    int2 r2 = csr2[i2], r3 = csr2[i3];
    bf16x8 p2 = *(const bf16x8*)(xl + (size_t)r2.x * HC0 + c0);
    bf16x8 p3 = *(const bf16x8*)(xl + (size_t)r3.x * HC0 + c0);
    edge_step0(r0, a0, e < cnt,     xrv, wef, attf, acc, den);
    edge_step0(r1, a1, e + 4 < cnt, xrv, wef, attf, acc, den);
    r0 = r2; r1 = r3; a0 = p2; a1 = p3; e += 8;
  }
  den += __shfl_xor(den, 16, 64); den += __shfl_xor(den, 32, 64);
#pragma unroll
  for (int j = 0; j < 8; ++j) {
    acc[j] += __shfl_xor(acc[j], 16, 64);
    acc[j] += __shfl_xor(acc[j], 32, 64);
  }
  float v[8], s1 = 0.f, s2 = 0.f;
  float dinv = 1.f / den;
  {
    float4 b0v = *(const float4*)(b + c0), b1v = *(const float4*)(b + c0 + 4);
    float bb[8] = {b0v.x,b0v.y,b0v.z,b0v.w,b1v.x,b1v.y,b1v.z,b1v.w};
#pragma unroll
    for (int j = 0; j < 8; ++j) {
      float t = acc[j] * dinv + bb[j];
      t = t > 0.f ? t : __expf(t) - 1.f;
      v[j] = t; s1 += t; s2 += t * t;
    }
  }
  s1 += __shfl_xor(s1, 1, 64); s2 += __shfl_xor(s2, 1, 64);
  s1 += __shfl_xor(s1, 2, 64); s2 += __shfl_xor(s2, 2, 64);
  s1 += __shfl_xor(s1, 4, 64); s2 += __shfl_xor(s2, 4, 64);
  s1 += __shfl_xor(s1, 8, 64); s2 += __shfl_xor(s2, 8, 64);
  float mean = s1 * (1.f / 128.f);
  float inv  = rsqrtf(s2 * (1.f / 128.f) - mean * mean + 1e-5f);
  if (grp == 0) {
    float4 g0v = *(const float4*)(g + c0),  g1v = *(const float4*)(g + c0 + 4);
    float4 e0v = *(const float4*)(be + c0), e1v = *(const float4*)(be + c0 + 4);
    float4 h0v = *(const float4*)(hres + (size_t)n * HC0 + c0);
    float4 h1v = *(const float4*)(hres + (size_t)n * HC0 + c0 + 4);
    float gg[8] = {g0v.x,g0v.y,g0v.z,g0v.w,g1v.x,g1v.y,g1v.z,g1v.w};
    float ee[8] = {e0v.x,e0v.y,e0v.z,e0v.w,e1v.x,e1v.y,e1v.z,e1v.w};
    float hh[8] = {h0v.x,h0v.y,h0v.z,h0v.w,h1v.x,h1v.y,h1v.z,h1v.w};
    bf16x8 o;
#pragma unroll
    for (int j = 0; j < 8; ++j)
      o[j] = (short)f2bf((v[j] - mean) * inv * gg[j] + ee[j] + hh[j]);
    *(bf16x8*)(hout + (size_t)n * HC0 + c0) = o;
  }
}

// ---------------------------------------------------------------------------
// Layer-1 aggregation: 1 wave/node, 2 edge groups, unroll 2 + prefetch
// (4 gathers in flight per wave).
// ---------------------------------------------------------------------------
__global__ __launch_bounds__(256) void agg1(
    const int* __restrict__ part, const int* __restrict__ bsum,
    const int* __restrict__ deg, const int2* __restrict__ csr2,
    const unsigned short* __restrict__ xl, const unsigned short* __restrict__ xr,
    const float* __restrict__ We, const float* __restrict__ att,
    const float* __restrict__ b, const float* __restrict__ g,
    const float* __restrict__ be, float* __restrict__ out) {
  const int wid = threadIdx.x >> 6, l = threadIdx.x & 63;
  const int n = blockIdx.x * 4 + wid;
  const int grp = l >> 5, cl = l & 31, c0 = cl * 8;
  float xrv[8], wef[8], attf[8];
  {
    bf16x8 x8 = *(const bf16x8*)(xr + (size_t)n * HC1 + c0);
    float4 w0 = *(const float4*)(We + c0),  w1 = *(const float4*)(We + c0 + 4);
    float4 t0 = *(const float4*)(att + c0), t1 = *(const float4*)(att + c0 + 4);
    wef[0]=w0.x; wef[1]=w0.y; wef[2]=w0.z; wef[3]=w0.w;
    wef[4]=w1.x; wef[5]=w1.y; wef[6]=w1.z; wef[7]=w1.w;
    attf[0]=t0.x; attf[1]=t0.y; attf[2]=t0.z; attf[3]=t0.w;
    attf[4]=t1.x; attf[5]=t1.y; attf[6]=t1.z; attf[7]=t1.w;
#pragma unroll
    for (int j = 0; j < 8; ++j) xrv[j] = bf2f((unsigned short)x8[j]);
  }
  const int start = part[n] + bsum[n >> 8];
  const int cnt   = deg[n] + 1;
  const int last  = start + cnt - 1;
  float acc[8] = {0,0,0,0,0,0,0,0}, den = 0.f;
  int e = grp;
  int i0 = start + e;     if (i0 > last) i0 = last;
  int i1 = start + e + 2; if (i1 > last) i1 = last;
  int2 r0 = csr2[i0], r1 = csr2[i1];
  bf16x8 a0 = *(const bf16x8*)(xl + (size_t)r0.x * HC1 + c0);
  bf16x8 a1 = *(const bf16x8*)(xl + (size_t)r1.x * HC1 + c0);
  const int trips = (cnt + 3) >> 2;
  for (int t = 0; t < trips; ++t) {
    int i2 = start + e + 4; if (i2 > last) i2 = last;
    int i3 = start + e + 6; if (i3 > last) i3 = last;
    int2 r2 = csr2[i2], r3 = csr2[i3];
    bf16x8 p2 = *(const bf16x8*)(xl + (size_t)r2.x * HC1 + c0);
    bf16x8 p3 = *(const bf16x8*)(xl + (size_t)r3.x * HC1 + c0);
    edge_step1(r0, a0, e < cnt,     xrv, wef, attf, acc, den);
    edge_step1(r1, a1, e + 2 < cnt, xrv, wef, attf, acc, den);
    r0 = r2; r1 = r3; a0 = p2; a1 = p3; e += 4;
  }
  den += __shfl_xor(den, 32, 64);
#pragma unroll
  for (int j = 0; j < 8; ++j) acc[j] += __shfl_xor(acc[j], 32, 64);
  __shared__ float lds[4][HC1];
  if (grp == 0) {
    float dinv = 1.f / den;
#pragma unroll
    for (int j = 0; j < 8; ++j) lds[wid][c0 + j] = acc[j] * dinv;
  }
  __syncthreads();
  float v = 0.25f * (lds[wid][l] + lds[wid][64 + l] + lds[wid][128 + l] +
                     lds[wid][192 + l]) + b[l];
  v = v > 0.f ? v : __expf(v) - 1.f;
  float s1 = v, s2 = v * v;
#pragma unroll
  for (int o = 32; o > 0; o >>= 1) { s1 += __shfl_xor(s1, o, 64); s2 += __shfl_xor(s2, o, 64); }
  float mean = s1 * (1.f / 64.f);
  float inv  = rsqrtf(s2 * (1.f / 64.f) - mean * mean + 1e-5f);
  out[(size_t)n * 64 + l] += (v - mean) * inv * g[l] + be[l];
}

// ---------------------------------------------------------------------------
extern "C" void kernel_launch(void* const* d_in, const int* in_sizes, int n_in,
                              void* d_out, int out_size, void* d_ws, size_t ws_size,
                              hipStream_t stream) {
  const float* x    = (const float*)d_in[0];
  const int*   ei   = (const int*)  d_in[1];
  const float* ew   = (const float*)d_in[2];
  const float* Wl0  = (const float*)d_in[3];
  const float* bl0  = (const float*)d_in[4];
  const float* Wr0  = (const float*)d_in[5];
  const float* br0  = (const float*)d_in[6];
  const float* We0  = (const float*)d_in[7];
  const float* att0 = (const float*)d_in[8];
  const float* b0   = (const float*)d_in[9];
  const float* g0   = (const float*)d_in[10];
  const float* be0  = (const float*)d_in[11];
  const float* Wl1  = (const float*)d_in[12];
  const float* bl1  = (const float*)d_in[13];
  const float* Wr1  = (const float*)d_in[14];
  const float* br1  = (const float*)d_in[15];
  const float* We1  = (const float*)d_in[16];
  const float* att1 = (const float*)d_in[17];
  const float* b1   = (const float*)d_in[18];
  const float* g1   = (const float*)d_in[19];
  const float* be1  = (const float*)d_in[20];
  const float* P0   = (const float*)d_in[21];
  const float* pb0  = (const float*)d_in[22];
  const float* P1   = (const float*)d_in[23];
  const float* pb1  = (const float*)d_in[24];
  float* out = (float*)d_out;

  // workspace layout (32-bit words)
  float* f        = (float*)d_ws;
  float* s_loopw  = f;                               // 50176
  int*   deg      = (int*)(f + 50176);               // 50176
  int*   cursor   = (int*)(f + 100352);              // 50176
  int*   part     = (int*)(f + 150528);              // 50176
  int*   bsum     = (int*)(f + 200704);              // 256
  int2*  csr2     = (int2*)(f + 200960);             // 450560 int2 = 901120 w
  unsigned short* wl0T = (unsigned short*)(f + 1102080);  // 384x128 bf16
  unsigned short* wr0T = wl0T + 16384;
  unsigned short* p0T  = wl0T + 32768;
  unsigned short* wl1T = (unsigned short*)(f + 1126656);  // 576x128 bf16
  unsigned short* wr1T = wl1T + 32768;
  unsigned short* p1T  = wl1T + 65536;
  unsigned short* xb   = (unsigned short*)(f + 1163520);  // MROWS x128 bf16
  unsigned short* hb   = (unsigned short*)(f + 4366592);  // MROWS x128 bf16
  float*          hres = f + 7569664;                     // MROWS x128 fp32
  unsigned short* RA   = (unsigned short*)(f + 13975808); // MROWS x256 bf16
  unsigned short* RB   = (unsigned short*)(f + 20381952); // MROWS x256 bf16
  unsigned short* xl0b = RA, *xr0b = RB;
  unsigned short* xl1b = RA, *xr1b = RB;

  // ---- CSR build ---------------------------------------------------------
  hipMemsetAsync(s_loopw, 0, (size_t)(50176 * 3) * sizeof(float), stream);
  deg_kernel<<<(N_EDGES + 255) / 256, 256, 0, stream>>>(ei, ew, s_loopw, deg);
  scan1<<<NPAD / 256, 256, 0, stream>>>(deg, part, bsum);
  scan2<<<1, 256, 0, stream>>>(bsum);
  self_kernel<<<(N_NODES + 255) / 256, 256, 0, stream>>>(s_loopw, deg, part, bsum, csr2);
  scatter_kernel<<<(N_EDGES + 255) / 256, 256, 0, stream>>>(ei, ew, part, bsum,
                                                            cursor, csr2);

  // ---- precision prep ----------------------------------------------------
  cvt_bf16<<<(N_NODES * 128 / 4 + 255) / 256, 256, 0, stream>>>(x, xb, N_NODES * 128 / 4);
  pack_w<<<960, 128, 0, stream>>>(Wl0, Wr0, P0, Wl1, Wr1, P1,
                                  wl0T, wr0T, p0T, wl1T, wr1T, p1T);

  // ---- layer 0 -----------------------------------------------------------
  const int GB = MROWS / 64;   // 782
  gemm_l0<<<GB, 256, 0, stream>>>(xb, wl0T, bl0, br0, pb0, xl0b, xr0b, hres, N_NODES);
  agg0<<<N_NODES / 4, 256, 0, stream>>>(part, bsum, deg, csr2,
                                        xl0b, xr0b, We0, att0, b0, g0, be0, hres, hb);

  // ---- layer 1 -----------------------------------------------------------
  gemm_l1<<<GB, 256, 0, stream>>>(hb, wl1T, bl1, br1, pb1, xl1b, xr1b, out, N_NODES);
  agg1<<<N_NODES / 4, 256, 0, stream>>>(part, bsum, deg, csr2,
                                        xl1b, xr1b, We1, att1, b1, g1, be1, out);
}

// Round 8
// 245.431 us; speedup vs baseline: 4.8198x; 1.0078x over previous
//
#include <hip/hip_runtime.h>
#include <math.h>

#define N_NODES 50000
#define N_EDGES 400000
#define NPAD    50176            // 196*256
#define MROWS   50048            // 782*64, padded row count for gemm outputs
#define HC0 128
#define HC1 256

typedef short bf16x8 __attribute__((ext_vector_type(8)));
typedef float f32x4  __attribute__((ext_vector_type(4)));

__device__ inline unsigned short f2bf(float f) {
  union { float f; unsigned u; } v; v.f = f;
  unsigned r = v.u + 0x7FFFu + ((v.u >> 16) & 1u);   // RNE
  return (unsigned short)(r >> 16);
}
__device__ inline float bf2f(unsigned short h) {
  union { unsigned u; float f; } v; v.u = ((unsigned)h) << 16;
  return v.f;
}

// ---------------------------------------------------------------------------
// CSR build. Segment per node = 1 (self loop, slot 0) + deg entries of
// int2 {src, w_bits}. Scan is over deg+1.
// ---------------------------------------------------------------------------
__global__ void deg_kernel(const int* __restrict__ ei, const float* __restrict__ ew,
                           float* __restrict__ s, int* __restrict__ deg) {
  int e = blockIdx.x * 256 + threadIdx.x;
  if (e < N_EDGES) {
    int dst = ei[N_EDGES + e];
    atomicAdd(&s[dst], ew[e]);
    atomicAdd(&deg[dst], 1);
  }
}

__global__ void scan1(const int* __restrict__ deg, int* __restrict__ part,
                      int* __restrict__ bsum) {
  int i = blockIdx.x * 256 + threadIdx.x;
  int lane = threadIdx.x & 63, wid = threadIdx.x >> 6;
  int v = (i < N_NODES) ? deg[i] + 1 : 0;
  int inc = v;
#pragma unroll
  for (int d = 1; d < 64; d <<= 1) { int y = __shfl_up(inc, d, 64); if (lane >= d) inc += y; }
  __shared__ int wsum[4];
  if (lane == 63) wsum[wid] = inc;
  __syncthreads();
  int off = 0;
#pragma unroll
  for (int w = 0; w < 4; ++w) { int sv = wsum[w]; if (w < wid) off += sv; }
  part[i] = inc - v + off;
  if (threadIdx.x == 0) bsum[blockIdx.x] = wsum[0] + wsum[1] + wsum[2] + wsum[3];
}

__global__ void scan2(int* __restrict__ bsum) {
  int t = threadIdx.x;
  int lane = t & 63, wid = t >> 6;
  int v = (t < 196) ? bsum[t] : 0;
  int inc = v;
#pragma unroll
  for (int d = 1; d < 64; d <<= 1) { int y = __shfl_up(inc, d, 64); if (lane >= d) inc += y; }
  __shared__ int wsum[4];
  if (lane == 63) wsum[wid] = inc;
  __syncthreads();
  int off = 0;
#pragma unroll
  for (int w = 0; w < 4; ++w) { int sv = wsum[w]; if (w < wid) off += sv; }
  if (t < 196) bsum[t] = inc - v + off;
}

// self-loop weight (mean of incoming) -> csr2[start] record
__global__ void self_kernel(const float* __restrict__ s, const int* __restrict__ deg,
                            const int* __restrict__ part, const int* __restrict__ bsum,
                            int2* __restrict__ csr2) {
  int i = blockIdx.x * 256 + threadIdx.x;
  if (i >= N_NODES) return;
  float w = s[i] / fmaxf((float)deg[i], 1.0f);
  int start = part[i] + bsum[i >> 8];
  csr2[start] = make_int2(i, __float_as_int(w));
}

__global__ void scatter_kernel(const int* __restrict__ ei, const float* __restrict__ ew,
                               const int* __restrict__ part, const int* __restrict__ bsum,
                               int* __restrict__ cursor, int2* __restrict__ csr2) {
  int e = blockIdx.x * 256 + threadIdx.x;
  if (e >= N_EDGES) return;
  int dst = ei[N_EDGES + e];
  int pos = atomicAdd(&cursor[dst], 1);
  int idx = part[dst] + bsum[dst >> 8] + 1 + pos;
  csr2[idx] = make_int2(ei[e], __float_as_int(ew[e]));
}

// ---------------------------------------------------------------------------
// fp32 -> bf16 (vectorized)
// ---------------------------------------------------------------------------
__global__ void cvt_bf16(const float* __restrict__ in, unsigned short* __restrict__ out,
                         int n4) {
  int i = blockIdx.x * 256 + threadIdx.x;
  if (i >= n4) return;
  float4 v = ((const float4*)in)[i];
  ushort4 o; o.x = f2bf(v.x); o.y = f2bf(v.y); o.z = f2bf(v.z); o.w = f2bf(v.w);
  ((ushort4*)out)[i] = o;
}

// ---------------------------------------------------------------------------
// weight pack: W[128][N] fp32 -> BT[N][128] bf16
// ---------------------------------------------------------------------------
__global__ void pack_w(const float* __restrict__ Wl0, const float* __restrict__ Wr0,
                       const float* __restrict__ P0,  const float* __restrict__ Wl1,
                       const float* __restrict__ Wr1, const float* __restrict__ P1,
                       unsigned short* __restrict__ o_wl0, unsigned short* __restrict__ o_wr0,
                       unsigned short* __restrict__ o_p0,  unsigned short* __restrict__ o_wl1,
                       unsigned short* __restrict__ o_wr1, unsigned short* __restrict__ o_p1) {
  int n = blockIdx.x, k = threadIdx.x;
  const float* W; unsigned short* O; int N, nl;
  if      (n < 128) { W = Wl0; O = o_wl0; N = 128; nl = n; }
  else if (n < 256) { W = Wr0; O = o_wr0; N = 128; nl = n - 128; }
  else if (n < 384) { W = P0;  O = o_p0;  N = 128; nl = n - 256; }
  else if (n < 640) { W = Wl1; O = o_wl1; N = 256; nl = n - 384; }
  else if (n < 896) { W = Wr1; O = o_wr1; N = 256; nl = n - 640; }
  else              { W = P1;  O = o_p1;  N = 64;  nl = n - 896; }
  O[nl * 128 + k] = f2bf(W[(size_t)k * N + nl]);
}

// ---------------------------------------------------------------------------
// Merged GEMM layer 0 (unchanged from round 6).
// ---------------------------------------------------------------------------
__global__ __launch_bounds__(256) void gemm_l0(
    const unsigned short* __restrict__ A, const unsigned short* __restrict__ BT,
    const float* __restrict__ bias0, const float* __restrict__ bias1,
    const float* __restrict__ bias2,
    unsigned short* __restrict__ o_xl, unsigned short* __restrict__ o_xr,
    float* __restrict__ o_h, int M) {
  __shared__ unsigned short As[64 * 136];   // 272B pitch
  const int tid = threadIdx.x;
  const int rbase = blockIdx.x * 64;
#pragma unroll
  for (int i = 0; i < 4; ++i) {
    int c = i * 256 + tid;
    int row = c >> 4, slot = c & 15;
    int ar = rbase + row; if (ar > M - 1) ar = M - 1;
    uint4 v = *(const uint4*)(A + (size_t)ar * 128 + slot * 8);
    *(uint4*)(As + row * 136 + slot * 8) = v;
  }
  __syncthreads();
  const int w = tid >> 6, l = tid & 63;
  const int lr = l & 15, lg = l >> 4;
#pragma unroll
  for (int i = 0; i < 6; ++i) {
    const int ct = w * 6 + i;
    const bf16x8* bp = (const bf16x8*)(BT + (size_t)(ct * 16 + lr) * 128 + lg * 8);
    bf16x8 b0 = bp[0], b1 = bp[4], b2 = bp[8], b3 = bp[12];
    const int colb = ct * 16 + lg * 4;
    const int cc = colb & 127;
    const float* bptr = (ct < 8 ? bias0 : (ct < 16 ? bias1 : bias2));
    float4 bv = *(const float4*)(bptr + cc);
#pragma unroll
    for (int rt = 0; rt < 4; ++rt) {
      const unsigned short* ap = As + (rt * 16 + lr) * 136 + lg * 8;
      bf16x8 a0 = *(const bf16x8*)(ap);
      bf16x8 a1 = *(const bf16x8*)(ap + 32);
      bf16x8 a2 = *(const bf16x8*)(ap + 64);
      bf16x8 a3 = *(const bf16x8*)(ap + 96);
      f32x4 acc = {0.f, 0.f, 0.f, 0.f};
      acc = __builtin_amdgcn_mfma_f32_16x16x32_bf16(b0, a0, acc, 0, 0, 0);
      acc = __builtin_amdgcn_mfma_f32_16x16x32_bf16(b1, a1, acc, 0, 0, 0);
      acc = __builtin_amdgcn_mfma_f32_16x16x32_bf16(b2, a2, acc, 0, 0, 0);
      acc = __builtin_amdgcn_mfma_f32_16x16x32_bf16(b3, a3, acc, 0, 0, 0);
      const int row = rbase + rt * 16 + lr;
      if (ct < 16) {
        ushort4 o;
        o.x = f2bf(acc[0] + bv.x); o.y = f2bf(acc[1] + bv.y);
        o.z = f2bf(acc[2] + bv.z); o.w = f2bf(acc[3] + bv.w);
        *(ushort4*)((ct < 8 ? o_xl : o_xr) + (size_t)row * 128 + cc) = o;
      } else {
        float4 o;
        o.x = acc[0] + bv.x; o.y = acc[1] + bv.y;
        o.z = acc[2] + bv.z; o.w = acc[3] + bv.w;
        *(float4*)(o_h + (size_t)row * 128 + cc) = o;
      }
    }
  }
}

// ---------------------------------------------------------------------------
// Merged GEMM layer 1 (unchanged from round 6).
// ---------------------------------------------------------------------------
__global__ __launch_bounds__(256) void gemm_l1(
    const unsigned short* __restrict__ A, const unsigned short* __restrict__ BT,
    const float* __restrict__ bias0, const float* __restrict__ bias1,
    const float* __restrict__ bias2,
    unsigned short* __restrict__ o_xl, unsigned short* __restrict__ o_xr,
    float* __restrict__ o_out, int M) {
  __shared__ unsigned short As[64 * 136];
  const int tid = threadIdx.x;
  const int rbase = blockIdx.x * 64;
#pragma unroll
  for (int i = 0; i < 4; ++i) {
    int c = i * 256 + tid;
    int row = c >> 4, slot = c & 15;
    int ar = rbase + row; if (ar > M - 1) ar = M - 1;
    uint4 v = *(const uint4*)(A + (size_t)ar * 128 + slot * 8);
    *(uint4*)(As + row * 136 + slot * 8) = v;
  }
  __syncthreads();
  const int w = tid >> 6, l = tid & 63;
  const int lr = l & 15, lg = l >> 4;
#pragma unroll
  for (int i = 0; i < 9; ++i) {
    const int ct = w * 9 + i;
    const bf16x8* bp = (const bf16x8*)(BT + (size_t)(ct * 16 + lr) * 128 + lg * 8);
    bf16x8 b0 = bp[0], b1 = bp[4], b2 = bp[8], b3 = bp[12];
    const int colb = ct * 16 + lg * 4;
    const int cc = (ct < 32) ? (colb & 255) : (colb - 512);
    const float* bptr = (ct < 16 ? bias0 : (ct < 32 ? bias1 : bias2));
    float4 bv = *(const float4*)(bptr + cc);
#pragma unroll
    for (int rt = 0; rt < 4; ++rt) {
      const unsigned short* ap = As + (rt * 16 + lr) * 136 + lg * 8;
      bf16x8 a0 = *(const bf16x8*)(ap);
      bf16x8 a1 = *(const bf16x8*)(ap + 32);
      bf16x8 a2 = *(const bf16x8*)(ap + 64);
      bf16x8 a3 = *(const bf16x8*)(ap + 96);
      f32x4 acc = {0.f, 0.f, 0.f, 0.f};
      acc = __builtin_amdgcn_mfma_f32_16x16x32_bf16(b0, a0, acc, 0, 0, 0);
      acc = __builtin_amdgcn_mfma_f32_16x16x32_bf16(b1, a1, acc, 0, 0, 0);
      acc = __builtin_amdgcn_mfma_f32_16x16x32_bf16(b2, a2, acc, 0, 0, 0);
      acc = __builtin_amdgcn_mfma_f32_16x16x32_bf16(b3, a3, acc, 0, 0, 0);
      const int row = rbase + rt * 16 + lr;
      if (ct < 32) {
        ushort4 o;
        o.x = f2bf(acc[0] + bv.x); o.y = f2bf(acc[1] + bv.y);
        o.z = f2bf(acc[2] + bv.z); o.w = f2bf(acc[3] + bv.w);
        *(ushort4*)((ct < 16 ? o_xl : o_xr) + (size_t)row * 256 + cc) = o;
      } else if (row < M) {
        float4 o;
        o.x = acc[0] + bv.x; o.y = acc[1] + bv.y;
        o.z = acc[2] + bv.z; o.w = acc[3] + bv.w;
        *(float4*)(o_out + (size_t)row * 64 + cc) = o;
      }
    }
  }
}

// ---------------------------------------------------------------------------
// per-edge step helpers
// ---------------------------------------------------------------------------
__device__ inline void edge_step0(int2 rec, bf16x8 a8, bool valid,
                                  const float* xrv, const float* wef, const float* attf,
                                  float* acc, float& den) {
  float w = __int_as_float(rec.y);
  float av[8], c = 0.f;
#pragma unroll
  for (int j = 0; j < 8; ++j) {
    av[j] = bf2f((unsigned short)a8[j]);
    float t  = fmaf(w, wef[j], xrv[j]);
    float sv = av[j] + t;
    float lk = fmaxf(sv, 0.2f * sv);
    c = fmaf(lk, attf[j], c);
  }
  c += __shfl_xor(c, 1, 64); c += __shfl_xor(c, 2, 64);   // head = 4 lanes
  float p = valid ? __expf(c) : 0.f;
  den += p;
#pragma unroll
  for (int j = 0; j < 8; ++j) acc[j] = fmaf(p, av[j], acc[j]);
}

__device__ inline void edge_step1(int2 rec, bf16x8 a8, bool valid,
                                  const float* xrv, const float* wef, const float* attf,
                                  float* acc, float& den) {
  float w = __int_as_float(rec.y);
  float av[8], c = 0.f;
#pragma unroll
  for (int j = 0; j < 8; ++j) {
    av[j] = bf2f((unsigned short)a8[j]);
    float t  = fmaf(w, wef[j], xrv[j]);
    float sv = av[j] + t;
    float lk = fmaxf(sv, 0.2f * sv);
    c = fmaf(lk, attf[j], c);
  }
  c += __shfl_xor(c, 1, 64); c += __shfl_xor(c, 2, 64); c += __shfl_xor(c, 4, 64);
  float p = valid ? __expf(c) : 0.f;
  den += p;
#pragma unroll
  for (int j = 0; j < 8; ++j) acc[j] = fmaf(p, av[j], acc[j]);
}

// ---------------------------------------------------------------------------
// Layer-0 aggregation: 1 wave/node, 4 edge groups x unroll 2 (8 edges/trip).
// Split pipeline: CSR records fetched 2 trips ahead, xl gathers 1 trip ahead.
// ---------------------------------------------------------------------------
__global__ __launch_bounds__(256) void agg0(
    const int* __restrict__ part, const int* __restrict__ bsum,
    const int* __restrict__ deg, const int2* __restrict__ csr2,
    const unsigned short* __restrict__ xl, const unsigned short* __restrict__ xr,
    const float* __restrict__ We, const float* __restrict__ att,
    const float* __restrict__ b, const float* __restrict__ g,
    const float* __restrict__ be, const float* __restrict__ hres,
    unsigned short* __restrict__ hout) {
  const int wid = threadIdx.x >> 6, l = threadIdx.x & 63;
  const int n = blockIdx.x * 4 + wid;
  const int grp = l >> 4, cl = l & 15, c0 = cl * 8;
  float xrv[8], wef[8], attf[8];
  {
    bf16x8 x8 = *(const bf16x8*)(xr + (size_t)n * HC0 + c0);
    float4 w0 = *(const float4*)(We + c0),  w1 = *(const float4*)(We + c0 + 4);
    float4 t0 = *(const float4*)(att + c0), t1 = *(const float4*)(att + c0 + 4);
    wef[0]=w0.x; wef[1]=w0.y; wef[2]=w0.z; wef[3]=w0.w;
    wef[4]=w1.x; wef[5]=w1.y; wef[6]=w1.z; wef[7]=w1.w;
    attf[0]=t0.x; attf[1]=t0.y; attf[2]=t0.z; attf[3]=t0.w;
    attf[4]=t1.x; attf[5]=t1.y; attf[6]=t1.z; attf[7]=t1.w;
#pragma unroll
    for (int j = 0; j < 8; ++j) xrv[j] = bf2f((unsigned short)x8[j]);
  }
  const int start = part[n] + bsum[n >> 8];
  const int cnt   = deg[n] + 1;
  const int last  = start + cnt - 1;
  float acc[8] = {0,0,0,0,0,0,0,0}, den = 0.f;
#define IDX0(E) (start + (E) > last ? last : start + (E))
  int2 rA0 = csr2[IDX0(grp)],      rA1 = csr2[IDX0(grp + 4)];
  int2 rB0 = csr2[IDX0(grp + 8)],  rB1 = csr2[IDX0(grp + 12)];
  bf16x8 aA0 = *(const bf16x8*)(xl + (size_t)rA0.x * HC0 + c0);
  bf16x8 aA1 = *(const bf16x8*)(xl + (size_t)rA1.x * HC0 + c0);
  const int trips = (cnt + 7) >> 3;
  int e = grp;
  for (int t = 0; t < trips; ++t) {
    int2 rC0 = csr2[IDX0(e + 16)], rC1 = csr2[IDX0(e + 20)];
    bf16x8 aB0 = *(const bf16x8*)(xl + (size_t)rB0.x * HC0 + c0);
    bf16x8 aB1 = *(const bf16x8*)(xl + (size_t)rB1.x * HC0 + c0);
    edge_step0(rA0, aA0, e < cnt,     xrv, wef, attf, acc, den);
    edge_step0(rA1, aA1, e + 4 < cnt, xrv, wef, attf, acc, den);
    rA0 = rB0; rA1 = rB1; rB0 = rC0; rB1 = rC1; aA0 = aB0; aA1 = aB1;
    e += 8;
  }
#undef IDX0
  den += __shfl_xor(den, 16, 64); den += __shfl_xor(den, 32, 64);
#pragma unroll
  for (int j = 0; j < 8; ++j) {
    acc[j] += __shfl_xor(acc[j], 16, 64);
    acc[j] += __shfl_xor(acc[j], 32, 64);
  }
  float v[8], s1 = 0.f, s2 = 0.f;
  float dinv = 1.f / den;
  {
    float4 b0v = *(const float4*)(b + c0), b1v = *(const float4*)(b + c0 + 4);
    float bb[8] = {b0v.x,b0v.y,b0v.z,b0v.w,b1v.x,b1v.y,b1v.z,b1v.w};
#pragma unroll
    for (int j = 0; j < 8; ++j) {
      float t = acc[j] * dinv + bb[j];
      t = t > 0.f ? t : __expf(t) - 1.f;
      v[j] = t; s1 += t; s2 += t * t;
    }
  }
  s1 += __shfl_xor(s1, 1, 64); s2 += __shfl_xor(s2, 1, 64);
  s1 += __shfl_xor(s1, 2, 64); s2 += __shfl_xor(s2, 2, 64);
  s1 += __shfl_xor(s1, 4, 64); s2 += __shfl_xor(s2, 4, 64);
  s1 += __shfl_xor(s1, 8, 64); s2 += __shfl_xor(s2, 8, 64);
  float mean = s1 * (1.f / 128.f);
  float inv  = rsqrtf(s2 * (1.f / 128.f) - mean * mean + 1e-5f);
  if (grp == 0) {
    float4 g0v = *(const float4*)(g + c0),  g1v = *(const float4*)(g + c0 + 4);
    float4 e0v = *(const float4*)(be + c0), e1v = *(const float4*)(be + c0 + 4);
    float4 h0v = *(const float4*)(hres + (size_t)n * HC0 + c0);
    float4 h1v = *(const float4*)(hres + (size_t)n * HC0 + c0 + 4);
    float gg[8] = {g0v.x,g0v.y,g0v.z,g0v.w,g1v.x,g1v.y,g1v.z,g1v.w};
    float ee[8] = {e0v.x,e0v.y,e0v.z,e0v.w,e1v.x,e1v.y,e1v.z,e1v.w};
    float hh[8] = {h0v.x,h0v.y,h0v.z,h0v.w,h1v.x,h1v.y,h1v.z,h1v.w};
    bf16x8 o;
#pragma unroll
    for (int j = 0; j < 8; ++j)
      o[j] = (short)f2bf((v[j] - mean) * inv * gg[j] + ee[j] + hh[j]);
    *(bf16x8*)(hout + (size_t)n * HC0 + c0) = o;
  }
}

// ---------------------------------------------------------------------------
// Layer-1 aggregation: 1 wave/node, 2 edge groups x unroll 2 (4 edges/trip).
// Split pipeline as agg0. Barrier-free epilogue: head-mean via shfl_xor(8,16),
// LN(64) stats via shfl_xor(1,2,4); no LDS, no __syncthreads.
// ---------------------------------------------------------------------------
__global__ __launch_bounds__(256) void agg1(
    const int* __restrict__ part, const int* __restrict__ bsum,
    const int* __restrict__ deg, const int2* __restrict__ csr2,
    const unsigned short* __restrict__ xl, const unsigned short* __restrict__ xr,
    const float* __restrict__ We, const float* __restrict__ att,
    const float* __restrict__ b, const float* __restrict__ g,
    const float* __restrict__ be, float* __restrict__ out) {
  const int wid = threadIdx.x >> 6, l = threadIdx.x & 63;
  const int n = blockIdx.x * 4 + wid;
  const int grp = l >> 5, cl = l & 31, c0 = cl * 8;
  float xrv[8], wef[8], attf[8];
  {
    bf16x8 x8 = *(const bf16x8*)(xr + (size_t)n * HC1 + c0);
    float4 w0 = *(const float4*)(We + c0),  w1 = *(const float4*)(We + c0 + 4);
    float4 t0 = *(const float4*)(att + c0), t1 = *(const float4*)(att + c0 + 4);
    wef[0]=w0.x; wef[1]=w0.y; wef[2]=w0.z; wef[3]=w0.w;
    wef[4]=w1.x; wef[5]=w1.y; wef[6]=w1.z; wef[7]=w1.w;
    attf[0]=t0.x; attf[1]=t0.y; attf[2]=t0.z; attf[3]=t0.w;
    attf[4]=t1.x; attf[5]=t1.y; attf[6]=t1.z; attf[7]=t1.w;
#pragma unroll
    for (int j = 0; j < 8; ++j) xrv[j] = bf2f((unsigned short)x8[j]);
  }
  const int start = part[n] + bsum[n >> 8];
  const int cnt   = deg[n] + 1;
  const int last  = start + cnt - 1;
  float acc[8] = {0,0,0,0,0,0,0,0}, den = 0.f;
#define IDX1(E) (start + (E) > last ? last : start + (E))
  int2 rA0 = csr2[IDX1(grp)],     rA1 = csr2[IDX1(grp + 2)];
  int2 rB0 = csr2[IDX1(grp + 4)], rB1 = csr2[IDX1(grp + 6)];
  bf16x8 aA0 = *(const bf16x8*)(xl + (size_t)rA0.x * HC1 + c0);
  bf16x8 aA1 = *(const bf16x8*)(xl + (size_t)rA1.x * HC1 + c0);
  const int trips = (cnt + 3) >> 2;
  int e = grp;
  for (int t = 0; t < trips; ++t) {
    int2 rC0 = csr2[IDX1(e + 8)], rC1 = csr2[IDX1(e + 10)];
    bf16x8 aB0 = *(const bf16x8*)(xl + (size_t)rB0.x * HC1 + c0);
    bf16x8 aB1 = *(const bf16x8*)(xl + (size_t)rB1.x * HC1 + c0);
    edge_step1(rA0, aA0, e < cnt,     xrv, wef, attf, acc, den);
    edge_step1(rA1, aA1, e + 2 < cnt, xrv, wef, attf, acc, den);
    rA0 = rB0; rA1 = rB1; rB0 = rC0; rB1 = rC1; aA0 = aB0; aA1 = aB1;
    e += 4;
  }
#undef IDX1
  den += __shfl_xor(den, 32, 64);
#pragma unroll
  for (int j = 0; j < 8; ++j) acc[j] += __shfl_xor(acc[j], 32, 64);
  // head-mean in-wave: lane cl holds head h=cl>>3, output block oc=(cl&7)*8.
  // xor 8 + xor 16 sums the 4 heads for the same oc block.
  float dinv = 1.f / den;
  float v[8], s1 = 0.f, s2 = 0.f;
  const int oc = (cl & 7) * 8;
  {
    float4 b0v = *(const float4*)(b + oc), b1v = *(const float4*)(b + oc + 4);
    float bb[8] = {b0v.x,b0v.y,b0v.z,b0v.w,b1v.x,b1v.y,b1v.z,b1v.w};
#pragma unroll
    for (int j = 0; j < 8; ++j) {
      float t = acc[j] * dinv;
      t += __shfl_xor(t, 8, 64);
      t += __shfl_xor(t, 16, 64);
      t = t * 0.25f + bb[j];
      t = t > 0.f ? t : __expf(t) - 1.f;       // ELU
      v[j] = t; s1 += t; s2 += t * t;
    }
  }
  s1 += __shfl_xor(s1, 1, 64); s2 += __shfl_xor(s2, 1, 64);
  s1 += __shfl_xor(s1, 2, 64); s2 += __shfl_xor(s2, 2, 64);
  s1 += __shfl_xor(s1, 4, 64); s2 += __shfl_xor(s2, 4, 64);
  float mean = s1 * (1.f / 64.f);
  float inv  = rsqrtf(s2 * (1.f / 64.f) - mean * mean + 1e-5f);
  if (grp == 0 && cl < 8) {
    float4 g0v = *(const float4*)(g + oc),  g1v = *(const float4*)(g + oc + 4);
    float4 e0v = *(const float4*)(be + oc), e1v = *(const float4*)(be + oc + 4);
    float gg[8] = {g0v.x,g0v.y,g0v.z,g0v.w,g1v.x,g1v.y,g1v.z,g1v.w};
    float ee[8] = {e0v.x,e0v.y,e0v.z,e0v.w,e1v.x,e1v.y,e1v.z,e1v.w};
    float* po = out + (size_t)n * 64 + oc;
    float4 o0 = *(const float4*)po, o1 = *(const float4*)(po + 4);
    o0.x += (v[0] - mean) * inv * gg[0] + ee[0];
    o0.y += (v[1] - mean) * inv * gg[1] + ee[1];
    o0.z += (v[2] - mean) * inv * gg[2] + ee[2];
    o0.w += (v[3] - mean) * inv * gg[3] + ee[3];
    o1.x += (v[4] - mean) * inv * gg[4] + ee[4];
    o1.y += (v[5] - mean) * inv * gg[5] + ee[5];
    o1.z += (v[6] - mean) * inv * gg[6] + ee[6];
    o1.w += (v[7] - mean) * inv * gg[7] + ee[7];
    *(float4*)po = o0; *(float4*)(po + 4) = o1;
  }
}

// ---------------------------------------------------------------------------
extern "C" void kernel_launch(void* const* d_in, const int* in_sizes, int n_in,
                              void* d_out, int out_size, void* d_ws, size_t ws_size,
                              hipStream_t stream) {
  const float* x    = (const float*)d_in[0];
  const int*   ei   = (const int*)  d_in[1];
  const float* ew   = (const float*)d_in[2];
  const float* Wl0  = (const float*)d_in[3];
  const float* bl0  = (const float*)d_in[4];
  const float* Wr0  = (const float*)d_in[5];
  const float* br0  = (const float*)d_in[6];
  const float* We0  = (const float*)d_in[7];
  const float* att0 = (const float*)d_in[8];
  const float* b0   = (const float*)d_in[9];
  const float* g0   = (const float*)d_in[10];
  const float* be0  = (const float*)d_in[11];
  const float* Wl1  = (const float*)d_in[12];
  const float* bl1  = (const float*)d_in[13];
  const float* Wr1  = (const float*)d_in[14];
  const float* br1  = (const float*)d_in[15];
  const float* We1  = (const float*)d_in[16];
  const float* att1 = (const float*)d_in[17];
  const float* b1   = (const float*)d_in[18];
  const float* g1   = (const float*)d_in[19];
  const float* be1  = (const float*)d_in[20];
  const float* P0   = (const float*)d_in[21];
  const float* pb0  = (const float*)d_in[22];
  const float* P1   = (const float*)d_in[23];
  const float* pb1  = (const float*)d_in[24];
  float* out = (float*)d_out;

  // workspace layout (32-bit words)
  float* f        = (float*)d_ws;
  float* s_loopw  = f;                               // 50176
  int*   deg      = (int*)(f + 50176);               // 50176
  int*   cursor   = (int*)(f + 100352);              // 50176
  int*   part     = (int*)(f + 150528);              // 50176
  int*   bsum     = (int*)(f + 200704);              // 256
  int2*  csr2     = (int2*)(f + 200960);             // 450560 int2 = 901120 w
  unsigned short* wl0T = (unsigned short*)(f + 1102080);  // 384x128 bf16
  unsigned short* wr0T = wl0T + 16384;
  unsigned short* p0T  = wl0T + 32768;
  unsigned short* wl1T = (unsigned short*)(f + 1126656);  // 576x128 bf16
  unsigned short* wr1T = wl1T + 32768;
  unsigned short* p1T  = wl1T + 65536;
  unsigned short* xb   = (unsigned short*)(f + 1163520);  // MROWS x128 bf16
  unsigned short* hb   = (unsigned short*)(f + 4366592);  // MROWS x128 bf16
  float*          hres = f + 7569664;                     // MROWS x128 fp32
  unsigned short* RA   = (unsigned short*)(f + 13975808); // MROWS x256 bf16
  unsigned short* RB   = (unsigned short*)(f + 20381952); // MROWS x256 bf16
  unsigned short* xl0b = RA, *xr0b = RB;
  unsigned short* xl1b = RA, *xr1b = RB;

  // ---- CSR build ---------------------------------------------------------
  hipMemsetAsync(s_loopw, 0, (size_t)(50176 * 3) * sizeof(float), stream);
  deg_kernel<<<(N_EDGES + 255) / 256, 256, 0, stream>>>(ei, ew, s_loopw, deg);
  scan1<<<NPAD / 256, 256, 0, stream>>>(deg, part, bsum);
  scan2<<<1, 256, 0, stream>>>(bsum);
  self_kernel<<<(N_NODES + 255) / 256, 256, 0, stream>>>(s_loopw, deg, part, bsum, csr2);
  scatter_kernel<<<(N_EDGES + 255) / 256, 256, 0, stream>>>(ei, ew, part, bsum,
                                                            cursor, csr2);

  // ---- precision prep ----------------------------------------------------
  cvt_bf16<<<(N_NODES * 128 / 4 + 255) / 256, 256, 0, stream>>>(x, xb, N_NODES * 128 / 4);
  pack_w<<<960, 128, 0, stream>>>(Wl0, Wr0, P0, Wl1, Wr1, P1,
                                  wl0T, wr0T, p0T, wl1T, wr1T, p1T);

  // ---- layer 0 -----------------------------------------------------------
  const int GB = MROWS / 64;   // 782
  gemm_l0<<<GB, 256, 0, stream>>>(xb, wl0T, bl0, br0, pb0, xl0b, xr0b, hres, N_NODES);
  agg0<<<N_NODES / 4, 256, 0, stream>>>(part, bsum, deg, csr2,
                                        xl0b, xr0b, We0, att0, b0, g0, be0, hres, hb);

  // ---- layer 1 -----------------------------------------------------------
  gemm_l1<<<GB, 256, 0, stream>>>(hb, wl1T, bl1, br1, pb1, xl1b, xr1b, out, N_NODES);
  agg1<<<N_NODES / 4, 256, 0, stream>>>(part, bsum, deg, csr2,
                                        xl1b, xr1b, We1, att1, b1, g1, be1, out);
}

// Round 9
// 228.119 us; speedup vs baseline: 5.1856x; 1.0759x over previous
//
#include <hip/hip_runtime.h>
#include <math.h>

#define N_NODES 50000
#define N_EDGES 400000
#define NPAD    50176            // 196*256
#define MROWS   50048            // 782*64, padded row count for gemm outputs
#define HC0 128
#define HC1 256

typedef short    bf16x8 __attribute__((ext_vector_type(8)));
typedef float    f32x4  __attribute__((ext_vector_type(4)));
typedef _Float16 h2     __attribute__((ext_vector_type(2)));
typedef _Float16 h4     __attribute__((ext_vector_type(4)));
typedef _Float16 h8     __attribute__((ext_vector_type(8)));

__device__ inline unsigned short f2bf(float f) {
  union { float f; unsigned u; } v; v.f = f;
  unsigned r = v.u + 0x7FFFu + ((v.u >> 16) & 1u);   // RNE
  return (unsigned short)(r >> 16);
}
__device__ inline h2 mkh2(float a, float b) {
  h2 r; r[0] = (_Float16)a; r[1] = (_Float16)b; return r;
}
__device__ inline float hdot2(h2 a, h2 b, float c) {
#if __has_builtin(__builtin_amdgcn_fdot2)
  return __builtin_amdgcn_fdot2(a, b, c, false);
#else
  return c + (float)a[0] * (float)b[0] + (float)a[1] * (float)b[1];
#endif
}

// ---------------------------------------------------------------------------
// CSR build. Segment per node = 1 (self loop, slot 0) + deg entries of
// int2 {src, w_bits}. Scan is over deg+1.
// ---------------------------------------------------------------------------
__global__ void deg_kernel(const int* __restrict__ ei, const float* __restrict__ ew,
                           float* __restrict__ s, int* __restrict__ deg) {
  int e = blockIdx.x * 256 + threadIdx.x;
  if (e < N_EDGES) {
    int dst = ei[N_EDGES + e];
    atomicAdd(&s[dst], ew[e]);
    atomicAdd(&deg[dst], 1);
  }
}

__global__ void scan1(const int* __restrict__ deg, int* __restrict__ part,
                      int* __restrict__ bsum) {
  int i = blockIdx.x * 256 + threadIdx.x;
  int lane = threadIdx.x & 63, wid = threadIdx.x >> 6;
  int v = (i < N_NODES) ? deg[i] + 1 : 0;
  int inc = v;
#pragma unroll
  for (int d = 1; d < 64; d <<= 1) { int y = __shfl_up(inc, d, 64); if (lane >= d) inc += y; }
  __shared__ int wsum[4];
  if (lane == 63) wsum[wid] = inc;
  __syncthreads();
  int off = 0;
#pragma unroll
  for (int w = 0; w < 4; ++w) { int sv = wsum[w]; if (w < wid) off += sv; }
  part[i] = inc - v + off;
  if (threadIdx.x == 0) bsum[blockIdx.x] = wsum[0] + wsum[1] + wsum[2] + wsum[3];
}

__global__ void scan2(int* __restrict__ bsum) {
  int t = threadIdx.x;
  int lane = t & 63, wid = t >> 6;
  int v = (t < 196) ? bsum[t] : 0;
  int inc = v;
#pragma unroll
  for (int d = 1; d < 64; d <<= 1) { int y = __shfl_up(inc, d, 64); if (lane >= d) inc += y; }
  __shared__ int wsum[4];
  if (lane == 63) wsum[wid] = inc;
  __syncthreads();
  int off = 0;
#pragma unroll
  for (int w = 0; w < 4; ++w) { int sv = wsum[w]; if (w < wid) off += sv; }
  if (t < 196) bsum[t] = inc - v + off;
}

__global__ void self_kernel(const float* __restrict__ s, const int* __restrict__ deg,
                            const int* __restrict__ part, const int* __restrict__ bsum,
                            int2* __restrict__ csr2) {
  int i = blockIdx.x * 256 + threadIdx.x;
  if (i >= N_NODES) return;
  float w = s[i] / fmaxf((float)deg[i], 1.0f);
  int start = part[i] + bsum[i >> 8];
  csr2[start] = make_int2(i, __float_as_int(w));
}

__global__ void scatter_kernel(const int* __restrict__ ei, const float* __restrict__ ew,
                               const int* __restrict__ part, const int* __restrict__ bsum,
                               int* __restrict__ cursor, int2* __restrict__ csr2) {
  int e = blockIdx.x * 256 + threadIdx.x;
  if (e >= N_EDGES) return;
  int dst = ei[N_EDGES + e];
  int pos = atomicAdd(&cursor[dst], 1);
  int idx = part[dst] + bsum[dst >> 8] + 1 + pos;
  csr2[idx] = make_int2(ei[e], __float_as_int(ew[e]));
}

// ---------------------------------------------------------------------------
// fp32 -> bf16 (vectorized)
// ---------------------------------------------------------------------------
__global__ void cvt_bf16(const float* __restrict__ in, unsigned short* __restrict__ out,
                         int n4) {
  int i = blockIdx.x * 256 + threadIdx.x;
  if (i >= n4) return;
  float4 v = ((const float4*)in)[i];
  ushort4 o; o.x = f2bf(v.x); o.y = f2bf(v.y); o.z = f2bf(v.z); o.w = f2bf(v.w);
  ((ushort4*)out)[i] = o;
}

// ---------------------------------------------------------------------------
// weight pack: W[128][N] fp32 -> BT[N][128] bf16
// ---------------------------------------------------------------------------
__global__ void pack_w(const float* __restrict__ Wl0, const float* __restrict__ Wr0,
                       const float* __restrict__ P0,  const float* __restrict__ Wl1,
                       const float* __restrict__ Wr1, const float* __restrict__ P1,
                       unsigned short* __restrict__ o_wl0, unsigned short* __restrict__ o_wr0,
                       unsigned short* __restrict__ o_p0,  unsigned short* __restrict__ o_wl1,
                       unsigned short* __restrict__ o_wr1, unsigned short* __restrict__ o_p1) {
  int n = blockIdx.x, k = threadIdx.x;
  const float* W; unsigned short* O; int N, nl;
  if      (n < 128) { W = Wl0; O = o_wl0; N = 128; nl = n; }
  else if (n < 256) { W = Wr0; O = o_wr0; N = 128; nl = n - 128; }
  else if (n < 384) { W = P0;  O = o_p0;  N = 128; nl = n - 256; }
  else if (n < 640) { W = Wl1; O = o_wl1; N = 256; nl = n - 384; }
  else if (n < 896) { W = Wr1; O = o_wr1; N = 256; nl = n - 640; }
  else              { W = P1;  O = o_p1;  N = 64;  nl = n - 896; }
  O[nl * 128 + k] = f2bf(W[(size_t)k * N + nl]);
}

// ---------------------------------------------------------------------------
// Merged GEMM layer 0: xl/xr outputs now fp16 (h4 stores), hres fp32.
// ---------------------------------------------------------------------------
__global__ __launch_bounds__(256) void gemm_l0(
    const unsigned short* __restrict__ A, const unsigned short* __restrict__ BT,
    const float* __restrict__ bias0, const float* __restrict__ bias1,
    const float* __restrict__ bias2,
    _Float16* __restrict__ o_xl, _Float16* __restrict__ o_xr,
    float* __restrict__ o_h, int M) {
  __shared__ unsigned short As[64 * 136];   // 272B pitch
  const int tid = threadIdx.x;
  const int rbase = blockIdx.x * 64;
#pragma unroll
  for (int i = 0; i < 4; ++i) {
    int c = i * 256 + tid;
    int row = c >> 4, slot = c & 15;
    int ar = rbase + row; if (ar > M - 1) ar = M - 1;
    uint4 v = *(const uint4*)(A + (size_t)ar * 128 + slot * 8);
    *(uint4*)(As + row * 136 + slot * 8) = v;
  }
  __syncthreads();
  const int w = tid >> 6, l = tid & 63;
  const int lr = l & 15, lg = l >> 4;
#pragma unroll
  for (int i = 0; i < 6; ++i) {
    const int ct = w * 6 + i;
    const bf16x8* bp = (const bf16x8*)(BT + (size_t)(ct * 16 + lr) * 128 + lg * 8);
    bf16x8 b0 = bp[0], b1 = bp[4], b2 = bp[8], b3 = bp[12];
    const int colb = ct * 16 + lg * 4;
    const int cc = colb & 127;
    const float* bptr = (ct < 8 ? bias0 : (ct < 16 ? bias1 : bias2));
    float4 bv = *(const float4*)(bptr + cc);
#pragma unroll
    for (int rt = 0; rt < 4; ++rt) {
      const unsigned short* ap = As + (rt * 16 + lr) * 136 + lg * 8;
      bf16x8 a0 = *(const bf16x8*)(ap);
      bf16x8 a1 = *(const bf16x8*)(ap + 32);
      bf16x8 a2 = *(const bf16x8*)(ap + 64);
      bf16x8 a3 = *(const bf16x8*)(ap + 96);
      f32x4 acc = {0.f, 0.f, 0.f, 0.f};
      acc = __builtin_amdgcn_mfma_f32_16x16x32_bf16(b0, a0, acc, 0, 0, 0);
      acc = __builtin_amdgcn_mfma_f32_16x16x32_bf16(b1, a1, acc, 0, 0, 0);
      acc = __builtin_amdgcn_mfma_f32_16x16x32_bf16(b2, a2, acc, 0, 0, 0);
      acc = __builtin_amdgcn_mfma_f32_16x16x32_bf16(b3, a3, acc, 0, 0, 0);
      const int row = rbase + rt * 16 + lr;
      if (ct < 16) {
        h4 o;
        o[0] = (_Float16)(acc[0] + bv.x); o[1] = (_Float16)(acc[1] + bv.y);
        o[2] = (_Float16)(acc[2] + bv.z); o[3] = (_Float16)(acc[3] + bv.w);
        *(h4*)((ct < 8 ? o_xl : o_xr) + (size_t)row * 128 + cc) = o;
      } else {
        float4 o;
        o.x = acc[0] + bv.x; o.y = acc[1] + bv.y;
        o.z = acc[2] + bv.z; o.w = acc[3] + bv.w;
        *(float4*)(o_h + (size_t)row * 128 + cc) = o;
      }
    }
  }
}

// ---------------------------------------------------------------------------
// Merged GEMM layer 1: xl/xr outputs fp16, residual out fp32 (guarded).
// ---------------------------------------------------------------------------
__global__ __launch_bounds__(256) void gemm_l1(
    const unsigned short* __restrict__ A, const unsigned short* __restrict__ BT,
    const float* __restrict__ bias0, const float* __restrict__ bias1,
    const float* __restrict__ bias2,
    _Float16* __restrict__ o_xl, _Float16* __restrict__ o_xr,
    float* __restrict__ o_out, int M) {
  __shared__ unsigned short As[64 * 136];
  const int tid = threadIdx.x;
  const int rbase = blockIdx.x * 64;
#pragma unroll
  for (int i = 0; i < 4; ++i) {
    int c = i * 256 + tid;
    int row = c >> 4, slot = c & 15;
    int ar = rbase + row; if (ar > M - 1) ar = M - 1;
    uint4 v = *(const uint4*)(A + (size_t)ar * 128 + slot * 8);
    *(uint4*)(As + row * 136 + slot * 8) = v;
  }
  __syncthreads();
  const int w = tid >> 6, l = tid & 63;
  const int lr = l & 15, lg = l >> 4;
#pragma unroll
  for (int i = 0; i < 9; ++i) {
    const int ct = w * 9 + i;
    const bf16x8* bp = (const bf16x8*)(BT + (size_t)(ct * 16 + lr) * 128 + lg * 8);
    bf16x8 b0 = bp[0], b1 = bp[4], b2 = bp[8], b3 = bp[12];
    const int colb = ct * 16 + lg * 4;
    const int cc = (ct < 32) ? (colb & 255) : (colb - 512);
    const float* bptr = (ct < 16 ? bias0 : (ct < 32 ? bias1 : bias2));
    float4 bv = *(const float4*)(bptr + cc);
#pragma unroll
    for (int rt = 0; rt < 4; ++rt) {
      const unsigned short* ap = As + (rt * 16 + lr) * 136 + lg * 8;
      bf16x8 a0 = *(const bf16x8*)(ap);
      bf16x8 a1 = *(const bf16x8*)(ap + 32);
      bf16x8 a2 = *(const bf16x8*)(ap + 64);
      bf16x8 a3 = *(const bf16x8*)(ap + 96);
      f32x4 acc = {0.f, 0.f, 0.f, 0.f};
      acc = __builtin_amdgcn_mfma_f32_16x16x32_bf16(b0, a0, acc, 0, 0, 0);
      acc = __builtin_amdgcn_mfma_f32_16x16x32_bf16(b1, a1, acc, 0, 0, 0);
      acc = __builtin_amdgcn_mfma_f32_16x16x32_bf16(b2, a2, acc, 0, 0, 0);
      acc = __builtin_amdgcn_mfma_f32_16x16x32_bf16(b3, a3, acc, 0, 0, 0);
      const int row = rbase + rt * 16 + lr;
      if (ct < 32) {
        h4 o;
        o[0] = (_Float16)(acc[0] + bv.x); o[1] = (_Float16)(acc[1] + bv.y);
        o[2] = (_Float16)(acc[2] + bv.z); o[3] = (_Float16)(acc[3] + bv.w);
        *(h4*)((ct < 16 ? o_xl : o_xr) + (size_t)row * 256 + cc) = o;
      } else if (row < M) {
        float4 o;
        o.x = acc[0] + bv.x; o.y = acc[1] + bv.y;
        o.z = acc[2] + bv.z; o.w = acc[3] + bv.w;
        *(float4*)(o_out + (size_t)row * 64 + cc) = o;
      }
    }
  }
}

// ---------------------------------------------------------------------------
// per-edge steps, packed f16 (VOP3P): pk_fma/pk_add/pk_mul/pk_max + fdot2.
// ---------------------------------------------------------------------------
__device__ inline void edge_step0(int2 rec, h8 a8, bool valid,
                                  const h2* xrv2, const h2* wef2, const h2* att2,
                                  h2* acc2, float& den) {
  _Float16 wh = (_Float16)__int_as_float(rec.y);
  h2 w2; w2[0] = wh; w2[1] = wh;
  const h2 c02 = mkh2(0.2f, 0.2f);
  int4 ai = __builtin_bit_cast(int4, a8);
  h2 av[4];
  av[0] = __builtin_bit_cast(h2, ai.x); av[1] = __builtin_bit_cast(h2, ai.y);
  av[2] = __builtin_bit_cast(h2, ai.z); av[3] = __builtin_bit_cast(h2, ai.w);
  float c = 0.f;
#pragma unroll
  for (int k = 0; k < 4; ++k) {
    h2 sv = av[k] + (w2 * wef2[k] + xrv2[k]);
    h2 lk = __builtin_elementwise_max(sv, sv * c02);
    c = hdot2(lk, att2[k], c);
  }
  c += __shfl_xor(c, 1, 64); c += __shfl_xor(c, 2, 64);   // head = 4 lanes
  float p = valid ? __expf(c) : 0.f;
  den += p;
  _Float16 ph = (_Float16)p;
  h2 p2; p2[0] = ph; p2[1] = ph;
#pragma unroll
  for (int k = 0; k < 4; ++k) acc2[k] = p2 * av[k] + acc2[k];
}

__device__ inline void edge_step1(int2 rec, h8 a8, bool valid,
                                  const h2* xrv2, const h2* wef2, const h2* att2,
                                  h2* acc2, float& den) {
  _Float16 wh = (_Float16)__int_as_float(rec.y);
  h2 w2; w2[0] = wh; w2[1] = wh;
  const h2 c02 = mkh2(0.2f, 0.2f);
  int4 ai = __builtin_bit_cast(int4, a8);
  h2 av[4];
  av[0] = __builtin_bit_cast(h2, ai.x); av[1] = __builtin_bit_cast(h2, ai.y);
  av[2] = __builtin_bit_cast(h2, ai.z); av[3] = __builtin_bit_cast(h2, ai.w);
  float c = 0.f;
#pragma unroll
  for (int k = 0; k < 4; ++k) {
    h2 sv = av[k] + (w2 * wef2[k] + xrv2[k]);
    h2 lk = __builtin_elementwise_max(sv, sv * c02);
    c = hdot2(lk, att2[k], c);
  }
  c += __shfl_xor(c, 1, 64); c += __shfl_xor(c, 2, 64); c += __shfl_xor(c, 4, 64);
  float p = valid ? __expf(c) : 0.f;
  den += p;
  _Float16 ph = (_Float16)p;
  h2 p2; p2[0] = ph; p2[1] = ph;
#pragma unroll
  for (int k = 0; k < 4; ++k) acc2[k] = p2 * av[k] + acc2[k];
}

// ---------------------------------------------------------------------------
// Layer-0 aggregation: 1 wave/node, 4 edge groups x unroll 2; packed f16.
// ---------------------------------------------------------------------------
__global__ __launch_bounds__(256) void agg0(
    const int* __restrict__ part, const int* __restrict__ bsum,
    const int* __restrict__ deg, const int2* __restrict__ csr2,
    const _Float16* __restrict__ xl, const _Float16* __restrict__ xr,
    const float* __restrict__ We, const float* __restrict__ att,
    const float* __restrict__ b, const float* __restrict__ g,
    const float* __restrict__ be, const float* __restrict__ hres,
    unsigned short* __restrict__ hout) {
  const int wid = threadIdx.x >> 6, l = threadIdx.x & 63;
  const int n = blockIdx.x * 4 + wid;
  const int grp = l >> 4, cl = l & 15, c0 = cl * 8;
  h2 xrv2[4], wef2[4], att2[4];
  {
    h8 x8 = *(const h8*)(xr + (size_t)n * HC0 + c0);
    int4 xi = __builtin_bit_cast(int4, x8);
    xrv2[0] = __builtin_bit_cast(h2, xi.x); xrv2[1] = __builtin_bit_cast(h2, xi.y);
    xrv2[2] = __builtin_bit_cast(h2, xi.z); xrv2[3] = __builtin_bit_cast(h2, xi.w);
    float4 w0 = *(const float4*)(We + c0),  w1 = *(const float4*)(We + c0 + 4);
    float4 t0 = *(const float4*)(att + c0), t1 = *(const float4*)(att + c0 + 4);
    wef2[0] = mkh2(w0.x, w0.y); wef2[1] = mkh2(w0.z, w0.w);
    wef2[2] = mkh2(w1.x, w1.y); wef2[3] = mkh2(w1.z, w1.w);
    att2[0] = mkh2(t0.x, t0.y); att2[1] = mkh2(t0.z, t0.w);
    att2[2] = mkh2(t1.x, t1.y); att2[3] = mkh2(t1.z, t1.w);
  }
  const int start = part[n] + bsum[n >> 8];
  const int cnt   = deg[n] + 1;
  const int last  = start + cnt - 1;
  h2 acc2[4] = {};
  float den = 0.f;
#define IDX0(E) (start + (E) > last ? last : start + (E))
  int2 rA0 = csr2[IDX0(grp)],      rA1 = csr2[IDX0(grp + 4)];
  int2 rB0 = csr2[IDX0(grp + 8)],  rB1 = csr2[IDX0(grp + 12)];
  h8 aA0 = *(const h8*)(xl + (size_t)rA0.x * HC0 + c0);
  h8 aA1 = *(const h8*)(xl + (size_t)rA1.x * HC0 + c0);
  const int trips = (cnt + 7) >> 3;
  int e = grp;
  for (int t = 0; t < trips; ++t) {
    int2 rC0 = csr2[IDX0(e + 16)], rC1 = csr2[IDX0(e + 20)];
    h8 aB0 = *(const h8*)(xl + (size_t)rB0.x * HC0 + c0);
    h8 aB1 = *(const h8*)(xl + (size_t)rB1.x * HC0 + c0);
    edge_step0(rA0, aA0, e < cnt,     xrv2, wef2, att2, acc2, den);
    edge_step0(rA1, aA1, e + 4 < cnt, xrv2, wef2, att2, acc2, den);
    rA0 = rB0; rA1 = rB1; rB0 = rC0; rB1 = rC1; aA0 = aB0; aA1 = aB1;
    e += 8;
  }
#undef IDX0
  den += __shfl_xor(den, 16, 64); den += __shfl_xor(den, 32, 64);
#pragma unroll
  for (int k = 0; k < 4; ++k) {
    int b16 = __shfl_xor(__builtin_bit_cast(int, acc2[k]), 16, 64);
    acc2[k] = acc2[k] + __builtin_bit_cast(h2, b16);
    int b32 = __shfl_xor(__builtin_bit_cast(int, acc2[k]), 32, 64);
    acc2[k] = acc2[k] + __builtin_bit_cast(h2, b32);
  }
  float v[8], s1 = 0.f, s2 = 0.f;
  float dinv = 1.f / den;
  {
    float4 b0v = *(const float4*)(b + c0), b1v = *(const float4*)(b + c0 + 4);
    float bb[8] = {b0v.x,b0v.y,b0v.z,b0v.w,b1v.x,b1v.y,b1v.z,b1v.w};
#pragma unroll
    for (int j = 0; j < 8; ++j) {
      float t = (float)acc2[j >> 1][j & 1] * dinv + bb[j];
      t = t > 0.f ? t : __expf(t) - 1.f;
      v[j] = t; s1 += t; s2 += t * t;
    }
  }
  s1 += __shfl_xor(s1, 1, 64); s2 += __shfl_xor(s2, 1, 64);
  s1 += __shfl_xor(s1, 2, 64); s2 += __shfl_xor(s2, 2, 64);
  s1 += __shfl_xor(s1, 4, 64); s2 += __shfl_xor(s2, 4, 64);
  s1 += __shfl_xor(s1, 8, 64); s2 += __shfl_xor(s2, 8, 64);
  float mean = s1 * (1.f / 128.f);
  float inv  = rsqrtf(s2 * (1.f / 128.f) - mean * mean + 1e-5f);
  if (grp == 0) {
    float4 g0v = *(const float4*)(g + c0),  g1v = *(const float4*)(g + c0 + 4);
    float4 e0v = *(const float4*)(be + c0), e1v = *(const float4*)(be + c0 + 4);
    float4 h0v = *(const float4*)(hres + (size_t)n * HC0 + c0);
    float4 h1v = *(const float4*)(hres + (size_t)n * HC0 + c0 + 4);
    float gg[8] = {g0v.x,g0v.y,g0v.z,g0v.w,g1v.x,g1v.y,g1v.z,g1v.w};
    float ee[8] = {e0v.x,e0v.y,e0v.z,e0v.w,e1v.x,e1v.y,e1v.z,e1v.w};
    float hh[8] = {h0v.x,h0v.y,h0v.z,h0v.w,h1v.x,h1v.y,h1v.z,h1v.w};
    bf16x8 o;
#pragma unroll
    for (int j = 0; j < 8; ++j)
      o[j] = (short)f2bf((v[j] - mean) * inv * gg[j] + ee[j] + hh[j]);
    *(bf16x8*)(hout + (size_t)n * HC0 + c0) = o;
  }
}

// ---------------------------------------------------------------------------
// Layer-1 aggregation: 1 wave/node, 2 edge groups x unroll 2; packed f16;
// barrier-free epilogue (head-mean via shfl 8/16, LN(64) via shfl 1/2/4).
// ---------------------------------------------------------------------------
__global__ __launch_bounds__(256) void agg1(
    const int* __restrict__ part, const int* __restrict__ bsum,
    const int* __restrict__ deg, const int2* __restrict__ csr2,
    const _Float16* __restrict__ xl, const _Float16* __restrict__ xr,
    const float* __restrict__ We, const float* __restrict__ att,
    const float* __restrict__ b, const float* __restrict__ g,
    const float* __restrict__ be, float* __restrict__ out) {
  const int wid = threadIdx.x >> 6, l = threadIdx.x & 63;
  const int n = blockIdx.x * 4 + wid;
  const int grp = l >> 5, cl = l & 31, c0 = cl * 8;
  h2 xrv2[4], wef2[4], att2[4];
  {
    h8 x8 = *(const h8*)(xr + (size_t)n * HC1 + c0);
    int4 xi = __builtin_bit_cast(int4, x8);
    xrv2[0] = __builtin_bit_cast(h2, xi.x); xrv2[1] = __builtin_bit_cast(h2, xi.y);
    xrv2[2] = __builtin_bit_cast(h2, xi.z); xrv2[3] = __builtin_bit_cast(h2, xi.w);
    float4 w0 = *(const float4*)(We + c0),  w1 = *(const float4*)(We + c0 + 4);
    float4 t0 = *(const float4*)(att + c0), t1 = *(const float4*)(att + c0 + 4);
    wef2[0] = mkh2(w0.x, w0.y); wef2[1] = mkh2(w0.z, w0.w);
    wef2[2] = mkh2(w1.x, w1.y); wef2[3] = mkh2(w1.z, w1.w);
    att2[0] = mkh2(t0.x, t0.y); att2[1] = mkh2(t0.z, t0.w);
    att2[2] = mkh2(t1.x, t1.y); att2[3] = mkh2(t1.z, t1.w);
  }
  const int start = part[n] + bsum[n >> 8];
  const int cnt   = deg[n] + 1;
  const int last  = start + cnt - 1;
  h2 acc2[4] = {};
  float den = 0.f;
#define IDX1(E) (start + (E) > last ? last : start + (E))
  int2 rA0 = csr2[IDX1(grp)],     rA1 = csr2[IDX1(grp + 2)];
  int2 rB0 = csr2[IDX1(grp + 4)], rB1 = csr2[IDX1(grp + 6)];
  h8 aA0 = *(const h8*)(xl + (size_t)rA0.x * HC1 + c0);
  h8 aA1 = *(const h8*)(xl + (size_t)rA1.x * HC1 + c0);
  const int trips = (cnt + 3) >> 2;
  int e = grp;
  for (int t = 0; t < trips; ++t) {
    int2 rC0 = csr2[IDX1(e + 8)], rC1 = csr2[IDX1(e + 10)];
    h8 aB0 = *(const h8*)(xl + (size_t)rB0.x * HC1 + c0);
    h8 aB1 = *(const h8*)(xl + (size_t)rB1.x * HC1 + c0);
    edge_step1(rA0, aA0, e < cnt,     xrv2, wef2, att2, acc2, den);
    edge_step1(rA1, aA1, e + 2 < cnt, xrv2, wef2, att2, acc2, den);
    rA0 = rB0; rA1 = rB1; rB0 = rC0; rB1 = rC1; aA0 = aB0; aA1 = aB1;
    e += 4;
  }
#undef IDX1
  den += __shfl_xor(den, 32, 64);
#pragma unroll
  for (int k = 0; k < 4; ++k) {
    int b32 = __shfl_xor(__builtin_bit_cast(int, acc2[k]), 32, 64);
    acc2[k] = acc2[k] + __builtin_bit_cast(h2, b32);
  }
  // head-mean in-wave: lane cl holds head h=cl>>3, output block oc=(cl&7)*8.
  float dinv = 1.f / den;
  float v[8], s1 = 0.f, s2 = 0.f;
  const int oc = (cl & 7) * 8;
  {
    float4 b0v = *(const float4*)(b + oc), b1v = *(const float4*)(b + oc + 4);
    float bb[8] = {b0v.x,b0v.y,b0v.z,b0v.w,b1v.x,b1v.y,b1v.z,b1v.w};
#pragma unroll
    for (int j = 0; j < 8; ++j) {
      float t = (float)acc2[j >> 1][j & 1] * dinv;
      t += __shfl_xor(t, 8, 64);
      t += __shfl_xor(t, 16, 64);
      t = t * 0.25f + bb[j];
      t = t > 0.f ? t : __expf(t) - 1.f;       // ELU
      v[j] = t; s1 += t; s2 += t * t;
    }
  }
  s1 += __shfl_xor(s1, 1, 64); s2 += __shfl_xor(s2, 1, 64);
  s1 += __shfl_xor(s1, 2, 64); s2 += __shfl_xor(s2, 2, 64);
  s1 += __shfl_xor(s1, 4, 64); s2 += __shfl_xor(s2, 4, 64);
  float mean = s1 * (1.f / 64.f);
  float inv  = rsqrtf(s2 * (1.f / 64.f) - mean * mean + 1e-5f);
  if (grp == 0 && cl < 8) {
    float4 g0v = *(const float4*)(g + oc),  g1v = *(const float4*)(g + oc + 4);
    float4 e0v = *(const float4*)(be + oc), e1v = *(const float4*)(be + oc + 4);
    float gg[8] = {g0v.x,g0v.y,g0v.z,g0v.w,g1v.x,g1v.y,g1v.z,g1v.w};
    float ee[8] = {e0v.x,e0v.y,e0v.z,e0v.w,e1v.x,e1v.y,e1v.z,e1v.w};
    float* po = out + (size_t)n * 64 + oc;
    float4 o0 = *(const float4*)po, o1 = *(const float4*)(po + 4);
    o0.x += (v[0] - mean) * inv * gg[0] + ee[0];
    o0.y += (v[1] - mean) * inv * gg[1] + ee[1];
    o0.z += (v[2] - mean) * inv * gg[2] + ee[2];
    o0.w += (v[3] - mean) * inv * gg[3] + ee[3];
    o1.x += (v[4] - mean) * inv * gg[4] + ee[4];
    o1.y += (v[5] - mean) * inv * gg[5] + ee[5];
    o1.z += (v[6] - mean) * inv * gg[6] + ee[6];
    o1.w += (v[7] - mean) * inv * gg[7] + ee[7];
    *(float4*)po = o0; *(float4*)(po + 4) = o1;
  }
}

// ---------------------------------------------------------------------------
extern "C" void kernel_launch(void* const* d_in, const int* in_sizes, int n_in,
                              void* d_out, int out_size, void* d_ws, size_t ws_size,
                              hipStream_t stream) {
  const float* x    = (const float*)d_in[0];
  const int*   ei   = (const int*)  d_in[1];
  const float* ew   = (const float*)d_in[2];
  const float* Wl0  = (const float*)d_in[3];
  const float* bl0  = (const float*)d_in[4];
  const float* Wr0  = (const float*)d_in[5];
  const float* br0  = (const float*)d_in[6];
  const float* We0  = (const float*)d_in[7];
  const float* att0 = (const float*)d_in[8];
  const float* b0   = (const float*)d_in[9];
  const float* g0   = (const float*)d_in[10];
  const float* be0  = (const float*)d_in[11];
  const float* Wl1  = (const float*)d_in[12];
  const float* bl1  = (const float*)d_in[13];
  const float* Wr1  = (const float*)d_in[14];
  const float* br1  = (const float*)d_in[15];
  const float* We1  = (const float*)d_in[16];
  const float* att1 = (const float*)d_in[17];
  const float* b1   = (const float*)d_in[18];
  const float* g1   = (const float*)d_in[19];
  const float* be1  = (const float*)d_in[20];
  const float* P0   = (const float*)d_in[21];
  const float* pb0  = (const float*)d_in[22];
  const float* P1   = (const float*)d_in[23];
  const float* pb1  = (const float*)d_in[24];
  float* out = (float*)d_out;

  // workspace layout (32-bit words)
  float* f        = (float*)d_ws;
  float* s_loopw  = f;                               // 50176
  int*   deg      = (int*)(f + 50176);               // 50176
  int*   cursor   = (int*)(f + 100352);              // 50176
  int*   part     = (int*)(f + 150528);              // 50176
  int*   bsum     = (int*)(f + 200704);              // 256
  int2*  csr2     = (int2*)(f + 200960);             // 450560 int2 = 901120 w
  unsigned short* wl0T = (unsigned short*)(f + 1102080);  // 384x128 bf16
  unsigned short* wr0T = wl0T + 16384;
  unsigned short* p0T  = wl0T + 32768;
  unsigned short* wl1T = (unsigned short*)(f + 1126656);  // 576x128 bf16
  unsigned short* wr1T = wl1T + 32768;
  unsigned short* p1T  = wl1T + 65536;
  unsigned short* xb   = (unsigned short*)(f + 1163520);  // MROWS x128 bf16
  unsigned short* hb   = (unsigned short*)(f + 4366592);  // MROWS x128 bf16
  float*          hres = f + 7569664;                     // MROWS x128 fp32
  _Float16*       RA   = (_Float16*)(f + 13975808);       // MROWS x256 f16
  _Float16*       RB   = (_Float16*)(f + 20381952);       // MROWS x256 f16
  _Float16* xl0h = RA, *xr0h = RB;
  _Float16* xl1h = RA, *xr1h = RB;

  // ---- CSR build ---------------------------------------------------------
  hipMemsetAsync(s_loopw, 0, (size_t)(50176 * 3) * sizeof(float), stream);
  deg_kernel<<<(N_EDGES + 255) / 256, 256, 0, stream>>>(ei, ew, s_loopw, deg);
  scan1<<<NPAD / 256, 256, 0, stream>>>(deg, part, bsum);
  scan2<<<1, 256, 0, stream>>>(bsum);
  self_kernel<<<(N_NODES + 255) / 256, 256, 0, stream>>>(s_loopw, deg, part, bsum, csr2);
  scatter_kernel<<<(N_EDGES + 255) / 256, 256, 0, stream>>>(ei, ew, part, bsum,
                                                            cursor, csr2);

  // ---- precision prep ----------------------------------------------------
  cvt_bf16<<<(N_NODES * 128 / 4 + 255) / 256, 256, 0, stream>>>(x, xb, N_NODES * 128 / 4);
  pack_w<<<960, 128, 0, stream>>>(Wl0, Wr0, P0, Wl1, Wr1, P1,
                                  wl0T, wr0T, p0T, wl1T, wr1T, p1T);

  // ---- layer 0 -----------------------------------------------------------
  const int GB = MROWS / 64;   // 782
  gemm_l0<<<GB, 256, 0, stream>>>(xb, wl0T, bl0, br0, pb0, xl0h, xr0h, hres, N_NODES);
  agg0<<<N_NODES / 4, 256, 0, stream>>>(part, bsum, deg, csr2,
                                        xl0h, xr0h, We0, att0, b0, g0, be0, hres, hb);

  // ---- layer 1 -----------------------------------------------------------
  gemm_l1<<<GB, 256, 0, stream>>>(hb, wl1T, bl1, br1, pb1, xl1h, xr1h, out, N_NODES);
  agg1<<<N_NODES / 4, 256, 0, stream>>>(part, bsum, deg, csr2,
                                        xl1h, xr1h, We1, att1, b1, g1, be1, out);
}

// Round 10
// 223.267 us; speedup vs baseline: 5.2983x; 1.0217x over previous
//
#include <hip/hip_runtime.h>
#include <math.h>

#define N_NODES 50000
#define N_EDGES 400000
#define NPAD    50176            // 196*256
#define MROWS   50048            // 782*64, padded row count for gemm outputs
#define HC0 128
#define HC1 256
#define CSR_TOTAL (N_NODES + N_EDGES)   // 450000 records + 64 tail pad

typedef short    bf16x8 __attribute__((ext_vector_type(8)));
typedef float    f32x4  __attribute__((ext_vector_type(4)));
typedef _Float16 h2     __attribute__((ext_vector_type(2)));
typedef _Float16 h4     __attribute__((ext_vector_type(4)));
typedef _Float16 h8     __attribute__((ext_vector_type(8)));

__device__ inline unsigned short f2bf(float f) {
  union { float f; unsigned u; } v; v.f = f;
  unsigned r = v.u + 0x7FFFu + ((v.u >> 16) & 1u);   // RNE
  return (unsigned short)(r >> 16);
}
__device__ inline h2 mkh2(float a, float b) {
  h2 r; r[0] = (_Float16)a; r[1] = (_Float16)b; return r;
}
__device__ inline float hdot2(h2 a, h2 b, float c) {
#if __has_builtin(__builtin_amdgcn_fdot2)
  return __builtin_amdgcn_fdot2(a, b, c, false);
#else
  return c + (float)a[0] * (float)b[0] + (float)a[1] * (float)b[1];
#endif
}

// ---------------------------------------------------------------------------
// CSR build. Segment per node = 1 (self loop, slot 0) + deg entries of
// int2 {src, w_bits}. 64 zeroed tail records allow clamp-free over-read.
// ---------------------------------------------------------------------------
__global__ void deg_kernel(const int* __restrict__ ei, const float* __restrict__ ew,
                           float* __restrict__ s, int* __restrict__ deg) {
  int e = blockIdx.x * 256 + threadIdx.x;
  if (e < N_EDGES) {
    int dst = ei[N_EDGES + e];
    atomicAdd(&s[dst], ew[e]);
    atomicAdd(&deg[dst], 1);
  }
}

__global__ void scan1(const int* __restrict__ deg, int* __restrict__ part,
                      int* __restrict__ bsum) {
  int i = blockIdx.x * 256 + threadIdx.x;
  int lane = threadIdx.x & 63, wid = threadIdx.x >> 6;
  int v = (i < N_NODES) ? deg[i] + 1 : 0;
  int inc = v;
#pragma unroll
  for (int d = 1; d < 64; d <<= 1) { int y = __shfl_up(inc, d, 64); if (lane >= d) inc += y; }
  __shared__ int wsum[4];
  if (lane == 63) wsum[wid] = inc;
  __syncthreads();
  int off = 0;
#pragma unroll
  for (int w = 0; w < 4; ++w) { int sv = wsum[w]; if (w < wid) off += sv; }
  part[i] = inc - v + off;
  if (threadIdx.x == 0) bsum[blockIdx.x] = wsum[0] + wsum[1] + wsum[2] + wsum[3];
}

__global__ void scan2(int* __restrict__ bsum) {
  int t = threadIdx.x;
  int lane = t & 63, wid = t >> 6;
  int v = (t < 196) ? bsum[t] : 0;
  int inc = v;
#pragma unroll
  for (int d = 1; d < 64; d <<= 1) { int y = __shfl_up(inc, d, 64); if (lane >= d) inc += y; }
  __shared__ int wsum[4];
  if (lane == 63) wsum[wid] = inc;
  __syncthreads();
  int off = 0;
#pragma unroll
  for (int w = 0; w < 4; ++w) { int sv = wsum[w]; if (w < wid) off += sv; }
  if (t < 196) bsum[t] = inc - v + off;
}

__global__ void self_kernel(const float* __restrict__ s, const int* __restrict__ deg,
                            const int* __restrict__ part, const int* __restrict__ bsum,
                            int2* __restrict__ csr2) {
  int i = blockIdx.x * 256 + threadIdx.x;
  if (i >= N_NODES) return;
  float w = s[i] / fmaxf((float)deg[i], 1.0f);
  int start = part[i] + bsum[i >> 8];
  csr2[start] = make_int2(i, __float_as_int(w));
}

__global__ void scatter_kernel(const int* __restrict__ ei, const float* __restrict__ ew,
                               const int* __restrict__ part, const int* __restrict__ bsum,
                               int* __restrict__ cursor, int2* __restrict__ csr2) {
  int e = blockIdx.x * 256 + threadIdx.x;
  if (e >= N_EDGES) return;
  int dst = ei[N_EDGES + e];
  int pos = atomicAdd(&cursor[dst], 1);
  int idx = part[dst] + bsum[dst >> 8] + 1 + pos;
  csr2[idx] = make_int2(ei[e], __float_as_int(ew[e]));
}

// ---------------------------------------------------------------------------
// weight pack: W[128][N] fp32 -> BT[N][128] bf16
// ---------------------------------------------------------------------------
__global__ void pack_w(const float* __restrict__ Wl0, const float* __restrict__ Wr0,
                       const float* __restrict__ P0,  const float* __restrict__ Wl1,
                       const float* __restrict__ Wr1, const float* __restrict__ P1,
                       unsigned short* __restrict__ o_wl0, unsigned short* __restrict__ o_wr0,
                       unsigned short* __restrict__ o_p0,  unsigned short* __restrict__ o_wl1,
                       unsigned short* __restrict__ o_wr1, unsigned short* __restrict__ o_p1) {
  int n = blockIdx.x, k = threadIdx.x;
  const float* W; unsigned short* O; int N, nl;
  if      (n < 128) { W = Wl0; O = o_wl0; N = 128; nl = n; }
  else if (n < 256) { W = Wr0; O = o_wr0; N = 128; nl = n - 128; }
  else if (n < 384) { W = P0;  O = o_p0;  N = 128; nl = n - 256; }
  else if (n < 640) { W = Wl1; O = o_wl1; N = 256; nl = n - 384; }
  else if (n < 896) { W = Wr1; O = o_wr1; N = 256; nl = n - 640; }
  else              { W = P1;  O = o_p1;  N = 64;  nl = n - 896; }
  O[nl * 128 + k] = f2bf(W[(size_t)k * N + nl]);
}

// ---------------------------------------------------------------------------
// Merged GEMM layer 0: reads x fp32 directly (stages bf16 to LDS), outputs
// xl/xr fp16 and hres fp16.
// ---------------------------------------------------------------------------
__global__ __launch_bounds__(256) void gemm_l0(
    const float* __restrict__ X, const unsigned short* __restrict__ BT,
    const float* __restrict__ bias0, const float* __restrict__ bias1,
    const float* __restrict__ bias2,
    _Float16* __restrict__ o_xl, _Float16* __restrict__ o_xr,
    _Float16* __restrict__ o_h, int M) {
  __shared__ unsigned short As[64 * 136];   // 272B pitch
  const int tid = threadIdx.x;
  const int rbase = blockIdx.x * 64;
#pragma unroll
  for (int i = 0; i < 8; ++i) {
    int c = i * 256 + tid;                  // 2048 float4 chunks (64 rows x 32)
    int row = c >> 5, c4 = c & 31;
    int ar = rbase + row; if (ar > M - 1) ar = M - 1;
    float4 v = *(const float4*)(X + (size_t)ar * 128 + c4 * 4);
    ushort4 o; o.x = f2bf(v.x); o.y = f2bf(v.y); o.z = f2bf(v.z); o.w = f2bf(v.w);
    *(ushort4*)(As + row * 136 + c4 * 4) = o;
  }
  __syncthreads();
  const int w = tid >> 6, l = tid & 63;
  const int lr = l & 15, lg = l >> 4;
#pragma unroll
  for (int i = 0; i < 6; ++i) {
    const int ct = w * 6 + i;
    const bf16x8* bp = (const bf16x8*)(BT + (size_t)(ct * 16 + lr) * 128 + lg * 8);
    bf16x8 b0 = bp[0], b1 = bp[4], b2 = bp[8], b3 = bp[12];
    const int colb = ct * 16 + lg * 4;
    const int cc = colb & 127;
    const float* bptr = (ct < 8 ? bias0 : (ct < 16 ? bias1 : bias2));
    float4 bv = *(const float4*)(bptr + cc);
#pragma unroll
    for (int rt = 0; rt < 4; ++rt) {
      const unsigned short* ap = As + (rt * 16 + lr) * 136 + lg * 8;
      bf16x8 a0 = *(const bf16x8*)(ap);
      bf16x8 a1 = *(const bf16x8*)(ap + 32);
      bf16x8 a2 = *(const bf16x8*)(ap + 64);
      bf16x8 a3 = *(const bf16x8*)(ap + 96);
      f32x4 acc = {0.f, 0.f, 0.f, 0.f};
      acc = __builtin_amdgcn_mfma_f32_16x16x32_bf16(b0, a0, acc, 0, 0, 0);
      acc = __builtin_amdgcn_mfma_f32_16x16x32_bf16(b1, a1, acc, 0, 0, 0);
      acc = __builtin_amdgcn_mfma_f32_16x16x32_bf16(b2, a2, acc, 0, 0, 0);
      acc = __builtin_amdgcn_mfma_f32_16x16x32_bf16(b3, a3, acc, 0, 0, 0);
      const int row = rbase + rt * 16 + lr;
      h4 o;
      o[0] = (_Float16)(acc[0] + bv.x); o[1] = (_Float16)(acc[1] + bv.y);
      o[2] = (_Float16)(acc[2] + bv.z); o[3] = (_Float16)(acc[3] + bv.w);
      _Float16* dst = (ct < 8) ? o_xl : (ct < 16 ? o_xr : o_h);
      *(h4*)(dst + (size_t)row * 128 + cc) = o;
    }
  }
}

// ---------------------------------------------------------------------------
// Merged GEMM layer 1: xl/xr outputs fp16, residual out fp32 (guarded).
// ---------------------------------------------------------------------------
__global__ __launch_bounds__(256) void gemm_l1(
    const unsigned short* __restrict__ A, const unsigned short* __restrict__ BT,
    const float* __restrict__ bias0, const float* __restrict__ bias1,
    const float* __restrict__ bias2,
    _Float16* __restrict__ o_xl, _Float16* __restrict__ o_xr,
    float* __restrict__ o_out, int M) {
  __shared__ unsigned short As[64 * 136];
  const int tid = threadIdx.x;
  const int rbase = blockIdx.x * 64;
#pragma unroll
  for (int i = 0; i < 4; ++i) {
    int c = i * 256 + tid;
    int row = c >> 4, slot = c & 15;
    int ar = rbase + row; if (ar > M - 1) ar = M - 1;
    uint4 v = *(const uint4*)(A + (size_t)ar * 128 + slot * 8);
    *(uint4*)(As + row * 136 + slot * 8) = v;
  }
  __syncthreads();
  const int w = tid >> 6, l = tid & 63;
  const int lr = l & 15, lg = l >> 4;
#pragma unroll
  for (int i = 0; i < 9; ++i) {
    const int ct = w * 9 + i;
    const bf16x8* bp = (const bf16x8*)(BT + (size_t)(ct * 16 + lr) * 128 + lg * 8);
    bf16x8 b0 = bp[0], b1 = bp[4], b2 = bp[8], b3 = bp[12];
    const int colb = ct * 16 + lg * 4;
    const int cc = (ct < 32) ? (colb & 255) : (colb - 512);
    const float* bptr = (ct < 16 ? bias0 : (ct < 32 ? bias1 : bias2));
    float4 bv = *(const float4*)(bptr + cc);
#pragma unroll
    for (int rt = 0; rt < 4; ++rt) {
      const unsigned short* ap = As + (rt * 16 + lr) * 136 + lg * 8;
      bf16x8 a0 = *(const bf16x8*)(ap);
      bf16x8 a1 = *(const bf16x8*)(ap + 32);
      bf16x8 a2 = *(const bf16x8*)(ap + 64);
      bf16x8 a3 = *(const bf16x8*)(ap + 96);
      f32x4 acc = {0.f, 0.f, 0.f, 0.f};
      acc = __builtin_amdgcn_mfma_f32_16x16x32_bf16(b0, a0, acc, 0, 0, 0);
      acc = __builtin_amdgcn_mfma_f32_16x16x32_bf16(b1, a1, acc, 0, 0, 0);
      acc = __builtin_amdgcn_mfma_f32_16x16x32_bf16(b2, a2, acc, 0, 0, 0);
      acc = __builtin_amdgcn_mfma_f32_16x16x32_bf16(b3, a3, acc, 0, 0, 0);
      const int row = rbase + rt * 16 + lr;
      if (ct < 32) {
        h4 o;
        o[0] = (_Float16)(acc[0] + bv.x); o[1] = (_Float16)(acc[1] + bv.y);
        o[2] = (_Float16)(acc[2] + bv.z); o[3] = (_Float16)(acc[3] + bv.w);
        *(h4*)((ct < 16 ? o_xl : o_xr) + (size_t)row * 256 + cc) = o;
      } else if (row < M) {
        float4 o;
        o.x = acc[0] + bv.x; o.y = acc[1] + bv.y;
        o.z = acc[2] + bv.z; o.w = acc[3] + bv.w;
        *(float4*)(o_out + (size_t)row * 64 + cc) = o;
      }
    }
  }
}

// ---------------------------------------------------------------------------
// per-edge steps, packed f16 (VOP3P): pk_fma/pk_add/pk_mul/pk_max + fdot2.
// ---------------------------------------------------------------------------
__device__ inline void edge_step0(int2 rec, h8 a8, bool valid,
                                  const h2* xrv2, const h2* wef2, const h2* att2,
                                  h2* acc2, float& den) {
  _Float16 wh = (_Float16)__int_as_float(rec.y);
  h2 w2; w2[0] = wh; w2[1] = wh;
  const h2 c02 = mkh2(0.2f, 0.2f);
  int4 ai = __builtin_bit_cast(int4, a8);
  h2 av[4];
  av[0] = __builtin_bit_cast(h2, ai.x); av[1] = __builtin_bit_cast(h2, ai.y);
  av[2] = __builtin_bit_cast(h2, ai.z); av[3] = __builtin_bit_cast(h2, ai.w);
  float c = 0.f;
#pragma unroll
  for (int k = 0; k < 4; ++k) {
    h2 sv = av[k] + (w2 * wef2[k] + xrv2[k]);
    h2 lk = __builtin_elementwise_max(sv, sv * c02);
    c = hdot2(lk, att2[k], c);
  }
  c += __shfl_xor(c, 1, 64); c += __shfl_xor(c, 2, 64);   // head = 4 lanes
  float p = valid ? __expf(c) : 0.f;
  den += p;
  _Float16 ph = (_Float16)p;
  h2 p2; p2[0] = ph; p2[1] = ph;
#pragma unroll
  for (int k = 0; k < 4; ++k) acc2[k] = p2 * av[k] + acc2[k];
}

__device__ inline void edge_step1(int2 rec, h8 a8, bool valid,
                                  const h2* xrv2, const h2* wef2, const h2* att2,
                                  h2* acc2, float& den) {
  _Float16 wh = (_Float16)__int_as_float(rec.y);
  h2 w2; w2[0] = wh; w2[1] = wh;
  const h2 c02 = mkh2(0.2f, 0.2f);
  int4 ai = __builtin_bit_cast(int4, a8);
  h2 av[4];
  av[0] = __builtin_bit_cast(h2, ai.x); av[1] = __builtin_bit_cast(h2, ai.y);
  av[2] = __builtin_bit_cast(h2, ai.z); av[3] = __builtin_bit_cast(h2, ai.w);
  float c = 0.f;
#pragma unroll
  for (int k = 0; k < 4; ++k) {
    h2 sv = av[k] + (w2 * wef2[k] + xrv2[k]);
    h2 lk = __builtin_elementwise_max(sv, sv * c02);
    c = hdot2(lk, att2[k], c);
  }
  c += __shfl_xor(c, 1, 64); c += __shfl_xor(c, 2, 64); c += __shfl_xor(c, 4, 64);
  float p = valid ? __expf(c) : 0.f;
  den += p;
  _Float16 ph = (_Float16)p;
  h2 p2; p2[0] = ph; p2[1] = ph;
#pragma unroll
  for (int k = 0; k < 4; ++k) acc2[k] = p2 * av[k] + acc2[k];
}

// ---------------------------------------------------------------------------
// Layer-0 aggregation: 1 wave/node, 4 edge groups x unroll 2; packed f16.
// Clamp-free segment reads (csr2 has 64-rec zeroed tail; e<cnt masks slops).
// ---------------------------------------------------------------------------
__global__ __launch_bounds__(256) void agg0(
    const int* __restrict__ part, const int* __restrict__ bsum,
    const int* __restrict__ deg, const int2* __restrict__ csr2,
    const _Float16* __restrict__ xl, const _Float16* __restrict__ xr,
    const float* __restrict__ We, const float* __restrict__ att,
    const float* __restrict__ b, const float* __restrict__ g,
    const float* __restrict__ be, const _Float16* __restrict__ hres,
    unsigned short* __restrict__ hout) {
  const int wid = threadIdx.x >> 6, l = threadIdx.x & 63;
  const int n = blockIdx.x * 4 + wid;
  const int grp = l >> 4, cl = l & 15, c0 = cl * 8;
  h2 xrv2[4], wef2[4], att2[4];
  {
    h8 x8 = *(const h8*)(xr + (size_t)n * HC0 + c0);
    int4 xi = __builtin_bit_cast(int4, x8);
    xrv2[0] = __builtin_bit_cast(h2, xi.x); xrv2[1] = __builtin_bit_cast(h2, xi.y);
    xrv2[2] = __builtin_bit_cast(h2, xi.z); xrv2[3] = __builtin_bit_cast(h2, xi.w);
    float4 w0 = *(const float4*)(We + c0),  w1 = *(const float4*)(We + c0 + 4);
    float4 t0 = *(const float4*)(att + c0), t1 = *(const float4*)(att + c0 + 4);
    wef2[0] = mkh2(w0.x, w0.y); wef2[1] = mkh2(w0.z, w0.w);
    wef2[2] = mkh2(w1.x, w1.y); wef2[3] = mkh2(w1.z, w1.w);
    att2[0] = mkh2(t0.x, t0.y); att2[1] = mkh2(t0.z, t0.w);
    att2[2] = mkh2(t1.x, t1.y); att2[3] = mkh2(t1.z, t1.w);
  }
  const int start = part[n] + bsum[n >> 8];
  const int cnt   = deg[n] + 1;
  const int2* seg = csr2 + start;
  h2 acc2[4] = {};
  float den = 0.f;
  int2 rA0 = seg[grp],      rA1 = seg[grp + 4];
  int2 rB0 = seg[grp + 8],  rB1 = seg[grp + 12];
  h8 aA0 = *(const h8*)(xl + (size_t)rA0.x * HC0 + c0);
  h8 aA1 = *(const h8*)(xl + (size_t)rA1.x * HC0 + c0);
  const int trips = (cnt + 7) >> 3;
  int e = grp;
  for (int t = 0; t < trips; ++t) {
    int2 rC0 = seg[e + 16], rC1 = seg[e + 20];
    h8 aB0 = *(const h8*)(xl + (size_t)rB0.x * HC0 + c0);
    h8 aB1 = *(const h8*)(xl + (size_t)rB1.x * HC0 + c0);
    edge_step0(rA0, aA0, e < cnt,     xrv2, wef2, att2, acc2, den);
    edge_step0(rA1, aA1, e + 4 < cnt, xrv2, wef2, att2, acc2, den);
    rA0 = rB0; rA1 = rB1; rB0 = rC0; rB1 = rC1; aA0 = aB0; aA1 = aB1;
    e += 8;
  }
  den += __shfl_xor(den, 16, 64); den += __shfl_xor(den, 32, 64);
#pragma unroll
  for (int k = 0; k < 4; ++k) {
    int b16 = __shfl_xor(__builtin_bit_cast(int, acc2[k]), 16, 64);
    acc2[k] = acc2[k] + __builtin_bit_cast(h2, b16);
    int b32 = __shfl_xor(__builtin_bit_cast(int, acc2[k]), 32, 64);
    acc2[k] = acc2[k] + __builtin_bit_cast(h2, b32);
  }
  float v[8], s1 = 0.f, s2 = 0.f;
  float dinv = 1.f / den;
  {
    float4 b0v = *(const float4*)(b + c0), b1v = *(const float4*)(b + c0 + 4);
    float bb[8] = {b0v.x,b0v.y,b0v.z,b0v.w,b1v.x,b1v.y,b1v.z,b1v.w};
#pragma unroll
    for (int j = 0; j < 8; ++j) {
      float t = (float)acc2[j >> 1][j & 1] * dinv + bb[j];
      t = t > 0.f ? t : __expf(t) - 1.f;
      v[j] = t; s1 += t; s2 += t * t;
    }
  }
  s1 += __shfl_xor(s1, 1, 64); s2 += __shfl_xor(s2, 1, 64);
  s1 += __shfl_xor(s1, 2, 64); s2 += __shfl_xor(s2, 2, 64);
  s1 += __shfl_xor(s1, 4, 64); s2 += __shfl_xor(s2, 4, 64);
  s1 += __shfl_xor(s1, 8, 64); s2 += __shfl_xor(s2, 8, 64);
  float mean = s1 * (1.f / 128.f);
  float inv  = rsqrtf(s2 * (1.f / 128.f) - mean * mean + 1e-5f);
  if (grp == 0) {
    float4 g0v = *(const float4*)(g + c0),  g1v = *(const float4*)(g + c0 + 4);
    float4 e0v = *(const float4*)(be + c0), e1v = *(const float4*)(be + c0 + 4);
    h8 hh = *(const h8*)(hres + (size_t)n * HC0 + c0);
    float gg[8] = {g0v.x,g0v.y,g0v.z,g0v.w,g1v.x,g1v.y,g1v.z,g1v.w};
    float ee[8] = {e0v.x,e0v.y,e0v.z,e0v.w,e1v.x,e1v.y,e1v.z,e1v.w};
    bf16x8 o;
#pragma unroll
    for (int j = 0; j < 8; ++j)
      o[j] = (short)f2bf((v[j] - mean) * inv * gg[j] + ee[j] + (float)hh[j]);
    *(bf16x8*)(hout + (size_t)n * HC0 + c0) = o;
  }
}

// ---------------------------------------------------------------------------
// Layer-1 aggregation: 1 wave/node, 2 edge groups x unroll 2; packed f16;
// clamp-free segment reads; barrier-free epilogue.
// ---------------------------------------------------------------------------
__global__ __launch_bounds__(256) void agg1(
    const int* __restrict__ part, const int* __restrict__ bsum,
    const int* __restrict__ deg, const int2* __restrict__ csr2,
    const _Float16* __restrict__ xl, const _Float16* __restrict__ xr,
    const float* __restrict__ We, const float* __restrict__ att,
    const float* __restrict__ b, const float* __restrict__ g,
    const float* __restrict__ be, float* __restrict__ out) {
  const int wid = threadIdx.x >> 6, l = threadIdx.x & 63;
  const int n = blockIdx.x * 4 + wid;
  const int grp = l >> 5, cl = l & 31, c0 = cl * 8;
  h2 xrv2[4], wef2[4], att2[4];
  {
    h8 x8 = *(const h8*)(xr + (size_t)n * HC1 + c0);
    int4 xi = __builtin_bit_cast(int4, x8);
    xrv2[0] = __builtin_bit_cast(h2, xi.x); xrv2[1] = __builtin_bit_cast(h2, xi.y);
    xrv2[2] = __builtin_bit_cast(h2, xi.z); xrv2[3] = __builtin_bit_cast(h2, xi.w);
    float4 w0 = *(const float4*)(We + c0),  w1 = *(const float4*)(We + c0 + 4);
    float4 t0 = *(const float4*)(att + c0), t1 = *(const float4*)(att + c0 + 4);
    wef2[0] = mkh2(w0.x, w0.y); wef2[1] = mkh2(w0.z, w0.w);
    wef2[2] = mkh2(w1.x, w1.y); wef2[3] = mkh2(w1.z, w1.w);
    att2[0] = mkh2(t0.x, t0.y); att2[1] = mkh2(t0.z, t0.w);
    att2[2] = mkh2(t1.x, t1.y); att2[3] = mkh2(t1.z, t1.w);
  }
  const int start = part[n] + bsum[n >> 8];
  const int cnt   = deg[n] + 1;
  const int2* seg = csr2 + start;
  h2 acc2[4] = {};
  float den = 0.f;
  int2 rA0 = seg[grp],     rA1 = seg[grp + 2];
  int2 rB0 = seg[grp + 4], rB1 = seg[grp + 6];
  h8 aA0 = *(const h8*)(xl + (size_t)rA0.x * HC1 + c0);
  h8 aA1 = *(const h8*)(xl + (size_t)rA1.x * HC1 + c0);
  const int trips = (cnt + 3) >> 2;
  int e = grp;
  for (int t = 0; t < trips; ++t) {
    int2 rC0 = seg[e + 8], rC1 = seg[e + 10];
    h8 aB0 = *(const h8*)(xl + (size_t)rB0.x * HC1 + c0);
    h8 aB1 = *(const h8*)(xl + (size_t)rB1.x * HC1 + c0);
    edge_step1(rA0, aA0, e < cnt,     xrv2, wef2, att2, acc2, den);
    edge_step1(rA1, aA1, e + 2 < cnt, xrv2, wef2, att2, acc2, den);
    rA0 = rB0; rA1 = rB1; rB0 = rC0; rB1 = rC1; aA0 = aB0; aA1 = aB1;
    e += 4;
  }
  den += __shfl_xor(den, 32, 64);
#pragma unroll
  for (int k = 0; k < 4; ++k) {
    int b32 = __shfl_xor(__builtin_bit_cast(int, acc2[k]), 32, 64);
    acc2[k] = acc2[k] + __builtin_bit_cast(h2, b32);
  }
  // head-mean in-wave: lane cl holds head h=cl>>3, output block oc=(cl&7)*8.
  float dinv = 1.f / den;
  float v[8], s1 = 0.f, s2 = 0.f;
  const int oc = (cl & 7) * 8;
  {
    float4 b0v = *(const float4*)(b + oc), b1v = *(const float4*)(b + oc + 4);
    float bb[8] = {b0v.x,b0v.y,b0v.z,b0v.w,b1v.x,b1v.y,b1v.z,b1v.w};
#pragma unroll
    for (int j = 0; j < 8; ++j) {
      float t = (float)acc2[j >> 1][j & 1] * dinv;
      t += __shfl_xor(t, 8, 64);
      t += __shfl_xor(t, 16, 64);
      t = t * 0.25f + bb[j];
      t = t > 0.f ? t : __expf(t) - 1.f;       // ELU
      v[j] = t; s1 += t; s2 += t * t;
    }
  }
  s1 += __shfl_xor(s1, 1, 64); s2 += __shfl_xor(s2, 1, 64);
  s1 += __shfl_xor(s1, 2, 64); s2 += __shfl_xor(s2, 2, 64);
  s1 += __shfl_xor(s1, 4, 64); s2 += __shfl_xor(s2, 4, 64);
  float mean = s1 * (1.f / 64.f);
  float inv  = rsqrtf(s2 * (1.f / 64.f) - mean * mean + 1e-5f);
  if (grp == 0 && cl < 8) {
    float4 g0v = *(const float4*)(g + oc),  g1v = *(const float4*)(g + oc + 4);
    float4 e0v = *(const float4*)(be + oc), e1v = *(const float4*)(be + oc + 4);
    float gg[8] = {g0v.x,g0v.y,g0v.z,g0v.w,g1v.x,g1v.y,g1v.z,g1v.w};
    float ee[8] = {e0v.x,e0v.y,e0v.z,e0v.w,e1v.x,e1v.y,e1v.z,e1v.w};
    float* po = out + (size_t)n * 64 + oc;
    float4 o0 = *(const float4*)po, o1 = *(const float4*)(po + 4);
    o0.x += (v[0] - mean) * inv * gg[0] + ee[0];
    o0.y += (v[1] - mean) * inv * gg[1] + ee[1];
    o0.z += (v[2] - mean) * inv * gg[2] + ee[2];
    o0.w += (v[3] - mean) * inv * gg[3] + ee[3];
    o1.x += (v[4] - mean) * inv * gg[4] + ee[4];
    o1.y += (v[5] - mean) * inv * gg[5] + ee[5];
    o1.z += (v[6] - mean) * inv * gg[6] + ee[6];
    o1.w += (v[7] - mean) * inv * gg[7] + ee[7];
    *(float4*)po = o0; *(float4*)(po + 4) = o1;
  }
}

// ---------------------------------------------------------------------------
extern "C" void kernel_launch(void* const* d_in, const int* in_sizes, int n_in,
                              void* d_out, int out_size, void* d_ws, size_t ws_size,
                              hipStream_t stream) {
  const float* x    = (const float*)d_in[0];
  const int*   ei   = (const int*)  d_in[1];
  const float* ew   = (const float*)d_in[2];
  const float* Wl0  = (const float*)d_in[3];
  const float* bl0  = (const float*)d_in[4];
  const float* Wr0  = (const float*)d_in[5];
  const float* br0  = (const float*)d_in[6];
  const float* We0  = (const float*)d_in[7];
  const float* att0 = (const float*)d_in[8];
  const float* b0   = (const float*)d_in[9];
  const float* g0   = (const float*)d_in[10];
  const float* be0  = (const float*)d_in[11];
  const float* Wl1  = (const float*)d_in[12];
  const float* bl1  = (const float*)d_in[13];
  const float* Wr1  = (const float*)d_in[14];
  const float* br1  = (const float*)d_in[15];
  const float* We1  = (const float*)d_in[16];
  const float* att1 = (const float*)d_in[17];
  const float* b1   = (const float*)d_in[18];
  const float* g1   = (const float*)d_in[19];
  const float* be1  = (const float*)d_in[20];
  const float* P0   = (const float*)d_in[21];
  const float* pb0  = (const float*)d_in[22];
  const float* P1   = (const float*)d_in[23];
  const float* pb1  = (const float*)d_in[24];
  float* out = (float*)d_out;

  // workspace layout (32-bit words)
  float* f        = (float*)d_ws;
  float* s_loopw  = f;                               // 50176
  int*   deg      = (int*)(f + 50176);               // 50176
  int*   cursor   = (int*)(f + 100352);              // 50176
  int*   part     = (int*)(f + 150528);              // 50176
  int*   bsum     = (int*)(f + 200704);              // 256
  int2*  csr2     = (int2*)(f + 200960);             // 450064 int2 (incl tail)
  unsigned short* wl0T = (unsigned short*)(f + 1102080);  // 384x128 bf16
  unsigned short* wr0T = wl0T + 16384;
  unsigned short* p0T  = wl0T + 32768;
  unsigned short* wl1T = (unsigned short*)(f + 1126656);  // 576x128 bf16
  unsigned short* wr1T = wl1T + 32768;
  unsigned short* p1T  = wl1T + 65536;
  unsigned short* hb   = (unsigned short*)(f + 1163520);  // MROWS x128 bf16
  _Float16*       hres = (_Float16*)(f + 4366592);        // MROWS x128 f16
  _Float16*       RA   = (_Float16*)(f + 7569664);        // MROWS x256 f16
  _Float16*       RB   = (_Float16*)(f + 13975808);       // MROWS x256 f16
  _Float16* xl0h = RA, *xr0h = RB;
  _Float16* xl1h = RA, *xr1h = RB;

  // ---- CSR build ---------------------------------------------------------
  hipMemsetAsync(s_loopw, 0, (size_t)(50176 * 3) * sizeof(float), stream); // s,deg,cursor
  hipMemsetAsync(csr2 + CSR_TOTAL, 0, 64 * sizeof(int2), stream);          // tail pad
  deg_kernel<<<(N_EDGES + 255) / 256, 256, 0, stream>>>(ei, ew, s_loopw, deg);
  scan1<<<NPAD / 256, 256, 0, stream>>>(deg, part, bsum);
  scan2<<<1, 256, 0, stream>>>(bsum);
  self_kernel<<<(N_NODES + 255) / 256, 256, 0, stream>>>(s_loopw, deg, part, bsum, csr2);
  scatter_kernel<<<(N_EDGES + 255) / 256, 256, 0, stream>>>(ei, ew, part, bsum,
                                                            cursor, csr2);

  // ---- precision prep ----------------------------------------------------
  pack_w<<<960, 128, 0, stream>>>(Wl0, Wr0, P0, Wl1, Wr1, P1,
                                  wl0T, wr0T, p0T, wl1T, wr1T, p1T);

  // ---- layer 0 -----------------------------------------------------------
  const int GB = MROWS / 64;   // 782
  gemm_l0<<<GB, 256, 0, stream>>>(x, wl0T, bl0, br0, pb0, xl0h, xr0h, hres, N_NODES);
  agg0<<<N_NODES / 4, 256, 0, stream>>>(part, bsum, deg, csr2,
                                        xl0h, xr0h, We0, att0, b0, g0, be0, hres, hb);

  // ---- layer 1 -----------------------------------------------------------
  gemm_l1<<<GB, 256, 0, stream>>>(hb, wl1T, bl1, br1, pb1, xl1h, xr1h, out, N_NODES);
  agg1<<<N_NODES / 4, 256, 0, stream>>>(part, bsum, deg, csr2,
                                        xl1h, xr1h, We1, att1, b1, g1, be1, out);
}